// Round 1
// baseline (2416.191 us; speedup 1.0000x reference)
//
#include <hip/hip_runtime.h>
#include <hip/hip_bf16.h>

// ---------------- direct convolution (one thread per output) ----------------
template<int CI,int CO,int HI,int WI,int HO,int WO,int STR,int PAD,bool BIAS>
__global__ void conv_direct(const float* __restrict__ in, const float* __restrict__ w,
                            const float* __restrict__ bias, float* __restrict__ out, int B) {
  int idx = blockIdx.x*blockDim.x + threadIdx.x;
  int total = B*CO*HO*WO;
  if (idx >= total) return;
  int wo = idx % WO; int t = idx / WO;
  int ho = t % HO;   t /= HO;
  int co = t % CO;   int b = t / CO;
  float acc = BIAS ? bias[co] : 0.f;
  const float* wp = w + co*CI*9;
  const float* ip = in + (size_t)b*CI*HI*WI;
  int hi0 = ho*STR - PAD, wi0 = wo*STR - PAD;
  for (int ci = 0; ci < CI; ++ci) {
    const float* ic = ip + ci*HI*WI;
    const float* wc = wp + ci*9;
    #pragma unroll
    for (int ki = 0; ki < 3; ++ki) {
      int hi = hi0 + ki;
      if (hi < 0 || hi >= HI) continue;
      #pragma unroll
      for (int kj = 0; kj < 3; ++kj) {
        int wi = wi0 + kj;
        if (wi < 0 || wi >= WI) continue;
        acc = fmaf(ic[hi*WI + wi], wc[ki*3+kj], acc);
      }
    }
  }
  out[idx] = acc;
}

// ---------------- BN training-mode stats (deterministic two-level) ----------------
template<int C,int HW,int SLICES>
__global__ void bn_partial(const float* __restrict__ x, float* __restrict__ part, int B) {
  int c = blockIdx.x / SLICES, s = blockIdx.x % SLICES;
  int bpp = B / SLICES;
  float sum = 0.f, sq = 0.f;
  for (int b = s*bpp; b < (s+1)*bpp; ++b) {
    const float* p = x + ((size_t)b*C + c)*HW;
    for (int i = threadIdx.x; i < HW; i += blockDim.x) {
      float v = p[i]; sum += v; sq += v*v;
    }
  }
  #pragma unroll
  for (int off = 32; off; off >>= 1) {
    sum += __shfl_down(sum, off, 64);
    sq  += __shfl_down(sq,  off, 64);
  }
  __shared__ float ls[2][4];
  int lane = threadIdx.x & 63, wv = threadIdx.x >> 6;
  if (lane == 0) { ls[0][wv] = sum; ls[1][wv] = sq; }
  __syncthreads();
  if (threadIdx.x == 0) {
    float S = 0.f, Q = 0.f;
    #pragma unroll
    for (int i = 0; i < 4; ++i) { S += ls[0][i]; Q += ls[1][i]; }
    part[(c*SLICES+s)*2+0] = S; part[(c*SLICES+s)*2+1] = Q;
  }
}

template<int C,int SLICES>
__global__ void bn_final(const float* __restrict__ part, const float* __restrict__ g,
                         const float* __restrict__ bta, float* __restrict__ sc, int NHW) {
  int c = blockIdx.x*blockDim.x + threadIdx.x;
  if (c >= C) return;
  float S = 0.f, Q = 0.f;
  for (int s = 0; s < SLICES; ++s) { S += part[(c*SLICES+s)*2]; Q += part[(c*SLICES+s)*2+1]; }
  float m = S / NHW, v = Q / NHW - m*m;
  float inv = rsqrtf(v + 1e-5f);
  float a = g[c] * inv;
  sc[c*2] = a; sc[c*2+1] = bta[c] - m*a;
}

template<int C,int HW>
__global__ void bn_apply(float* __restrict__ x, const float* __restrict__ sc, int total) {
  int idx = blockIdx.x*blockDim.x + threadIdx.x;
  if (idx >= total) return;
  int c = (idx / HW) % C;
  float v = x[idx]*sc[c*2] + sc[c*2+1];
  x[idx] = v > 0.f ? v : 0.f;
}

// ---------------- squash primary caps in place (groups of 12 in flat layout) ----------------
__global__ void squash_pc(float* __restrict__ pc, int ncaps) {
  int i = blockIdx.x*blockDim.x + threadIdx.x;
  if (i >= ncaps) return;
  float* p = pc + (size_t)i*12;
  float v[12]; float s = 0.f;
  #pragma unroll
  for (int d = 0; d < 12; ++d) { v[d] = p[d]; s += v[d]*v[d]; }
  float sc = s / ((1.f + s)*sqrtf(s + 1e-6f));
  #pragma unroll
  for (int d = 0; d < 12; ++d) p[d] = v[d]*sc;
}

// ---------------- uu gather: index-permutation of squashed pc ----------------
__global__ void uu_gather(const float* __restrict__ sq, float* __restrict__ uu, int B) {
  int idx = blockIdx.x*blockDim.x + threadIdx.x;
  int total = B*49*144*12;
  if (idx >= total) return;
  int ii = idx % 12; int t0 = idx / 12;
  int kk = t0 % 144; t0 /= 144;
  int tt = t0 % 49;  int b = t0 / 49;
  int f = tt*1728 + kk*12 + ii;
  int c = f / 441; int r = f - c*441;
  int k = r / 49;  int sp = r - k*49;
  int y = sp / 7, x = sp - y*7;
  int iy = y + k/3 - 1, ix = x + (k%3) - 1;
  float val = 0.f;
  if (iy >= 0 && iy < 7 && ix >= 0 && ix < 7)
    val = sq[((size_t)(b*192 + c)*7 + iy)*7 + ix];
  uu[idx] = val;
}

// ---------------- ConvCaps einsum: per-k GEMM tile, bf16 u_hat output ----------------
// grid (144, 13), block 192. u_hat chunk layout [rowLocal][k][o] bf16
__global__ void cc_einsum(const float* __restrict__ uu, const float* __restrict__ wcc,
                          __hip_bfloat16* __restrict__ uhat, int row0, int nrows) {
  int k  = blockIdx.x;
  int m0 = blockIdx.y * 64;
  __shared__ float A[64][12];
  int o = threadIdx.x;                       // 0..191
  for (int e = threadIdx.x; e < 64*12; e += 192) {
    int m = e / 12, ii = e % 12;
    int row = m0 + m;
    A[m][ii] = (row < nrows) ? uu[((size_t)(row0+row)*144 + k)*12 + ii] : 0.f;
  }
  __syncthreads();
  float w[12];
  #pragma unroll
  for (int ii = 0; ii < 12; ++ii) w[ii] = wcc[((size_t)k*192 + o)*12 + ii];
  int mmax = nrows - m0; if (mmax > 64) mmax = 64;
  for (int m = 0; m < mmax; ++m) {
    float acc = 0.f;
    #pragma unroll
    for (int ii = 0; ii < 12; ++ii) acc = fmaf(w[ii], A[m][ii], acc);
    uhat[((size_t)(m0+m)*144 + k)*192 + o] = __float2bfloat16(acc);
  }
}

// ---------------- ConvCaps routing: u_hat tile resident in LDS, 3 iterations ----------------
__global__ __launch_bounds__(512,1) void cc_route(const __hip_bfloat16* __restrict__ uhat,
                                                  float* __restrict__ u2, int bBase) {
  int row = blockIdx.x;          // 0..783 within chunk (b_local*49 + t)
  __shared__ __align__(16) __hip_bfloat16 uh[144*192];
  __shared__ float blog[144*16];
  __shared__ float cc[144*16];
  __shared__ float sv[2][192];
  __shared__ float scl[16];
  int tid = threadIdx.x;
  const uint4* src = (const uint4*)(uhat + (size_t)row*144*192);
  uint4* dst = (uint4*)uh;
  for (int i = tid; i < 3456; i += 512) dst[i] = src[i];       // 55 KB copy
  for (int i = tid; i < 2304; i += 512) blog[i] = 0.f;
  __syncthreads();
  for (int r = 0; r < 3; ++r) {
    // softmax over the 16 output-caps axis, per k
    if (tid < 144) {
      float mx = -1e30f;
      #pragma unroll
      for (int o = 0; o < 16; ++o) mx = fmaxf(mx, blog[tid*16+o]);
      float e[16]; float ssum = 0.f;
      #pragma unroll
      for (int o = 0; o < 16; ++o) { e[o] = __expf(blog[tid*16+o]-mx); ssum += e[o]; }
      float inv = 1.f/ssum;
      #pragma unroll
      for (int o = 0; o < 16; ++o) cc[tid*16+o] = e[o]*inv;
    }
    __syncthreads();
    // s[o] = sum_k c[k, o/12] * u_hat[k, o]
    if (tid < 384) {
      int o = tid % 192, half = tid / 192;
      float acc = 0.f;
      for (int k = half*72; k < half*72+72; ++k)
        acc = fmaf(cc[k*16 + o/12], __bfloat162float(uh[k*192+o]), acc);
      sv[half][o] = acc;
    }
    __syncthreads();
    if (tid < 192) sv[0][tid] += sv[1][tid];
    __syncthreads();
    if (tid < 16) {
      float s = 0.f;
      #pragma unroll
      for (int d = 0; d < 12; ++d) { float v = sv[0][tid*12+d]; s += v*v; }
      scl[tid] = s / ((1.f + s)*sqrtf(s + 1e-6f));
    }
    __syncthreads();
    if (tid < 192) sv[0][tid] *= scl[tid/12];
    __syncthreads();
    if (r < 2) {
      for (int p = tid; p < 2304; p += 512) {
        int k = p >> 4, oc = p & 15;
        float dot = 0.f;
        #pragma unroll
        for (int d = 0; d < 12; ++d)
          dot = fmaf(sv[0][oc*12+d], __bfloat162float(uh[k*192+oc*12+d]), dot);
        blog[p] += dot;
      }
      __syncthreads();
    }
  }
  if (tid < 192) u2[((size_t)bBase*49 + row)*192 + tid] = sv[0][tid];
}

// ---------------- Class caps einsum ----------------
// grid 784, block 320. uhat2 layout [b][n][o*16+d]
__global__ void class_einsum(const float* __restrict__ u2, const float* __restrict__ wcl,
                             float* __restrict__ uhat2, int B) {
  int n = blockIdx.x;
  __shared__ float u2l[64][12];
  int tid = threadIdx.x;
  for (int e = tid; e < 64*12; e += 320) {
    int b = e / 12, i = e % 12;
    u2l[b][i] = u2[(size_t)b*9408 + n*12 + i];
  }
  __syncthreads();
  int od = tid % 160, bh = tid / 160;
  int o = od >> 4, d = od & 15;
  float w[12];
  #pragma unroll
  for (int i = 0; i < 12; ++i) w[i] = wcl[(size_t)n*1920 + o*192 + d*12 + i];
  for (int b = bh*32; b < bh*32+32; ++b) {
    float acc = 0.f;
    #pragma unroll
    for (int i = 0; i < 12; ++i) acc = fmaf(w[i], u2l[b][i], acc);
    uhat2[((size_t)b*784 + n)*160 + od] = acc;
  }
}

__global__ void fill_zero(float* __restrict__ p, int n) {
  int i = blockIdx.x*blockDim.x + threadIdx.x;
  if (i < n) p[i] = 0.f;
}

__global__ void class_softmax(const float* __restrict__ b2l, float* __restrict__ c2, int total) {
  int i = blockIdx.x*blockDim.x + threadIdx.x;
  if (i >= total) return;
  const float* p = b2l + (size_t)i*10;
  float mx = -1e30f;
  #pragma unroll
  for (int o = 0; o < 10; ++o) mx = fmaxf(mx, p[o]);
  float e[10]; float s = 0.f;
  #pragma unroll
  for (int o = 0; o < 10; ++o) { e[o] = __expf(p[o]-mx); s += e[o]; }
  float inv = 1.f/s;
  float* q = c2 + (size_t)i*10;
  #pragma unroll
  for (int o = 0; o < 10; ++o) q[o] = e[o]*inv;
}

// grid B*10, block 256: s[b,o,:] = sum_n c*uhat2, then squash, write v
__global__ void class_s(const float* __restrict__ c2, const float* __restrict__ uhat2,
                        float* __restrict__ vout, int B) {
  int b = blockIdx.x / 10, o = blockIdx.x % 10;
  int d = threadIdx.x & 15, sl = threadIdx.x >> 4;
  float acc = 0.f;
  for (int n = sl; n < 784; n += 16)
    acc = fmaf(c2[((size_t)b*784+n)*10+o], uhat2[((size_t)b*784+n)*160 + o*16 + d], acc);
  __shared__ float red[16][17];
  __shared__ float sd[16];
  red[sl][d] = acc;
  __syncthreads();
  if (threadIdx.x < 16) {
    float s = 0.f;
    #pragma unroll
    for (int i = 0; i < 16; ++i) s += red[i][threadIdx.x];
    sd[threadIdx.x] = s;
  }
  __syncthreads();
  if (threadIdx.x < 16) {
    float nrm = 0.f;
    #pragma unroll
    for (int i = 0; i < 16; ++i) nrm += sd[i]*sd[i];
    float sc = nrm / ((1.f + nrm)*sqrtf(nrm + 1e-6f));
    vout[((size_t)b*10+o)*16 + threadIdx.x] = sd[threadIdx.x]*sc;
  }
}

__global__ void class_bupd(const float* __restrict__ vv, const float* __restrict__ uhat2,
                           float* __restrict__ b2l, int total) {
  int i = blockIdx.x*blockDim.x + threadIdx.x;
  if (i >= total) return;
  int o = i % 10; int bn = i / 10; int b = bn / 784;
  const float* up = uhat2 + (size_t)bn*160 + o*16;
  const float* vp = vv + ((size_t)b*10+o)*16;
  float dot = 0.f;
  #pragma unroll
  for (int d = 0; d < 16; ++d) dot = fmaf(vp[d], up[d], dot);
  b2l[i] += dot;
}

// ---------------- host launch ----------------
extern "C" void kernel_launch(void* const* d_in, const int* in_sizes, int n_in,
                              void* d_out, int out_size, void* d_ws, size_t ws_size,
                              hipStream_t stream) {
  const float* images = (const float*)d_in[0];
  const float* w1  = (const float*)d_in[1];
  const float* g1  = (const float*)d_in[2];
  const float* b1  = (const float*)d_in[3];
  const float* w2  = (const float*)d_in[4];
  const float* g2  = (const float*)d_in[5];
  const float* b2  = (const float*)d_in[6];
  const float* w3  = (const float*)d_in[7];
  const float* g3  = (const float*)d_in[8];
  const float* b3  = (const float*)d_in[9];
  const float* wp  = (const float*)d_in[10];
  const float* bp  = (const float*)d_in[11];
  const float* wcc = (const float*)d_in[12];
  const float* wcl = (const float*)d_in[13];
  float* out = (float*)d_out;
  float* ws  = (float*)d_ws;

  // ws layout (float offsets, all 16-float aligned)
  float* t1    = ws + 0;            // 3,145,728
  float* t2    = ws + 3145728;      // 1,572,864
  float* t3    = ws + 4718592;      // 3,145,728
  float* pc    = ws + 7864320;      //   602,112
  float* uu    = ws + 8466432;      // 5,419,008
  float* u2b   = ws + 13885440;     //   602,112
  float* uh2   = ws + 14487552;     // 8,028,160
  float* b2l   = ws + 22515712;     //   501,760
  float* c2    = ws + 23017472;     //   501,760
  float* v2    = ws + 23519232;     //    10,240
  float* spart = ws + 23529472;     //     3,072
  float* ssc   = ws + 23532544;     //       384
  __hip_bfloat16* uhc = (__hip_bfloat16*)(ws + 23532928);  // 21,676,032 bf16

  const int B = 64;

  // conv1 + BN + ReLU (32x32, 3->48)
  conv_direct<3,48,32,32,32,32,1,1,false><<<12288,256,0,stream>>>(images, w1, nullptr, t1, B);
  bn_partial<48,1024,8><<<48*8,256,0,stream>>>(t1, spart, B);
  bn_final<48,8><<<1,256,0,stream>>>(spart, g1, b1, ssc, 65536);
  bn_apply<48,1024><<<12288,256,0,stream>>>(t1, ssc, 3145728);
  // conv2 + BN + ReLU (32->16, 48->96, stride 2)
  conv_direct<48,96,32,32,16,16,2,1,false><<<6144,256,0,stream>>>(t1, w2, nullptr, t2, B);
  bn_partial<96,256,8><<<96*8,256,0,stream>>>(t2, spart, B);
  bn_final<96,8><<<1,256,0,stream>>>(spart, g2, b2, ssc, 16384);
  bn_apply<96,256><<<6144,256,0,stream>>>(t2, ssc, 1572864);
  // conv3 + BN + ReLU (16x16, 96->192)
  conv_direct<96,192,16,16,16,16,1,1,false><<<12288,256,0,stream>>>(t2, w3, nullptr, t3, B);
  bn_partial<192,256,8><<<192*8,256,0,stream>>>(t3, spart, B);
  bn_final<192,8><<<1,256,0,stream>>>(spart, g3, b3, ssc, 16384);
  bn_apply<192,256><<<12288,256,0,stream>>>(t3, ssc, 3145728);
  // primary caps conv (16->7, 192->192, stride 2, pad 0) + bias, then squash in place
  conv_direct<192,192,16,16,7,7,2,0,true><<<2352,256,0,stream>>>(t3, wp, bp, pc, B);
  squash_pc<<<196,256,0,stream>>>(pc, 50176);
  // uu gather (B,49,144,12)
  uu_gather<<<21168,256,0,stream>>>(pc, uu, B);
  // ConvCaps einsum + fused in-LDS routing, chunked over b (4 x 16 images)
  for (int cb = 0; cb < 4; ++cb) {
    cc_einsum<<<dim3(144,13),192,0,stream>>>(uu, wcc, uhc, cb*784, 784);
    cc_route<<<784,512,0,stream>>>(uhc, u2b, cb*16);
  }
  // Class caps einsum
  class_einsum<<<784,320,0,stream>>>(u2b, wcl, uh2, B);
  // Class routing (3 iterations)
  fill_zero<<<1960,256,0,stream>>>(b2l, 501760);
  for (int r = 0; r < 3; ++r) {
    class_softmax<<<196,256,0,stream>>>(b2l, c2, 50176);
    class_s<<<640,256,0,stream>>>(c2, uh2, (r == 2) ? out : v2, B);
    if (r < 2) class_bupd<<<1960,256,0,stream>>>(v2, uh2, b2l, 501760);
  }
  (void)in_sizes; (void)n_in; (void)out_size; (void)ws_size;
}

// Round 2
// 861.763 us; speedup vs baseline: 2.8038x; 2.8038x over previous
//
#include <hip/hip_runtime.h>
#include <hip/hip_bf16.h>

// ---------------- direct convolution (kept only for conv1, CI=3) ----------------
template<int CI,int CO,int HI,int WI,int HO,int WO,int STR,int PAD,bool BIAS>
__global__ void conv_direct(const float* __restrict__ in, const float* __restrict__ w,
                            const float* __restrict__ bias, float* __restrict__ out, int B) {
  int idx = blockIdx.x*blockDim.x + threadIdx.x;
  int total = B*CO*HO*WO;
  if (idx >= total) return;
  int wo = idx % WO; int t = idx / WO;
  int ho = t % HO;   t /= HO;
  int co = t % CO;   int b = t / CO;
  float acc = BIAS ? bias[co] : 0.f;
  const float* wp = w + co*CI*9;
  const float* ip = in + (size_t)b*CI*HI*WI;
  int hi0 = ho*STR - PAD, wi0 = wo*STR - PAD;
  for (int ci = 0; ci < CI; ++ci) {
    const float* ic = ip + ci*HI*WI;
    const float* wc = wp + ci*9;
    #pragma unroll
    for (int ki = 0; ki < 3; ++ki) {
      int hi = hi0 + ki;
      if (hi < 0 || hi >= HI) continue;
      #pragma unroll
      for (int kj = 0; kj < 3; ++kj) {
        int wi = wi0 + kj;
        if (wi < 0 || wi >= WI) continue;
        acc = fmaf(ic[hi*WI + wi], wc[ki*3+kj], acc);
      }
    }
  }
  out[idx] = acc;
}

// ---------------- implicit-GEMM conv: per-image M=CO, N=HO*WO, K=CI*9 ----------------
// block 256 = 16x16 threads, micro-tile MR x 4, tiles MT=MR*16 (M) x 64 (N), K-chunk KC.
// As[k][m] (weights transposed), Bs[k][n] (im2col gather). Requires K % KC == 0.
template<int CI,int HI,int WI,int HO,int WO,int STR,int PAD,int MR,int KC,bool BIAS>
__global__ __launch_bounds__(256) void conv_gemm(const float* __restrict__ in,
                                                 const float* __restrict__ w,
                                                 const float* __restrict__ bias,
                                                 float* __restrict__ out, int CO) {
  constexpr int MT = MR*16, NT = 64, K = CI*9, NSP = HO*WO;
  int b = blockIdx.z, m0 = blockIdx.x*MT, n0 = blockIdx.y*NT;
  __shared__ float As[KC][MT];
  __shared__ float Bs[KC][NT];
  int tid = threadIdx.x, tx = tid & 15, ty = tid >> 4;
  float acc[MR][4];
  #pragma unroll
  for (int r = 0; r < MR; ++r)
    #pragma unroll
    for (int c = 0; c < 4; ++c) acc[r][c] = 0.f;
  const float* inb = in + (size_t)b*CI*HI*WI;
  for (int kc = 0; kc < K; kc += KC) {
    // stage A (weights): m-fast so LDS writes are conflict-free; w is L2-hot
    for (int e = tid; e < MT*KC; e += 256) {
      int m = e % MT, k = e / MT;
      As[k][m] = w[(size_t)(m0+m)*K + kc + k];
    }
    // stage B (im2col gather)
    for (int e = tid; e < NT*KC; e += 256) {
      int n = e % NT, k = e / NT;
      int kg = kc + k;
      int ci = kg / 9, tap = kg % 9;
      int sp = n0 + n;
      int ho = sp / WO, wo = sp % WO;
      int hi = ho*STR - PAD + tap/3, wi = wo*STR - PAD + tap%3;
      float v = 0.f;
      if (sp < NSP && hi >= 0 && hi < HI && wi >= 0 && wi < WI)
        v = inb[(ci*HI + hi)*WI + wi];
      Bs[k][n] = v;
    }
    __syncthreads();
    #pragma unroll
    for (int k = 0; k < KC; ++k) {
      float4 bv = *(const float4*)&Bs[k][tx*4];
      #pragma unroll
      for (int r = 0; r < MR; ++r) {
        float av = As[k][ty*MR + r];
        acc[r][0] = fmaf(av, bv.x, acc[r][0]);
        acc[r][1] = fmaf(av, bv.y, acc[r][1]);
        acc[r][2] = fmaf(av, bv.z, acc[r][2]);
        acc[r][3] = fmaf(av, bv.w, acc[r][3]);
      }
    }
    __syncthreads();
  }
  #pragma unroll
  for (int r = 0; r < MR; ++r) {
    int co = m0 + ty*MR + r;
    float bs = BIAS ? bias[co] : 0.f;
    #pragma unroll
    for (int c = 0; c < 4; ++c) {
      int sp = n0 + tx*4 + c;
      if (sp < NSP)
        out[((size_t)b*CO + co)*NSP + sp] = acc[r][c] + bs;
    }
  }
}

// ---------------- BN training-mode stats (deterministic two-level) ----------------
template<int C,int HW,int SLICES>
__global__ void bn_partial(const float* __restrict__ x, float* __restrict__ part, int B) {
  int c = blockIdx.x / SLICES, s = blockIdx.x % SLICES;
  int bpp = B / SLICES;
  float sum = 0.f, sq = 0.f;
  for (int b = s*bpp; b < (s+1)*bpp; ++b) {
    const float* p = x + ((size_t)b*C + c)*HW;
    for (int i = threadIdx.x; i < HW; i += blockDim.x) {
      float v = p[i]; sum += v; sq += v*v;
    }
  }
  #pragma unroll
  for (int off = 32; off; off >>= 1) {
    sum += __shfl_down(sum, off, 64);
    sq  += __shfl_down(sq,  off, 64);
  }
  __shared__ float ls[2][4];
  int lane = threadIdx.x & 63, wv = threadIdx.x >> 6;
  if (lane == 0) { ls[0][wv] = sum; ls[1][wv] = sq; }
  __syncthreads();
  if (threadIdx.x == 0) {
    float S = 0.f, Q = 0.f;
    #pragma unroll
    for (int i = 0; i < 4; ++i) { S += ls[0][i]; Q += ls[1][i]; }
    part[(c*SLICES+s)*2+0] = S; part[(c*SLICES+s)*2+1] = Q;
  }
}

template<int C,int SLICES>
__global__ void bn_final(const float* __restrict__ part, const float* __restrict__ g,
                         const float* __restrict__ bta, float* __restrict__ sc, int NHW) {
  int c = blockIdx.x*blockDim.x + threadIdx.x;
  if (c >= C) return;
  float S = 0.f, Q = 0.f;
  for (int s = 0; s < SLICES; ++s) { S += part[(c*SLICES+s)*2]; Q += part[(c*SLICES+s)*2+1]; }
  float m = S / NHW, v = Q / NHW - m*m;
  float inv = rsqrtf(v + 1e-5f);
  float a = g[c] * inv;
  sc[c*2] = a; sc[c*2+1] = bta[c] - m*a;
}

template<int C,int HW>
__global__ void bn_apply(float* __restrict__ x, const float* __restrict__ sc, int total) {
  int idx = blockIdx.x*blockDim.x + threadIdx.x;
  if (idx >= total) return;
  int c = (idx / HW) % C;
  float v = x[idx]*sc[c*2] + sc[c*2+1];
  x[idx] = v > 0.f ? v : 0.f;
}

// ---------------- squash primary caps in place (groups of 12 in flat layout) ----------------
__global__ void squash_pc(float* __restrict__ pc, int ncaps) {
  int i = blockIdx.x*blockDim.x + threadIdx.x;
  if (i >= ncaps) return;
  float* p = pc + (size_t)i*12;
  float v[12]; float s = 0.f;
  #pragma unroll
  for (int d = 0; d < 12; ++d) { v[d] = p[d]; s += v[d]*v[d]; }
  float sc = s / ((1.f + s)*sqrtf(s + 1e-6f));
  #pragma unroll
  for (int d = 0; d < 12; ++d) p[d] = v[d]*sc;
}

// ---------------- uu gather: index-permutation of squashed pc ----------------
__global__ void uu_gather(const float* __restrict__ sq, float* __restrict__ uu, int B) {
  int idx = blockIdx.x*blockDim.x + threadIdx.x;
  int total = B*49*144*12;
  if (idx >= total) return;
  int ii = idx % 12; int t0 = idx / 12;
  int kk = t0 % 144; t0 /= 144;
  int tt = t0 % 49;  int b = t0 / 49;
  int f = tt*1728 + kk*12 + ii;
  int c = f / 441; int r = f - c*441;
  int k = r / 49;  int sp = r - k*49;
  int y = sp / 7, x = sp - y*7;
  int iy = y + k/3 - 1, ix = x + (k%3) - 1;
  float val = 0.f;
  if (iy >= 0 && iy < 7 && ix >= 0 && ix < 7)
    val = sq[((size_t)(b*192 + c)*7 + iy)*7 + ix];
  uu[idx] = val;
}

// ---------------- ConvCaps einsum: per-k GEMM tile, bf16 u_hat output ----------------
__global__ void cc_einsum(const float* __restrict__ uu, const float* __restrict__ wcc,
                          __hip_bfloat16* __restrict__ uhat, int row0, int nrows) {
  int k  = blockIdx.x;
  int m0 = blockIdx.y * 64;
  __shared__ float A[64][12];
  int o = threadIdx.x;                       // 0..191
  for (int e = threadIdx.x; e < 64*12; e += 192) {
    int m = e / 12, ii = e % 12;
    int row = m0 + m;
    A[m][ii] = (row < nrows) ? uu[((size_t)(row0+row)*144 + k)*12 + ii] : 0.f;
  }
  __syncthreads();
  float w[12];
  #pragma unroll
  for (int ii = 0; ii < 12; ++ii) w[ii] = wcc[((size_t)k*192 + o)*12 + ii];
  int mmax = nrows - m0; if (mmax > 64) mmax = 64;
  for (int m = 0; m < mmax; ++m) {
    float acc = 0.f;
    #pragma unroll
    for (int ii = 0; ii < 12; ++ii) acc = fmaf(w[ii], A[m][ii], acc);
    uhat[((size_t)(m0+m)*144 + k)*192 + o] = __float2bfloat16(acc);
  }
}

// ---------------- ConvCaps routing: u_hat tile resident in LDS, 3 iterations ----------------
__global__ __launch_bounds__(512,1) void cc_route(const __hip_bfloat16* __restrict__ uhat,
                                                  float* __restrict__ u2, int bBase) {
  int row = blockIdx.x;          // 0..783 within chunk (b_local*49 + t)
  __shared__ __align__(16) __hip_bfloat16 uh[144*192];
  __shared__ float blog[144*16];
  __shared__ float cc[144*16];
  __shared__ float sv[2][192];
  __shared__ float scl[16];
  int tid = threadIdx.x;
  const uint4* src = (const uint4*)(uhat + (size_t)row*144*192);
  uint4* dst = (uint4*)uh;
  for (int i = tid; i < 3456; i += 512) dst[i] = src[i];       // 55 KB copy
  for (int i = tid; i < 2304; i += 512) blog[i] = 0.f;
  __syncthreads();
  for (int r = 0; r < 3; ++r) {
    if (tid < 144) {
      float mx = -1e30f;
      #pragma unroll
      for (int o = 0; o < 16; ++o) mx = fmaxf(mx, blog[tid*16+o]);
      float e[16]; float ssum = 0.f;
      #pragma unroll
      for (int o = 0; o < 16; ++o) { e[o] = __expf(blog[tid*16+o]-mx); ssum += e[o]; }
      float inv = 1.f/ssum;
      #pragma unroll
      for (int o = 0; o < 16; ++o) cc[tid*16+o] = e[o]*inv;
    }
    __syncthreads();
    if (tid < 384) {
      int o = tid % 192, half = tid / 192;
      float acc = 0.f;
      for (int k = half*72; k < half*72+72; ++k)
        acc = fmaf(cc[k*16 + o/12], __bfloat162float(uh[k*192+o]), acc);
      sv[half][o] = acc;
    }
    __syncthreads();
    if (tid < 192) sv[0][tid] += sv[1][tid];
    __syncthreads();
    if (tid < 16) {
      float s = 0.f;
      #pragma unroll
      for (int d = 0; d < 12; ++d) { float v = sv[0][tid*12+d]; s += v*v; }
      scl[tid] = s / ((1.f + s)*sqrtf(s + 1e-6f));
    }
    __syncthreads();
    if (tid < 192) sv[0][tid] *= scl[tid/12];
    __syncthreads();
    if (r < 2) {
      for (int p = tid; p < 2304; p += 512) {
        int k = p >> 4, oc = p & 15;
        float dot = 0.f;
        #pragma unroll
        for (int d = 0; d < 12; ++d)
          dot = fmaf(sv[0][oc*12+d], __bfloat162float(uh[k*192+oc*12+d]), dot);
        blog[p] += dot;
      }
      __syncthreads();
    }
  }
  if (tid < 192) u2[((size_t)bBase*49 + row)*192 + tid] = sv[0][tid];
}

// ---------------- Class caps einsum ----------------
__global__ void class_einsum(const float* __restrict__ u2, const float* __restrict__ wcl,
                             float* __restrict__ uhat2, int B) {
  int n = blockIdx.x;
  __shared__ float u2l[64][12];
  int tid = threadIdx.x;
  for (int e = tid; e < 64*12; e += 320) {
    int b = e / 12, i = e % 12;
    u2l[b][i] = u2[(size_t)b*9408 + n*12 + i];
  }
  __syncthreads();
  int od = tid % 160, bh = tid / 160;
  int o = od >> 4, d = od & 15;
  float w[12];
  #pragma unroll
  for (int i = 0; i < 12; ++i) w[i] = wcl[(size_t)n*1920 + o*192 + d*12 + i];
  for (int b = bh*32; b < bh*32+32; ++b) {
    float acc = 0.f;
    #pragma unroll
    for (int i = 0; i < 12; ++i) acc = fmaf(w[i], u2l[b][i], acc);
    uhat2[((size_t)b*784 + n)*160 + od] = acc;
  }
}

__global__ void fill_zero(float* __restrict__ p, int n) {
  int i = blockIdx.x*blockDim.x + threadIdx.x;
  if (i < n) p[i] = 0.f;
}

__global__ void class_softmax(const float* __restrict__ b2l, float* __restrict__ c2, int total) {
  int i = blockIdx.x*blockDim.x + threadIdx.x;
  if (i >= total) return;
  const float* p = b2l + (size_t)i*10;
  float mx = -1e30f;
  #pragma unroll
  for (int o = 0; o < 10; ++o) mx = fmaxf(mx, p[o]);
  float e[10]; float s = 0.f;
  #pragma unroll
  for (int o = 0; o < 10; ++o) { e[o] = __expf(p[o]-mx); s += e[o]; }
  float inv = 1.f/s;
  float* q = c2 + (size_t)i*10;
  #pragma unroll
  for (int o = 0; o < 10; ++o) q[o] = e[o]*inv;
}

__global__ void class_s(const float* __restrict__ c2, const float* __restrict__ uhat2,
                        float* __restrict__ vout, int B) {
  int b = blockIdx.x / 10, o = blockIdx.x % 10;
  int d = threadIdx.x & 15, sl = threadIdx.x >> 4;
  float acc = 0.f;
  for (int n = sl; n < 784; n += 16)
    acc = fmaf(c2[((size_t)b*784+n)*10+o], uhat2[((size_t)b*784+n)*160 + o*16 + d], acc);
  __shared__ float red[16][17];
  __shared__ float sd[16];
  red[sl][d] = acc;
  __syncthreads();
  if (threadIdx.x < 16) {
    float s = 0.f;
    #pragma unroll
    for (int i = 0; i < 16; ++i) s += red[i][threadIdx.x];
    sd[threadIdx.x] = s;
  }
  __syncthreads();
  if (threadIdx.x < 16) {
    float nrm = 0.f;
    #pragma unroll
    for (int i = 0; i < 16; ++i) nrm += sd[i]*sd[i];
    float sc = nrm / ((1.f + nrm)*sqrtf(nrm + 1e-6f));
    vout[((size_t)b*10+o)*16 + threadIdx.x] = sd[threadIdx.x]*sc;
  }
}

__global__ void class_bupd(const float* __restrict__ vv, const float* __restrict__ uhat2,
                           float* __restrict__ b2l, int total) {
  int i = blockIdx.x*blockDim.x + threadIdx.x;
  if (i >= total) return;
  int o = i % 10; int bn = i / 10; int b = bn / 784;
  const float* up = uhat2 + (size_t)bn*160 + o*16;
  const float* vp = vv + ((size_t)b*10+o)*16;
  float dot = 0.f;
  #pragma unroll
  for (int d = 0; d < 16; ++d) dot = fmaf(vp[d], up[d], dot);
  b2l[i] += dot;
}

// ---------------- host launch ----------------
extern "C" void kernel_launch(void* const* d_in, const int* in_sizes, int n_in,
                              void* d_out, int out_size, void* d_ws, size_t ws_size,
                              hipStream_t stream) {
  const float* images = (const float*)d_in[0];
  const float* w1  = (const float*)d_in[1];
  const float* g1  = (const float*)d_in[2];
  const float* b1  = (const float*)d_in[3];
  const float* w2  = (const float*)d_in[4];
  const float* g2  = (const float*)d_in[5];
  const float* b2  = (const float*)d_in[6];
  const float* w3  = (const float*)d_in[7];
  const float* g3  = (const float*)d_in[8];
  const float* b3  = (const float*)d_in[9];
  const float* wp  = (const float*)d_in[10];
  const float* bp  = (const float*)d_in[11];
  const float* wcc = (const float*)d_in[12];
  const float* wcl = (const float*)d_in[13];
  float* out = (float*)d_out;
  float* ws  = (float*)d_ws;

  float* t1    = ws + 0;            // 3,145,728
  float* t2    = ws + 3145728;      // 1,572,864
  float* t3    = ws + 4718592;      // 3,145,728
  float* pc    = ws + 7864320;      //   602,112
  float* uu    = ws + 8466432;      // 5,419,008
  float* u2b   = ws + 13885440;     //   602,112
  float* uh2   = ws + 14487552;     // 8,028,160
  float* b2l   = ws + 22515712;     //   501,760
  float* c2    = ws + 23017472;     //   501,760
  float* v2    = ws + 23519232;     //    10,240
  float* spart = ws + 23529472;     //     3,072
  float* ssc   = ws + 23532544;     //       384
  __hip_bfloat16* uhc = (__hip_bfloat16*)(ws + 23532928);  // 21,676,032 bf16

  const int B = 64;

  // conv1 + BN + ReLU (32x32, 3->48) — direct (K=27, cheap)
  conv_direct<3,48,32,32,32,32,1,1,false><<<12288,256,0,stream>>>(images, w1, nullptr, t1, B);
  bn_partial<48,1024,8><<<48*8,256,0,stream>>>(t1, spart, B);
  bn_final<48,8><<<1,256,0,stream>>>(spart, g1, b1, ssc, 65536);
  bn_apply<48,1024><<<12288,256,0,stream>>>(t1, ssc, 3145728);
  // conv2 + BN + ReLU (32->16, 48->96, stride 2) — implicit GEMM: M=96(2x48), N=256(4x64), K=432
  conv_gemm<48,32,32,16,16,2,1,3,16,false><<<dim3(2,4,64),256,0,stream>>>(t1, w2, nullptr, t2, 96);
  bn_partial<96,256,8><<<96*8,256,0,stream>>>(t2, spart, B);
  bn_final<96,8><<<1,256,0,stream>>>(spart, g2, b2, ssc, 16384);
  bn_apply<96,256><<<6144,256,0,stream>>>(t2, ssc, 1572864);
  // conv3 + BN + ReLU (16x16, 96->192) — M=192(3x64), N=256(4x64), K=864
  conv_gemm<96,16,16,16,16,1,1,4,32,false><<<dim3(3,4,64),256,0,stream>>>(t2, w3, nullptr, t3, 192);
  bn_partial<192,256,8><<<192*8,256,0,stream>>>(t3, spart, B);
  bn_final<192,8><<<1,256,0,stream>>>(spart, g3, b3, ssc, 16384);
  bn_apply<192,256><<<12288,256,0,stream>>>(t3, ssc, 3145728);
  // primary caps conv (16->7, 192->192, s2 p0) + bias — M=192(3x64), N=49(1x64), K=1728
  conv_gemm<192,16,16,7,7,2,0,4,32,true><<<dim3(3,1,64),256,0,stream>>>(t3, wp, bp, pc, 192);
  squash_pc<<<196,256,0,stream>>>(pc, 50176);
  // uu gather (B,49,144,12)
  uu_gather<<<21168,256,0,stream>>>(pc, uu, B);
  // ConvCaps einsum + fused in-LDS routing, chunked over b (4 x 16 images)
  for (int cb = 0; cb < 4; ++cb) {
    cc_einsum<<<dim3(144,13),192,0,stream>>>(uu, wcc, uhc, cb*784, 784);
    cc_route<<<784,512,0,stream>>>(uhc, u2b, cb*16);
  }
  // Class caps einsum
  class_einsum<<<784,320,0,stream>>>(u2b, wcl, uh2, B);
  // Class routing (3 iterations)
  fill_zero<<<1960,256,0,stream>>>(b2l, 501760);
  for (int r = 0; r < 3; ++r) {
    class_softmax<<<196,256,0,stream>>>(b2l, c2, 50176);
    class_s<<<640,256,0,stream>>>(c2, uh2, (r == 2) ? out : v2, B);
    if (r < 2) class_bupd<<<1960,256,0,stream>>>(v2, uh2, b2l, 501760);
  }
  (void)in_sizes; (void)n_in; (void)out_size; (void)ws_size;
}

// Round 3
// 645.193 us; speedup vs baseline: 3.7449x; 1.3357x over previous
//
#include <hip/hip_runtime.h>
#include <hip/hip_bf16.h>

// ---------------- direct convolution (kept only for conv1, CI=3) ----------------
template<int CI,int CO,int HI,int WI,int HO,int WO,int STR,int PAD,bool BIAS>
__global__ void conv_direct(const float* __restrict__ in, const float* __restrict__ w,
                            const float* __restrict__ bias, float* __restrict__ out, int B) {
  int idx = blockIdx.x*blockDim.x + threadIdx.x;
  int total = B*CO*HO*WO;
  if (idx >= total) return;
  int wo = idx % WO; int t = idx / WO;
  int ho = t % HO;   t /= HO;
  int co = t % CO;   int b = t / CO;
  float acc = BIAS ? bias[co] : 0.f;
  const float* wp = w + co*CI*9;
  const float* ip = in + (size_t)b*CI*HI*WI;
  int hi0 = ho*STR - PAD, wi0 = wo*STR - PAD;
  for (int ci = 0; ci < CI; ++ci) {
    const float* ic = ip + ci*HI*WI;
    const float* wc = wp + ci*9;
    #pragma unroll
    for (int ki = 0; ki < 3; ++ki) {
      int hi = hi0 + ki;
      if (hi < 0 || hi >= HI) continue;
      #pragma unroll
      for (int kj = 0; kj < 3; ++kj) {
        int wi = wi0 + kj;
        if (wi < 0 || wi >= WI) continue;
        acc = fmaf(ic[hi*WI + wi], wc[ki*3+kj], acc);
      }
    }
  }
  out[idx] = acc;
}

// ---------------- weight transpose: w[CO][K] -> wT[K][CO] ----------------
__global__ void transpose_w(const float* __restrict__ w, float* __restrict__ wT, int CO, int K) {
  int i = blockIdx.x*256 + threadIdx.x;
  if (i >= CO*K) return;
  int k = i % K, co = i / K;
  wT[(size_t)k*CO + co] = w[i];
}

// ---------------- batched-N split-K implicit-GEMM conv ----------------
// M = CO, N = B*HO*WO, K = CI*9. block 256 = 16x16, micro 4x4, tile 64x64.
// A = wT[K][CO] (coalesced stage), B = im2col gather with optional fused BN+ReLU.
// SPLITK>1: writes partials part[ks][co][n]; else writes out[b][co][sp].
template<int CI,int HI,int WI,int HO,int WO,int STR,int PAD,int KC,int SPLITK,bool FUSE_BN>
__global__ __launch_bounds__(256) void conv_gemm2(const float* __restrict__ in,
                                                  const float* __restrict__ wT,
                                                  const float* __restrict__ bnsc,
                                                  float* __restrict__ out, int CO, int B) {
  constexpr int MT = 64, NT = 64, K = CI*9, NSP = HO*WO;
  constexpr int KCH = K / SPLITK;
  static_assert(KCH % KC == 0, "KC must divide K/SPLITK");
  const int m0 = blockIdx.x*MT, n0 = blockIdx.y*NT, ks = blockIdx.z;
  const int NTOT = B*NSP;
  __shared__ float As[KC][MT];
  __shared__ float Bs[KC][NT];
  int tid = threadIdx.x, tx = tid & 15, ty = tid >> 4;
  float acc[4][4];
  #pragma unroll
  for (int r = 0; r < 4; ++r)
    #pragma unroll
    for (int c = 0; c < 4; ++c) acc[r][c] = 0.f;
  for (int kc = ks*KCH; kc < (ks+1)*KCH; kc += KC) {
    // stage A: coalesced rows of wT
    #pragma unroll
    for (int e = tid; e < MT*KC; e += 256) {
      int m = e & 63, k = e >> 6;
      int mg = m0 + m;
      As[k][m] = (mg < CO) ? wT[(size_t)(kc+k)*CO + mg] : 0.f;
    }
    // stage B: im2col gather (+ fused BN affine + ReLU of the previous layer)
    #pragma unroll
    for (int e = tid; e < NT*KC; e += 256) {
      int n = e & 63, k = e >> 6;
      int kg = kc + k;
      int ci = kg / 9, tap = kg % 9;
      int nn = n0 + n;
      int b = nn / NSP, sp = nn % NSP;
      int ho = sp / WO, wo = sp % WO;
      int hi = ho*STR - PAD + tap/3, wi = wo*STR - PAD + tap%3;
      float v = 0.f;
      if (hi >= 0 && hi < HI && wi >= 0 && wi < WI) {
        v = in[((size_t)(b*CI + ci)*HI + hi)*WI + wi];
        if (FUSE_BN) {
          v = fmaf(v, bnsc[ci*2], bnsc[ci*2+1]);
          v = v > 0.f ? v : 0.f;
        }
      }
      Bs[k][n] = v;
    }
    __syncthreads();
    #pragma unroll
    for (int k = 0; k < KC; ++k) {
      float4 a4 = *(const float4*)&As[k][ty*4];
      float4 b4 = *(const float4*)&Bs[k][tx*4];
      acc[0][0] = fmaf(a4.x, b4.x, acc[0][0]); acc[0][1] = fmaf(a4.x, b4.y, acc[0][1]);
      acc[0][2] = fmaf(a4.x, b4.z, acc[0][2]); acc[0][3] = fmaf(a4.x, b4.w, acc[0][3]);
      acc[1][0] = fmaf(a4.y, b4.x, acc[1][0]); acc[1][1] = fmaf(a4.y, b4.y, acc[1][1]);
      acc[1][2] = fmaf(a4.y, b4.z, acc[1][2]); acc[1][3] = fmaf(a4.y, b4.w, acc[1][3]);
      acc[2][0] = fmaf(a4.z, b4.x, acc[2][0]); acc[2][1] = fmaf(a4.z, b4.y, acc[2][1]);
      acc[2][2] = fmaf(a4.z, b4.z, acc[2][2]); acc[2][3] = fmaf(a4.z, b4.w, acc[2][3]);
      acc[3][0] = fmaf(a4.w, b4.x, acc[3][0]); acc[3][1] = fmaf(a4.w, b4.y, acc[3][1]);
      acc[3][2] = fmaf(a4.w, b4.z, acc[3][2]); acc[3][3] = fmaf(a4.w, b4.w, acc[3][3]);
    }
    __syncthreads();
  }
  if (SPLITK > 1) {
    #pragma unroll
    for (int r = 0; r < 4; ++r) {
      int co = m0 + ty*4 + r;
      if (co >= CO) continue;
      #pragma unroll
      for (int c = 0; c < 4; ++c) {
        int n = n0 + tx*4 + c;
        out[((size_t)(ks*CO + co))*NTOT + n] = acc[r][c];
      }
    }
  } else {
    #pragma unroll
    for (int r = 0; r < 4; ++r) {
      int co = m0 + ty*4 + r;
      if (co >= CO) continue;
      #pragma unroll
      for (int c = 0; c < 4; ++c) {
        int n = n0 + tx*4 + c;
        int b = n / NSP, sp = n % NSP;
        out[((size_t)b*CO + co)*NSP + sp] = acc[r][c];
      }
    }
  }
}

// ---------------- split-K reduce (+ optional bias), [ks][co][n] -> [b][co][sp] ----------------
template<int CO,int NSP,int SPLITK,bool BIAS>
__global__ void splitk_reduce(const float* __restrict__ part, const float* __restrict__ bias,
                              float* __restrict__ out, int B) {
  int i = blockIdx.x*256 + threadIdx.x;
  int NTOT = B*NSP;
  if (i >= CO*NTOT) return;
  int co = i / NTOT, n = i % NTOT;
  float s = 0.f;
  #pragma unroll
  for (int ks = 0; ks < SPLITK; ++ks) s += part[(size_t)(ks*CO + co)*NTOT + n];
  if (BIAS) s += bias[co];
  int b = n / NSP, sp = n % NSP;
  out[((size_t)b*CO + co)*NSP + sp] = s;
}

// ---------------- BN training-mode stats (deterministic two-level) ----------------
template<int C,int HW,int SLICES>
__global__ void bn_partial(const float* __restrict__ x, float* __restrict__ part, int B) {
  int c = blockIdx.x / SLICES, s = blockIdx.x % SLICES;
  int bpp = B / SLICES;
  float sum = 0.f, sq = 0.f;
  for (int b = s*bpp; b < (s+1)*bpp; ++b) {
    const float* p = x + ((size_t)b*C + c)*HW;
    for (int i = threadIdx.x; i < HW; i += blockDim.x) {
      float v = p[i]; sum += v; sq += v*v;
    }
  }
  #pragma unroll
  for (int off = 32; off; off >>= 1) {
    sum += __shfl_down(sum, off, 64);
    sq  += __shfl_down(sq,  off, 64);
  }
  __shared__ float ls[2][4];
  int lane = threadIdx.x & 63, wv = threadIdx.x >> 6;
  if (lane == 0) { ls[0][wv] = sum; ls[1][wv] = sq; }
  __syncthreads();
  if (threadIdx.x == 0) {
    float S = 0.f, Q = 0.f;
    #pragma unroll
    for (int i = 0; i < 4; ++i) { S += ls[0][i]; Q += ls[1][i]; }
    part[(c*SLICES+s)*2+0] = S; part[(c*SLICES+s)*2+1] = Q;
  }
}

template<int C,int SLICES>
__global__ void bn_final(const float* __restrict__ part, const float* __restrict__ g,
                         const float* __restrict__ bta, float* __restrict__ sc, int NHW) {
  int c = blockIdx.x*blockDim.x + threadIdx.x;
  if (c >= C) return;
  float S = 0.f, Q = 0.f;
  for (int s = 0; s < SLICES; ++s) { S += part[(c*SLICES+s)*2]; Q += part[(c*SLICES+s)*2+1]; }
  float m = S / NHW, v = Q / NHW - m*m;
  float inv = rsqrtf(v + 1e-5f);
  float a = g[c] * inv;
  sc[c*2] = a; sc[c*2+1] = bta[c] - m*a;
}

// ---------------- squash primary caps in place (groups of 12 in flat layout) ----------------
__global__ void squash_pc(float* __restrict__ pc, int ncaps) {
  int i = blockIdx.x*blockDim.x + threadIdx.x;
  if (i >= ncaps) return;
  float* p = pc + (size_t)i*12;
  float v[12]; float s = 0.f;
  #pragma unroll
  for (int d = 0; d < 12; ++d) { v[d] = p[d]; s += v[d]*v[d]; }
  float sc = s / ((1.f + s)*sqrtf(s + 1e-6f));
  #pragma unroll
  for (int d = 0; d < 12; ++d) p[d] = v[d]*sc;
}

// ---------------- uu gather: index-permutation of squashed pc ----------------
__global__ void uu_gather(const float* __restrict__ sq, float* __restrict__ uu, int B) {
  int idx = blockIdx.x*blockDim.x + threadIdx.x;
  int total = B*49*144*12;
  if (idx >= total) return;
  int ii = idx % 12; int t0 = idx / 12;
  int kk = t0 % 144; t0 /= 144;
  int tt = t0 % 49;  int b = t0 / 49;
  int f = tt*1728 + kk*12 + ii;
  int c = f / 441; int r = f - c*441;
  int k = r / 49;  int sp = r - k*49;
  int y = sp / 7, x = sp - y*7;
  int iy = y + k/3 - 1, ix = x + (k%3) - 1;
  float val = 0.f;
  if (iy >= 0 && iy < 7 && ix >= 0 && ix < 7)
    val = sq[((size_t)(b*192 + c)*7 + iy)*7 + ix];
  uu[idx] = val;
}

// ---------------- ConvCaps einsum: per-k GEMM tile, bf16 u_hat output ----------------
__global__ void cc_einsum(const float* __restrict__ uu, const float* __restrict__ wcc,
                          __hip_bfloat16* __restrict__ uhat, int row0, int nrows) {
  int k  = blockIdx.x;
  int m0 = blockIdx.y * 64;
  __shared__ float A[64][12];
  int o = threadIdx.x;                       // 0..191
  for (int e = threadIdx.x; e < 64*12; e += 192) {
    int m = e / 12, ii = e % 12;
    int row = m0 + m;
    A[m][ii] = (row < nrows) ? uu[((size_t)(row0+row)*144 + k)*12 + ii] : 0.f;
  }
  __syncthreads();
  float w[12];
  #pragma unroll
  for (int ii = 0; ii < 12; ++ii) w[ii] = wcc[((size_t)k*192 + o)*12 + ii];
  int mmax = nrows - m0; if (mmax > 64) mmax = 64;
  for (int m = 0; m < mmax; ++m) {
    float acc = 0.f;
    #pragma unroll
    for (int ii = 0; ii < 12; ++ii) acc = fmaf(w[ii], A[m][ii], acc);
    uhat[((size_t)(m0+m)*144 + k)*192 + o] = __float2bfloat16(acc);
  }
}

// ---------------- ConvCaps routing: u_hat tile resident in LDS, 3 iterations ----------------
__global__ __launch_bounds__(512,1) void cc_route(const __hip_bfloat16* __restrict__ uhat,
                                                  float* __restrict__ u2, int bBase) {
  int row = blockIdx.x;          // 0..783 within chunk (b_local*49 + t)
  __shared__ __align__(16) __hip_bfloat16 uh[144*192];
  __shared__ float blog[144*16];
  __shared__ float cc[144*16];
  __shared__ float sv[2][192];
  __shared__ float scl[16];
  int tid = threadIdx.x;
  const uint4* src = (const uint4*)(uhat + (size_t)row*144*192);
  uint4* dst = (uint4*)uh;
  for (int i = tid; i < 3456; i += 512) dst[i] = src[i];       // 55 KB copy
  for (int i = tid; i < 2304; i += 512) blog[i] = 0.f;
  __syncthreads();
  for (int r = 0; r < 3; ++r) {
    if (tid < 144) {
      float mx = -1e30f;
      #pragma unroll
      for (int o = 0; o < 16; ++o) mx = fmaxf(mx, blog[tid*16+o]);
      float e[16]; float ssum = 0.f;
      #pragma unroll
      for (int o = 0; o < 16; ++o) { e[o] = __expf(blog[tid*16+o]-mx); ssum += e[o]; }
      float inv = 1.f/ssum;
      #pragma unroll
      for (int o = 0; o < 16; ++o) cc[tid*16+o] = e[o]*inv;
    }
    __syncthreads();
    if (tid < 384) {
      int o = tid % 192, half = tid / 192;
      float acc = 0.f;
      for (int k = half*72; k < half*72+72; ++k)
        acc = fmaf(cc[k*16 + o/12], __bfloat162float(uh[k*192+o]), acc);
      sv[half][o] = acc;
    }
    __syncthreads();
    if (tid < 192) sv[0][tid] += sv[1][tid];
    __syncthreads();
    if (tid < 16) {
      float s = 0.f;
      #pragma unroll
      for (int d = 0; d < 12; ++d) { float v = sv[0][tid*12+d]; s += v*v; }
      scl[tid] = s / ((1.f + s)*sqrtf(s + 1e-6f));
    }
    __syncthreads();
    if (tid < 192) sv[0][tid] *= scl[tid/12];
    __syncthreads();
    if (r < 2) {
      for (int p = tid; p < 2304; p += 512) {
        int k = p >> 4, oc = p & 15;
        float dot = 0.f;
        #pragma unroll
        for (int d = 0; d < 12; ++d)
          dot = fmaf(sv[0][oc*12+d], __bfloat162float(uh[k*192+oc*12+d]), dot);
        blog[p] += dot;
      }
      __syncthreads();
    }
  }
  if (tid < 192) u2[((size_t)bBase*49 + row)*192 + tid] = sv[0][tid];
}

// ---------------- Class caps einsum ----------------
__global__ void class_einsum(const float* __restrict__ u2, const float* __restrict__ wcl,
                             float* __restrict__ uhat2, int B) {
  int n = blockIdx.x;
  __shared__ float u2l[64][12];
  int tid = threadIdx.x;
  for (int e = tid; e < 64*12; e += 320) {
    int b = e / 12, i = e % 12;
    u2l[b][i] = u2[(size_t)b*9408 + n*12 + i];
  }
  __syncthreads();
  int od = tid % 160, bh = tid / 160;
  int o = od >> 4, d = od & 15;
  float w[12];
  #pragma unroll
  for (int i = 0; i < 12; ++i) w[i] = wcl[(size_t)n*1920 + o*192 + d*12 + i];
  for (int b = bh*32; b < bh*32+32; ++b) {
    float acc = 0.f;
    #pragma unroll
    for (int i = 0; i < 12; ++i) acc = fmaf(w[i], u2l[b][i], acc);
    uhat2[((size_t)b*784 + n)*160 + od] = acc;
  }
}

__global__ void fill_zero(float* __restrict__ p, int n) {
  int i = blockIdx.x*blockDim.x + threadIdx.x;
  if (i < n) p[i] = 0.f;
}

__global__ void class_softmax(const float* __restrict__ b2l, float* __restrict__ c2, int total) {
  int i = blockIdx.x*blockDim.x + threadIdx.x;
  if (i >= total) return;
  const float* p = b2l + (size_t)i*10;
  float mx = -1e30f;
  #pragma unroll
  for (int o = 0; o < 10; ++o) mx = fmaxf(mx, p[o]);
  float e[10]; float s = 0.f;
  #pragma unroll
  for (int o = 0; o < 10; ++o) { e[o] = __expf(p[o]-mx); s += e[o]; }
  float inv = 1.f/s;
  float* q = c2 + (size_t)i*10;
  #pragma unroll
  for (int o = 0; o < 10; ++o) q[o] = e[o]*inv;
}

__global__ void class_s(const float* __restrict__ c2, const float* __restrict__ uhat2,
                        float* __restrict__ vout, int B) {
  int b = blockIdx.x / 10, o = blockIdx.x % 10;
  int d = threadIdx.x & 15, sl = threadIdx.x >> 4;
  float acc = 0.f;
  for (int n = sl; n < 784; n += 16)
    acc = fmaf(c2[((size_t)b*784+n)*10+o], uhat2[((size_t)b*784+n)*160 + o*16 + d], acc);
  __shared__ float red[16][17];
  __shared__ float sd[16];
  red[sl][d] = acc;
  __syncthreads();
  if (threadIdx.x < 16) {
    float s = 0.f;
    #pragma unroll
    for (int i = 0; i < 16; ++i) s += red[i][threadIdx.x];
    sd[threadIdx.x] = s;
  }
  __syncthreads();
  if (threadIdx.x < 16) {
    float nrm = 0.f;
    #pragma unroll
    for (int i = 0; i < 16; ++i) nrm += sd[i]*sd[i];
    float sc = nrm / ((1.f + nrm)*sqrtf(nrm + 1e-6f));
    vout[((size_t)b*10+o)*16 + threadIdx.x] = sd[threadIdx.x]*sc;
  }
}

__global__ void class_bupd(const float* __restrict__ vv, const float* __restrict__ uhat2,
                           float* __restrict__ b2l, int total) {
  int i = blockIdx.x*blockDim.x + threadIdx.x;
  if (i >= total) return;
  int o = i % 10; int bn = i / 10; int b = bn / 784;
  const float* up = uhat2 + (size_t)bn*160 + o*16;
  const float* vp = vv + ((size_t)b*10+o)*16;
  float dot = 0.f;
  #pragma unroll
  for (int d = 0; d < 16; ++d) dot = fmaf(vp[d], up[d], dot);
  b2l[i] += dot;
}

// ---------------- host launch ----------------
extern "C" void kernel_launch(void* const* d_in, const int* in_sizes, int n_in,
                              void* d_out, int out_size, void* d_ws, size_t ws_size,
                              hipStream_t stream) {
  const float* images = (const float*)d_in[0];
  const float* w1  = (const float*)d_in[1];
  const float* g1  = (const float*)d_in[2];
  const float* b1  = (const float*)d_in[3];
  const float* w2  = (const float*)d_in[4];
  const float* g2  = (const float*)d_in[5];
  const float* b2  = (const float*)d_in[6];
  const float* w3  = (const float*)d_in[7];
  const float* g3  = (const float*)d_in[8];
  const float* b3  = (const float*)d_in[9];
  const float* wp  = (const float*)d_in[10];
  const float* bp  = (const float*)d_in[11];
  const float* wcc = (const float*)d_in[12];
  const float* wcl = (const float*)d_in[13];
  float* out = (float*)d_out;
  float* ws  = (float*)d_ws;

  // persistent regions (float offsets)
  float* t1    = ws + 0;            // 3,145,728
  float* t2    = ws + 3145728;      // 1,572,864
  float* t3    = ws + 4718592;      // 3,145,728
  float* pc    = ws + 7864320;      //   602,112
  float* uu    = ws + 8466432;      // 5,419,008
  float* u2b   = ws + 13885440;     //   602,112
  float* uh2   = ws + 14487552;     // 8,028,160
  float* b2l   = ws + 22515712;     //   501,760
  float* c2    = ws + 23017472;     //   501,760
  float* v2    = ws + 23519232;     //    10,240
  float* spart = ws + 23529472;     //     3,072
  float* ssc1  = ws + 23532544;     //        96
  float* ssc2  = ws + 23532640;     //       192
  float* ssc3  = ws + 23532832;     //       384
  __hip_bfloat16* uhc = (__hip_bfloat16*)(ws + 23533312);  // 21,676,032 bf16

  // transient overlays (dead regions at time of use)
  float* wT2   = uu + 0;            //  41,472  (dead until uu_gather)
  float* wT3   = uu + 41472;        // 165,888
  float* wTp   = uu + 207360;       // 331,776
  float* part2 = uu + 539136;       // 3,145,728 (2x96x16384) — conv2 split-K partials
  float* partp = ws + 0;            // 3,612,672 (6x192x3136) — t1/t2 dead by primary conv

  const int B = 64;

  // weight transposes (tiny)
  transpose_w<<<(96*432+255)/256,256,0,stream>>>(w2, wT2, 96, 432);
  transpose_w<<<(192*864+255)/256,256,0,stream>>>(w3, wT3, 192, 864);
  transpose_w<<<(192*1728+255)/256,256,0,stream>>>(wp, wTp, 192, 1728);

  // conv1 (32x32, 3->48) direct; BN1 stats only (affine fused into conv2 gather)
  conv_direct<3,48,32,32,32,32,1,1,false><<<12288,256,0,stream>>>(images, w1, nullptr, t1, B);
  bn_partial<48,1024,8><<<48*8,256,0,stream>>>(t1, spart, B);
  bn_final<48,8><<<1,256,0,stream>>>(spart, g1, b1, ssc1, 65536);
  // conv2 (32->16, 48->96, s2 p1), fused BN1, split-K=2
  conv_gemm2<48,32,32,16,16,2,1,24,2,true><<<dim3(2,256,2),256,0,stream>>>(t1, wT2, ssc1, part2, 96, B);
  splitk_reduce<96,256,2,false><<<6144,256,0,stream>>>(part2, nullptr, t2, B);
  bn_partial<96,256,8><<<96*8,256,0,stream>>>(t2, spart, B);
  bn_final<96,8><<<1,256,0,stream>>>(spart, g2, b2, ssc2, 16384);
  // conv3 (16x16, 96->192, s1 p1), fused BN2
  conv_gemm2<96,16,16,16,16,1,1,32,1,true><<<dim3(3,256,1),256,0,stream>>>(t2, wT3, ssc2, t3, 192, B);
  bn_partial<192,256,8><<<192*8,256,0,stream>>>(t3, spart, B);
  bn_final<192,8><<<1,256,0,stream>>>(spart, g3, b3, ssc3, 16384);
  // primary caps conv (16->7, 192->192, s2 p0), fused BN3, split-K=6; bias in reduce
  conv_gemm2<192,16,16,7,7,2,0,32,6,true><<<dim3(3,49,6),256,0,stream>>>(t3, wTp, ssc3, partp, 192, B);
  splitk_reduce<192,49,6,true><<<2352,256,0,stream>>>(partp, bp, pc, B);
  squash_pc<<<196,256,0,stream>>>(pc, 50176);
  // uu gather (B,49,144,12) — overlays dead by now
  uu_gather<<<21168,256,0,stream>>>(pc, uu, B);
  // ConvCaps einsum + fused in-LDS routing, chunked over b (4 x 16 images)
  for (int cb = 0; cb < 4; ++cb) {
    cc_einsum<<<dim3(144,13),192,0,stream>>>(uu, wcc, uhc, cb*784, 784);
    cc_route<<<784,512,0,stream>>>(uhc, u2b, cb*16);
  }
  // Class caps einsum
  class_einsum<<<784,320,0,stream>>>(u2b, wcl, uh2, B);
  // Class routing (3 iterations)
  fill_zero<<<1960,256,0,stream>>>(b2l, 501760);
  for (int r = 0; r < 3; ++r) {
    class_softmax<<<196,256,0,stream>>>(b2l, c2, 50176);
    class_s<<<640,256,0,stream>>>(c2, uh2, (r == 2) ? out : v2, B);
    if (r < 2) class_bupd<<<1960,256,0,stream>>>(v2, uh2, b2l, 501760);
  }
  (void)in_sizes; (void)n_in; (void)out_size; (void)ws_size;
}

// Round 4
// 561.409 us; speedup vs baseline: 4.3038x; 1.1492x over previous
//
#include <hip/hip_runtime.h>
#include <hip/hip_bf16.h>

typedef __attribute__((ext_vector_type(8))) short short8v;
typedef __attribute__((ext_vector_type(16))) float f32x16;

__device__ __forceinline__ unsigned short f2bf(float v) {
  unsigned u = __float_as_uint(v);
  unsigned r = u + 0x7fffu + ((u >> 16) & 1u);
  return (unsigned short)(r >> 16);
}
__device__ __forceinline__ float bf2f(unsigned short h) {
  return __uint_as_float(((unsigned)h) << 16);
}

// ---------------- direct convolution (conv1 only, CI=3) ----------------
template<int CI,int CO,int HI,int WI,int HO,int WO,int STR,int PAD,bool BIAS>
__global__ void conv_direct(const float* __restrict__ in, const float* __restrict__ w,
                            const float* __restrict__ bias, float* __restrict__ out, int B) {
  int idx = blockIdx.x*blockDim.x + threadIdx.x;
  int total = B*CO*HO*WO;
  if (idx >= total) return;
  int wo = idx % WO; int t = idx / WO;
  int ho = t % HO;   t /= HO;
  int co = t % CO;   int b = t / CO;
  float acc = BIAS ? bias[co] : 0.f;
  const float* wp = w + co*CI*9;
  const float* ip = in + (size_t)b*CI*HI*WI;
  int hi0 = ho*STR - PAD, wi0 = wo*STR - PAD;
  for (int ci = 0; ci < CI; ++ci) {
    const float* ic = ip + ci*HI*WI;
    const float* wc = wp + ci*9;
    #pragma unroll
    for (int ki = 0; ki < 3; ++ki) {
      int hi = hi0 + ki;
      if (hi < 0 || hi >= HI) continue;
      #pragma unroll
      for (int kj = 0; kj < 3; ++kj) {
        int wi = wi0 + kj;
        if (wi < 0 || wi >= WI) continue;
        acc = fmaf(ic[hi*WI + wi], wc[ki*3+kj], acc);
      }
    }
  }
  out[idx] = acc;
}

// ---------------- weight split+reorder: w[CO][CI][9] -> wh/wl [CO][tap][CI] bf16 ----------------
__global__ void split_w(const float* __restrict__ w, unsigned short* __restrict__ wh,
                        unsigned short* __restrict__ wl, int CO, int CI) {
  int K = CI*9;
  int i = blockIdx.x*256 + threadIdx.x;
  if (i >= CO*K) return;
  int co = i / K, rem = i % K, tap = rem / CI, ci = rem % CI;
  float v = w[(co*CI + ci)*9 + tap];
  unsigned short h = f2bf(v);
  wh[i] = h;
  wl[i] = f2bf(v - bf2f(h));
}

// ---------------- BN affine + ReLU + split to padded NHWC bf16 hi/lo ----------------
template<int C,int H,int W,int P>
__global__ void bn_split_nhwc(const float* __restrict__ in, const float* __restrict__ sc,
                              unsigned short* __restrict__ xh, unsigned short* __restrict__ xl) {
  int b = blockIdx.x / H, h = blockIdx.x % H;
  constexpr int HP = H + 2*P, WP = W + 2*P;
  for (int e = threadIdx.x; e < W*C; e += 256) {
    int w = e / C, c = e % C;
    float v = in[((size_t)(b*C + c)*H + h)*W + w];
    v = fmaf(v, sc[c*2], sc[c*2+1]);
    v = v > 0.f ? v : 0.f;
    unsigned short hh = f2bf(v);
    size_t o = ((size_t)(b*HP + h + P)*WP + (w + P))*C + c;
    xh[o] = hh;
    xl[o] = f2bf(v - bf2f(hh));
  }
}

// ---------------- MFMA implicit-GEMM conv, split-2 bf16 (hi/lo), NHWC padded input ----------------
// M=CO (tile 128), N=B*HO*WO (tile 256), K=9*CI ordered (tap,ci). 4 waves 2x2, wave tile 64x128
// of 32x32x16 MFMA. Writes split-K partials part[ks][co][n].
template<int CI,int HIP,int WIP,int HO,int WO,int STR,int SPLITK>
__global__ __launch_bounds__(256,2) void conv_mfma(
    const unsigned short* __restrict__ xh, const unsigned short* __restrict__ xl,
    const unsigned short* __restrict__ wh, const unsigned short* __restrict__ wl,
    float* __restrict__ part, int CO, int B) {
  constexpr int K = CI*9, NSP = HO*WO, KCH = K/SPLITK;
  const int NTOT = B*NSP;
  const int m0 = blockIdx.x*128, n0 = blockIdx.y*256, ks = blockIdx.z;
  __shared__ __align__(16) unsigned short Ah[128][40];
  __shared__ __align__(16) unsigned short Al[128][40];
  __shared__ __align__(16) unsigned short Bh[256][40];
  __shared__ __align__(16) unsigned short Bl[256][40];
  const int tid = threadIdx.x, lane = tid & 63, wid = tid >> 6;
  const int wm = wid >> 1, wn = wid & 1;
  // B-gather setup (thread owns one n column)
  int nn = n0 + tid; if (nn > NTOT-1) nn = NTOT-1;
  int bb = nn / NSP, sp = nn % NSP;
  int ho = sp / WO, wo = sp % WO;
  const size_t ibase = ((size_t)bb*HIP + ho*STR)*WIP + wo*STR;
  f32x16 acc[2][4];
  #pragma unroll
  for (int i = 0; i < 2; ++i)
    #pragma unroll
    for (int j = 0; j < 4; ++j) acc[i][j] = (f32x16)0.0f;
  const int kBeg = ks*KCH, kEnd = kBeg + KCH;
  for (int kc = kBeg; kc < kEnd; kc += 32) {
    const int kLim = (kEnd - kc) < 32 ? (kEnd - kc) : 32;   // multiple of 8
    // stage A (weights)
    #pragma unroll
    for (int i = 0; i < 2; ++i) {
      int e = tid + i*256;
      int m = e >> 2, k0 = (e & 3)*8;
      short8v vh = (short8v)(short)0, vl = (short8v)(short)0;
      if (m0 + m < CO && k0 < kLim) {
        size_t off = (size_t)(m0+m)*K + kc + k0;
        vh = *(const short8v*)(wh + off);
        vl = *(const short8v*)(wl + off);
      }
      *(short8v*)&Ah[m][k0] = vh;
      *(short8v*)&Al[m][k0] = vl;
    }
    // stage B (im2col gather from padded NHWC, ci-contiguous)
    #pragma unroll
    for (int i = 0; i < 4; ++i) {
      int k0 = i*8, kg = kc + k0;
      short8v vh = (short8v)(short)0, vl = (short8v)(short)0;
      if (k0 < kLim) {
        int tap = kg / CI, ci0 = kg - tap*CI;
        int dh = tap / 3, dw = tap - dh*3;
        size_t off = (ibase + (size_t)dh*WIP + dw)*CI + ci0;
        vh = *(const short8v*)(xh + off);
        vl = *(const short8v*)(xl + off);
      }
      *(short8v*)&Bh[tid][k0] = vh;
      *(short8v*)&Bl[tid][k0] = vl;
    }
    __syncthreads();
    #pragma unroll
    for (int kst = 0; kst < 2; ++kst) {
      const int kb = kst*16 + 8*(lane >> 5);
      const int ar = wm*64 + (lane & 31);
      short8v a0h = *(const short8v*)&Ah[ar][kb];
      short8v a0l = *(const short8v*)&Al[ar][kb];
      short8v a1h = *(const short8v*)&Ah[ar+32][kb];
      short8v a1l = *(const short8v*)&Al[ar+32][kb];
      const int br = wn*128 + (lane & 31);
      #pragma unroll
      for (int ns = 0; ns < 4; ++ns) {
        short8v bh = *(const short8v*)&Bh[br + ns*32][kb];
        short8v bl = *(const short8v*)&Bl[br + ns*32][kb];
        acc[0][ns] = __builtin_amdgcn_mfma_f32_32x32x16_bf16(a0h, bh, acc[0][ns], 0, 0, 0);
        acc[0][ns] = __builtin_amdgcn_mfma_f32_32x32x16_bf16(a0h, bl, acc[0][ns], 0, 0, 0);
        acc[0][ns] = __builtin_amdgcn_mfma_f32_32x32x16_bf16(a0l, bh, acc[0][ns], 0, 0, 0);
        acc[1][ns] = __builtin_amdgcn_mfma_f32_32x32x16_bf16(a1h, bh, acc[1][ns], 0, 0, 0);
        acc[1][ns] = __builtin_amdgcn_mfma_f32_32x32x16_bf16(a1h, bl, acc[1][ns], 0, 0, 0);
        acc[1][ns] = __builtin_amdgcn_mfma_f32_32x32x16_bf16(a1l, bh, acc[1][ns], 0, 0, 0);
      }
    }
    __syncthreads();
  }
  // store partials: C/D layout col=lane&31, row=(r&3)+8*(r>>2)+4*(lane>>5)
  #pragma unroll
  for (int ms = 0; ms < 2; ++ms)
    #pragma unroll
    for (int ns = 0; ns < 4; ++ns)
      #pragma unroll
      for (int r = 0; r < 16; ++r) {
        int row = (r & 3) + 8*(r >> 2) + 4*(lane >> 5);
        int m = m0 + wm*64 + ms*32 + row;
        int n = n0 + wn*128 + ns*32 + (lane & 31);
        if (m < CO && n < NTOT)
          part[((size_t)ks*CO + m)*NTOT + n] = acc[ms][ns][r];
      }
}

// ---------------- split-K reduce (+ optional bias), [ks][co][n] -> [b][co][sp] ----------------
template<int CO,int NSP,int SPLITK,bool BIAS>
__global__ void splitk_reduce(const float* __restrict__ part, const float* __restrict__ bias,
                              float* __restrict__ out, int B) {
  int i = blockIdx.x*256 + threadIdx.x;
  int NTOT = B*NSP;
  if (i >= CO*NTOT) return;
  int co = i / NTOT, n = i % NTOT;
  float s = 0.f;
  #pragma unroll
  for (int ks = 0; ks < SPLITK; ++ks) s += part[(size_t)(ks*CO + co)*NTOT + n];
  if (BIAS) s += bias[co];
  int b = n / NSP, sp = n % NSP;
  out[((size_t)b*CO + co)*NSP + sp] = s;
}

// ---------------- BN training-mode stats (deterministic two-level) ----------------
template<int C,int HW,int SLICES>
__global__ void bn_partial(const float* __restrict__ x, float* __restrict__ part, int B) {
  int c = blockIdx.x / SLICES, s = blockIdx.x % SLICES;
  int bpp = B / SLICES;
  float sum = 0.f, sq = 0.f;
  for (int b = s*bpp; b < (s+1)*bpp; ++b) {
    const float* p = x + ((size_t)b*C + c)*HW;
    for (int i = threadIdx.x; i < HW; i += blockDim.x) {
      float v = p[i]; sum += v; sq += v*v;
    }
  }
  #pragma unroll
  for (int off = 32; off; off >>= 1) {
    sum += __shfl_down(sum, off, 64);
    sq  += __shfl_down(sq,  off, 64);
  }
  __shared__ float ls[2][4];
  int lane = threadIdx.x & 63, wv = threadIdx.x >> 6;
  if (lane == 0) { ls[0][wv] = sum; ls[1][wv] = sq; }
  __syncthreads();
  if (threadIdx.x == 0) {
    float S = 0.f, Q = 0.f;
    #pragma unroll
    for (int i = 0; i < 4; ++i) { S += ls[0][i]; Q += ls[1][i]; }
    part[(c*SLICES+s)*2+0] = S; part[(c*SLICES+s)*2+1] = Q;
  }
}

template<int C,int SLICES>
__global__ void bn_final(const float* __restrict__ part, const float* __restrict__ g,
                         const float* __restrict__ bta, float* __restrict__ sc, int NHW) {
  int c = blockIdx.x*blockDim.x + threadIdx.x;
  if (c >= C) return;
  float S = 0.f, Q = 0.f;
  for (int s = 0; s < SLICES; ++s) { S += part[(c*SLICES+s)*2]; Q += part[(c*SLICES+s)*2+1]; }
  float m = S / NHW, v = Q / NHW - m*m;
  float inv = rsqrtf(v + 1e-5f);
  float a = g[c] * inv;
  sc[c*2] = a; sc[c*2+1] = bta[c] - m*a;
}

// ---------------- squash primary caps in place ----------------
__global__ void squash_pc(float* __restrict__ pc, int ncaps) {
  int i = blockIdx.x*blockDim.x + threadIdx.x;
  if (i >= ncaps) return;
  float* p = pc + (size_t)i*12;
  float v[12]; float s = 0.f;
  #pragma unroll
  for (int d = 0; d < 12; ++d) { v[d] = p[d]; s += v[d]*v[d]; }
  float sc = s / ((1.f + s)*sqrtf(s + 1e-6f));
  #pragma unroll
  for (int d = 0; d < 12; ++d) p[d] = v[d]*sc;
}

// ---------------- uu gather: index-permutation of squashed pc ----------------
__global__ void uu_gather(const float* __restrict__ sq, float* __restrict__ uu, int B) {
  int idx = blockIdx.x*blockDim.x + threadIdx.x;
  int total = B*49*144*12;
  if (idx >= total) return;
  int ii = idx % 12; int t0 = idx / 12;
  int kk = t0 % 144; t0 /= 144;
  int tt = t0 % 49;  int b = t0 / 49;
  int f = tt*1728 + kk*12 + ii;
  int c = f / 441; int r = f - c*441;
  int k = r / 49;  int sp = r - k*49;
  int y = sp / 7, x = sp - y*7;
  int iy = y + k/3 - 1, ix = x + (k%3) - 1;
  float val = 0.f;
  if (iy >= 0 && iy < 7 && ix >= 0 && ix < 7)
    val = sq[((size_t)(b*192 + c)*7 + iy)*7 + ix];
  uu[idx] = val;
}

// ---------------- ConvCaps einsum: per-k GEMM tile, bf16 u_hat output ----------------
__global__ void cc_einsum(const float* __restrict__ uu, const float* __restrict__ wcc,
                          __hip_bfloat16* __restrict__ uhat, int row0, int nrows) {
  int k  = blockIdx.x;
  int m0 = blockIdx.y * 64;
  __shared__ float A[64][12];
  int o = threadIdx.x;                       // 0..191
  for (int e = threadIdx.x; e < 64*12; e += 192) {
    int m = e / 12, ii = e % 12;
    int row = m0 + m;
    A[m][ii] = (row < nrows) ? uu[((size_t)(row0+row)*144 + k)*12 + ii] : 0.f;
  }
  __syncthreads();
  float w[12];
  #pragma unroll
  for (int ii = 0; ii < 12; ++ii) w[ii] = wcc[((size_t)k*192 + o)*12 + ii];
  int mmax = nrows - m0; if (mmax > 64) mmax = 64;
  for (int m = 0; m < mmax; ++m) {
    float acc = 0.f;
    #pragma unroll
    for (int ii = 0; ii < 12; ++ii) acc = fmaf(w[ii], A[m][ii], acc);
    uhat[((size_t)(m0+m)*144 + k)*192 + o] = __float2bfloat16(acc);
  }
}

// ---------------- ConvCaps routing: u_hat tile resident in LDS, 3 iterations ----------------
__global__ __launch_bounds__(512,1) void cc_route(const __hip_bfloat16* __restrict__ uhat,
                                                  float* __restrict__ u2, int bBase) {
  int row = blockIdx.x;
  __shared__ __align__(16) __hip_bfloat16 uh[144*192];
  __shared__ float blog[144*16];
  __shared__ float cc[144*16];
  __shared__ float sv[2][192];
  __shared__ float scl[16];
  int tid = threadIdx.x;
  const uint4* src = (const uint4*)(uhat + (size_t)row*144*192);
  uint4* dst = (uint4*)uh;
  for (int i = tid; i < 3456; i += 512) dst[i] = src[i];
  for (int i = tid; i < 2304; i += 512) blog[i] = 0.f;
  __syncthreads();
  for (int r = 0; r < 3; ++r) {
    if (tid < 144) {
      float mx = -1e30f;
      #pragma unroll
      for (int o = 0; o < 16; ++o) mx = fmaxf(mx, blog[tid*16+o]);
      float e[16]; float ssum = 0.f;
      #pragma unroll
      for (int o = 0; o < 16; ++o) { e[o] = __expf(blog[tid*16+o]-mx); ssum += e[o]; }
      float inv = 1.f/ssum;
      #pragma unroll
      for (int o = 0; o < 16; ++o) cc[tid*16+o] = e[o]*inv;
    }
    __syncthreads();
    if (tid < 384) {
      int o = tid % 192, half = tid / 192;
      float acc = 0.f;
      for (int k = half*72; k < half*72+72; ++k)
        acc = fmaf(cc[k*16 + o/12], __bfloat162float(uh[k*192+o]), acc);
      sv[half][o] = acc;
    }
    __syncthreads();
    if (tid < 192) sv[0][tid] += sv[1][tid];
    __syncthreads();
    if (tid < 16) {
      float s = 0.f;
      #pragma unroll
      for (int d = 0; d < 12; ++d) { float v = sv[0][tid*12+d]; s += v*v; }
      scl[tid] = s / ((1.f + s)*sqrtf(s + 1e-6f));
    }
    __syncthreads();
    if (tid < 192) sv[0][tid] *= scl[tid/12];
    __syncthreads();
    if (r < 2) {
      for (int p = tid; p < 2304; p += 512) {
        int k = p >> 4, oc = p & 15;
        float dot = 0.f;
        #pragma unroll
        for (int d = 0; d < 12; ++d)
          dot = fmaf(sv[0][oc*12+d], __bfloat162float(uh[k*192+oc*12+d]), dot);
        blog[p] += dot;
      }
      __syncthreads();
    }
  }
  if (tid < 192) u2[((size_t)bBase*49 + row)*192 + tid] = sv[0][tid];
}

// ---------------- Class caps einsum ----------------
__global__ void class_einsum(const float* __restrict__ u2, const float* __restrict__ wcl,
                             float* __restrict__ uhat2, int B) {
  int n = blockIdx.x;
  __shared__ float u2l[64][12];
  int tid = threadIdx.x;
  for (int e = tid; e < 64*12; e += 320) {
    int b = e / 12, i = e % 12;
    u2l[b][i] = u2[(size_t)b*9408 + n*12 + i];
  }
  __syncthreads();
  int od = tid % 160, bh = tid / 160;
  int o = od >> 4, d = od & 15;
  float w[12];
  #pragma unroll
  for (int i = 0; i < 12; ++i) w[i] = wcl[(size_t)n*1920 + o*192 + d*12 + i];
  for (int b = bh*32; b < bh*32+32; ++b) {
    float acc = 0.f;
    #pragma unroll
    for (int i = 0; i < 12; ++i) acc = fmaf(w[i], u2l[b][i], acc);
    uhat2[((size_t)b*784 + n)*160 + od] = acc;
  }
}

__global__ void fill_zero(float* __restrict__ p, int n) {
  int i = blockIdx.x*blockDim.x + threadIdx.x;
  if (i < n) p[i] = 0.f;
}

__global__ void class_softmax(const float* __restrict__ b2l, float* __restrict__ c2, int total) {
  int i = blockIdx.x*blockDim.x + threadIdx.x;
  if (i >= total) return;
  const float* p = b2l + (size_t)i*10;
  float mx = -1e30f;
  #pragma unroll
  for (int o = 0; o < 10; ++o) mx = fmaxf(mx, p[o]);
  float e[10]; float s = 0.f;
  #pragma unroll
  for (int o = 0; o < 10; ++o) { e[o] = __expf(p[o]-mx); s += e[o]; }
  float inv = 1.f/s;
  float* q = c2 + (size_t)i*10;
  #pragma unroll
  for (int o = 0; o < 10; ++o) q[o] = e[o]*inv;
}

__global__ void class_s(const float* __restrict__ c2, const float* __restrict__ uhat2,
                        float* __restrict__ vout, int B) {
  int b = blockIdx.x / 10, o = blockIdx.x % 10;
  int d = threadIdx.x & 15, sl = threadIdx.x >> 4;
  float acc = 0.f;
  for (int n = sl; n < 784; n += 16)
    acc = fmaf(c2[((size_t)b*784+n)*10+o], uhat2[((size_t)b*784+n)*160 + o*16 + d], acc);
  __shared__ float red[16][17];
  __shared__ float sd[16];
  red[sl][d] = acc;
  __syncthreads();
  if (threadIdx.x < 16) {
    float s = 0.f;
    #pragma unroll
    for (int i = 0; i < 16; ++i) s += red[i][threadIdx.x];
    sd[threadIdx.x] = s;
  }
  __syncthreads();
  if (threadIdx.x < 16) {
    float nrm = 0.f;
    #pragma unroll
    for (int i = 0; i < 16; ++i) nrm += sd[i]*sd[i];
    float sc = nrm / ((1.f + nrm)*sqrtf(nrm + 1e-6f));
    vout[((size_t)b*10+o)*16 + threadIdx.x] = sd[threadIdx.x]*sc;
  }
}

__global__ void class_bupd(const float* __restrict__ vv, const float* __restrict__ uhat2,
                           float* __restrict__ b2l, int total) {
  int i = blockIdx.x*blockDim.x + threadIdx.x;
  if (i >= total) return;
  int o = i % 10; int bn = i / 10; int b = bn / 784;
  const float* up = uhat2 + (size_t)bn*160 + o*16;
  const float* vp = vv + ((size_t)b*10+o)*16;
  float dot = 0.f;
  #pragma unroll
  for (int d = 0; d < 16; ++d) dot = fmaf(vp[d], up[d], dot);
  b2l[i] += dot;
}

// ---------------- host launch ----------------
extern "C" void kernel_launch(void* const* d_in, const int* in_sizes, int n_in,
                              void* d_out, int out_size, void* d_ws, size_t ws_size,
                              hipStream_t stream) {
  const float* images = (const float*)d_in[0];
  const float* w1  = (const float*)d_in[1];
  const float* g1  = (const float*)d_in[2];
  const float* b1  = (const float*)d_in[3];
  const float* w2  = (const float*)d_in[4];
  const float* g2  = (const float*)d_in[5];
  const float* b2  = (const float*)d_in[6];
  const float* w3  = (const float*)d_in[7];
  const float* g3  = (const float*)d_in[8];
  const float* b3  = (const float*)d_in[9];
  const float* wp  = (const float*)d_in[10];
  const float* bp  = (const float*)d_in[11];
  const float* wcc = (const float*)d_in[12];
  const float* wcl = (const float*)d_in[13];
  float* out = (float*)d_out;
  float* ws  = (float*)d_ws;

  // persistent regions (float offsets)
  float* t1    = ws + 0;            // 3,145,728
  float* t2    = ws + 3145728;      // 1,572,864
  float* t3    = ws + 4718592;      // 3,145,728
  float* pc    = ws + 7864320;      //   602,112
  float* uu    = ws + 8466432;      // 5,419,008
  float* u2b   = ws + 13885440;     //   602,112
  float* uh2   = ws + 14487552;     // 8,028,160
  float* b2l   = ws + 22515712;     //   501,760
  float* c2    = ws + 23017472;     //   501,760
  float* v2    = ws + 23519232;     //    10,240
  float* spart = ws + 23529472;     //     3,072
  float* ssc1  = ws + 23532544;     //        96
  float* ssc2  = ws + 23532640;     //       192
  float* ssc3  = ws + 23532832;     //       384
  float* U     = ws + 23533312;     // arena, 10,838,016 f32 (uhc region)
  __hip_bfloat16* uhc = (__hip_bfloat16*)U;

  // split/reordered weights live in dead `uu` region (dead until uu_gather)
  unsigned short* wh2 = (unsigned short*)(uu + 0);
  unsigned short* wl2 = (unsigned short*)(uu + 20736);
  unsigned short* wh3 = (unsigned short*)(uu + 41472);
  unsigned short* wl3 = (unsigned short*)(uu + 124416);
  unsigned short* whp = (unsigned short*)(uu + 207360);
  unsigned short* wlp = (unsigned short*)(uu + 373248);

  // phase transients in the U arena (sequential reuse, all dead before cc_einsum)
  unsigned short* x2h = (unsigned short*)(U + 0);         // 3,551,232 ush
  unsigned short* x2l = (unsigned short*)(U + 1775616);
  float*          part2 = U + 3551232;                    // 3x96x16384 f32
  unsigned short* x3h = (unsigned short*)(U + 0);         // 1,990,656 ush
  unsigned short* x3l = (unsigned short*)(U + 995328);
  float*          part3 = U + 1990656;                    // 2x192x16384 f32
  unsigned short* xph = (unsigned short*)(U + 0);         // 3,145,728 ush
  unsigned short* xpl = (unsigned short*)(U + 1572864);
  float*          partp = U + 3145728;                    // 8x192x3136 f32

  const int B = 64;

  // weight splits
  split_w<<<(96*432+255)/256,256,0,stream>>>(w2, wh2, wl2, 96, 48);
  split_w<<<(192*864+255)/256,256,0,stream>>>(w3, wh3, wl3, 192, 96);
  split_w<<<(192*1728+255)/256,256,0,stream>>>(wp, whp, wlp, 192, 192);

  // conv1 (direct fp32) + BN1 stats
  conv_direct<3,48,32,32,32,32,1,1,false><<<12288,256,0,stream>>>(images, w1, nullptr, t1, B);
  bn_partial<48,1024,8><<<48*8,256,0,stream>>>(t1, spart, B);
  bn_final<48,8><<<1,256,0,stream>>>(spart, g1, b1, ssc1, 65536);

  // conv2: BN1+ReLU+split to padded NHWC, MFMA, reduce
  fill_zero<<<(3551232+255)/256,256,0,stream>>>(U, 3551232);   // x2h+x2l halo zeros
  bn_split_nhwc<48,32,32,1><<<64*32,256,0,stream>>>(t1, ssc1, x2h, x2l);
  conv_mfma<48,34,34,16,16,2,3><<<dim3(1,64,3),256,0,stream>>>(x2h, x2l, wh2, wl2, part2, 96, B);
  splitk_reduce<96,256,3,false><<<6144,256,0,stream>>>(part2, nullptr, t2, B);
  bn_partial<96,256,8><<<96*8,256,0,stream>>>(t2, spart, B);
  bn_final<96,8><<<1,256,0,stream>>>(spart, g2, b2, ssc2, 16384);

  // conv3
  fill_zero<<<(1990656+255)/256,256,0,stream>>>(U, 1990656);
  bn_split_nhwc<96,16,16,1><<<64*16,256,0,stream>>>(t2, ssc2, x3h, x3l);
  conv_mfma<96,18,18,16,16,1,2><<<dim3(2,64,2),256,0,stream>>>(x3h, x3l, wh3, wl3, part3, 192, B);
  splitk_reduce<192,256,2,false><<<12288,256,0,stream>>>(part3, nullptr, t3, B);
  bn_partial<192,256,8><<<192*8,256,0,stream>>>(t3, spart, B);
  bn_final<192,8><<<1,256,0,stream>>>(spart, g3, b3, ssc3, 16384);

  // primary caps conv (no pad), bias added in reduce; then squash
  bn_split_nhwc<192,16,16,0><<<64*16,256,0,stream>>>(t3, ssc3, xph, xpl);
  conv_mfma<192,16,16,7,7,2,8><<<dim3(2,13,8),256,0,stream>>>(xph, xpl, whp, wlp, partp, 192, B);
  splitk_reduce<192,49,8,true><<<2352,256,0,stream>>>(partp, bp, pc, B);
  squash_pc<<<196,256,0,stream>>>(pc, 50176);

  // uu gather (B,49,144,12) — uu overlay (weights) dead now
  uu_gather<<<21168,256,0,stream>>>(pc, uu, B);
  // ConvCaps einsum + fused in-LDS routing, chunked over b (4 x 16 images)
  for (int cb = 0; cb < 4; ++cb) {
    cc_einsum<<<dim3(144,13),192,0,stream>>>(uu, wcc, uhc, cb*784, 784);
    cc_route<<<784,512,0,stream>>>(uhc, u2b, cb*16);
  }
  // Class caps einsum + routing
  class_einsum<<<784,320,0,stream>>>(u2b, wcl, uh2, B);
  fill_zero<<<1960,256,0,stream>>>(b2l, 501760);
  for (int r = 0; r < 3; ++r) {
    class_softmax<<<196,256,0,stream>>>(b2l, c2, 50176);
    class_s<<<640,256,0,stream>>>(c2, uh2, (r == 2) ? out : v2, B);
    if (r < 2) class_bupd<<<1960,256,0,stream>>>(v2, uh2, b2l, 501760);
  }
  (void)in_sizes; (void)n_in; (void)out_size; (void)ws_size;
}

// Round 5
// 510.559 us; speedup vs baseline: 4.7324x; 1.0996x over previous
//
#include <hip/hip_runtime.h>
#include <hip/hip_bf16.h>

typedef __attribute__((ext_vector_type(4))) short short4v;
typedef __attribute__((ext_vector_type(8))) short short8v;
typedef __attribute__((ext_vector_type(16))) float f32x16;

union frag8 { short8v v8; struct { short4v lo, hi; } p; };

__device__ __forceinline__ unsigned short f2bf(float v) {
  unsigned u = __float_as_uint(v);
  unsigned r = u + 0x7fffu + ((u >> 16) & 1u);
  return (unsigned short)(r >> 16);
}
__device__ __forceinline__ float bf2f(unsigned short h) {
  return __uint_as_float(((unsigned)h) << 16);
}

// ---------------- direct convolution (conv1 only, CI=3) ----------------
template<int CI,int CO,int HI,int WI,int HO,int WO,int STR,int PAD,bool BIAS>
__global__ void conv_direct(const float* __restrict__ in, const float* __restrict__ w,
                            const float* __restrict__ bias, float* __restrict__ out, int B) {
  int idx = blockIdx.x*blockDim.x + threadIdx.x;
  int total = B*CO*HO*WO;
  if (idx >= total) return;
  int wo = idx % WO; int t = idx / WO;
  int ho = t % HO;   t /= HO;
  int co = t % CO;   int b = t / CO;
  float acc = BIAS ? bias[co] : 0.f;
  const float* wp = w + co*CI*9;
  const float* ip = in + (size_t)b*CI*HI*WI;
  int hi0 = ho*STR - PAD, wi0 = wo*STR - PAD;
  for (int ci = 0; ci < CI; ++ci) {
    const float* ic = ip + ci*HI*WI;
    const float* wc = wp + ci*9;
    #pragma unroll
    for (int ki = 0; ki < 3; ++ki) {
      int hi = hi0 + ki;
      if (hi < 0 || hi >= HI) continue;
      #pragma unroll
      for (int kj = 0; kj < 3; ++kj) {
        int wi = wi0 + kj;
        if (wi < 0 || wi >= WI) continue;
        acc = fmaf(ic[hi*WI + wi], wc[ki*3+kj], acc);
      }
    }
  }
  out[idx] = acc;
}

// ---------------- weight split+reorder: w[CO][CI][9] -> wh/wl [CO][tap][CI] bf16 ----------------
__global__ void split_w(const float* __restrict__ w, unsigned short* __restrict__ wh,
                        unsigned short* __restrict__ wl, int CO, int CI) {
  int K = CI*9;
  int i = blockIdx.x*256 + threadIdx.x;
  if (i >= CO*K) return;
  int co = i / K, rem = i % K, tap = rem / CI, ci = rem % CI;
  float v = w[(co*CI + ci)*9 + tap];
  unsigned short h = f2bf(v);
  wh[i] = h;
  wl[i] = f2bf(v - bf2f(h));
}

// ---------------- BN affine + ReLU + split to padded NHWC bf16 hi/lo ----------------
template<int C,int H,int W,int P>
__global__ void bn_split_nhwc(const float* __restrict__ in, const float* __restrict__ sc,
                              unsigned short* __restrict__ xh, unsigned short* __restrict__ xl) {
  int b = blockIdx.x / H, h = blockIdx.x % H;
  constexpr int HP = H + 2*P, WP = W + 2*P;
  for (int e = threadIdx.x; e < W*C; e += 256) {
    int w = e / C, c = e % C;
    float v = in[((size_t)(b*C + c)*H + h)*W + w];
    v = fmaf(v, sc[c*2], sc[c*2+1]);
    v = v > 0.f ? v : 0.f;
    unsigned short hh = f2bf(v);
    size_t o = ((size_t)(b*HP + h + P)*WP + (w + P))*C + c;
    xh[o] = hh;
    xl[o] = f2bf(v - bf2f(hh));
  }
}

// ---------------- MFMA implicit-GEMM conv, split-2 bf16 (hi/lo), NHWC padded input ----------------
// Block tile 64(M) x 128(N), 4 waves 2x2, wave tile 32x64 of 32x32x16 MFMA.
// LDS rows padded to 36 shorts (72 B -> 2-way banks, free); b64 fragment loads.
// Writes split-K partials part[ks][co][n].
template<int CI,int HIP,int WIP,int HO,int WO,int STR,int SPLITK>
__global__ __launch_bounds__(256,4) void conv_mfma(
    const unsigned short* __restrict__ xh, const unsigned short* __restrict__ xl,
    const unsigned short* __restrict__ wh, const unsigned short* __restrict__ wl,
    float* __restrict__ part, int CO, int B) {
  constexpr int K = CI*9, NSP = HO*WO, KCH = K/SPLITK, LDA = 36;
  const int NTOT = B*NSP;
  const int m0 = blockIdx.x*64, n0 = blockIdx.y*128, ks = blockIdx.z;
  __shared__ unsigned short Ah[64*LDA], Al[64*LDA], Bh[128*LDA], Bl[128*LDA];
  const int tid = threadIdx.x, lane = tid & 63, wid = tid >> 6;
  const int wm = wid >> 1, wn = wid & 1;
  // A staging: 1 fragment/thread
  const int arow = tid >> 2, ak0 = (tid & 3)*8;
  const bool aok = (m0 + arow) < CO;
  const size_t abase = (size_t)(m0 + arow)*K;
  // B staging: 2 fragments/thread
  int brow[2], bk0[2];
  size_t bbase[2];
  #pragma unroll
  for (int i = 0; i < 2; ++i) {
    int e = tid + i*256;
    brow[i] = e >> 2; bk0[i] = (e & 3)*8;
    int nn = n0 + brow[i]; if (nn > NTOT-1) nn = NTOT-1;
    int bb = nn / NSP, sp = nn % NSP;
    int ho = sp / WO, wo = sp % WO;
    bbase[i] = ((size_t)bb*HIP + ho*STR)*WIP + wo*STR;
  }
  f32x16 acc0 = (f32x16)0.f, acc1 = (f32x16)0.f;
  const int kBeg = ks*KCH, kEnd = kBeg + KCH;
  for (int kc = kBeg; kc < kEnd; kc += 32) {
    const int kLim = (kEnd - kc) < 32 ? (kEnd - kc) : 32;  // multiple of 8
    // stage A (weights, [co][tap*CI+ci] bf16)
    {
      frag8 vh, vl;
      vh.v8 = (short8v)(short)0; vl.v8 = (short8v)(short)0;
      if (aok && ak0 < kLim) {
        size_t off = abase + kc + ak0;
        vh.v8 = *(const short8v*)(wh + off);
        vl.v8 = *(const short8v*)(wl + off);
      }
      int lo_ = arow*LDA + ak0;
      *(short4v*)(Ah + lo_) = vh.p.lo; *(short4v*)(Ah + lo_ + 4) = vh.p.hi;
      *(short4v*)(Al + lo_) = vl.p.lo; *(short4v*)(Al + lo_ + 4) = vl.p.hi;
    }
    // stage B (im2col gather from padded NHWC, ci-contiguous)
    #pragma unroll
    for (int i = 0; i < 2; ++i) {
      frag8 vh, vl;
      vh.v8 = (short8v)(short)0; vl.v8 = (short8v)(short)0;
      if (bk0[i] < kLim) {
        int kg = kc + bk0[i];
        int tap = kg / CI, ci0 = kg - tap*CI;
        int dh = tap / 3, dw = tap - dh*3;
        size_t off = (bbase[i] + (size_t)dh*WIP + dw)*CI + ci0;
        vh.v8 = *(const short8v*)(xh + off);
        vl.v8 = *(const short8v*)(xl + off);
      }
      int lo_ = brow[i]*LDA + bk0[i];
      *(short4v*)(Bh + lo_) = vh.p.lo; *(short4v*)(Bh + lo_ + 4) = vh.p.hi;
      *(short4v*)(Bl + lo_) = vl.p.lo; *(short4v*)(Bl + lo_ + 4) = vl.p.hi;
    }
    __syncthreads();
    #pragma unroll
    for (int kst = 0; kst < 2; ++kst) {
      const int kb = kst*16 + 8*(lane >> 5);
      const int ar = wm*32 + (lane & 31);
      frag8 ah, al;
      { int o = ar*LDA + kb;
        ah.p.lo = *(const short4v*)(Ah + o); ah.p.hi = *(const short4v*)(Ah + o + 4);
        al.p.lo = *(const short4v*)(Al + o); al.p.hi = *(const short4v*)(Al + o + 4); }
      const int br = wn*64 + (lane & 31);
      frag8 bh0, bl0, bh1, bl1;
      { int o = br*LDA + kb;
        bh0.p.lo = *(const short4v*)(Bh + o); bh0.p.hi = *(const short4v*)(Bh + o + 4);
        bl0.p.lo = *(const short4v*)(Bl + o); bl0.p.hi = *(const short4v*)(Bl + o + 4); }
      { int o = (br+32)*LDA + kb;
        bh1.p.lo = *(const short4v*)(Bh + o); bh1.p.hi = *(const short4v*)(Bh + o + 4);
        bl1.p.lo = *(const short4v*)(Bl + o); bl1.p.hi = *(const short4v*)(Bl + o + 4); }
      acc0 = __builtin_amdgcn_mfma_f32_32x32x16_bf16(ah.v8, bh0.v8, acc0, 0, 0, 0);
      acc0 = __builtin_amdgcn_mfma_f32_32x32x16_bf16(ah.v8, bl0.v8, acc0, 0, 0, 0);
      acc0 = __builtin_amdgcn_mfma_f32_32x32x16_bf16(al.v8, bh0.v8, acc0, 0, 0, 0);
      acc1 = __builtin_amdgcn_mfma_f32_32x32x16_bf16(ah.v8, bh1.v8, acc1, 0, 0, 0);
      acc1 = __builtin_amdgcn_mfma_f32_32x32x16_bf16(ah.v8, bl1.v8, acc1, 0, 0, 0);
      acc1 = __builtin_amdgcn_mfma_f32_32x32x16_bf16(al.v8, bh1.v8, acc1, 0, 0, 0);
    }
    __syncthreads();
  }
  // store partials: C/D layout col=lane&31, row=(r&3)+8*(r>>2)+4*(lane>>5)
  #pragma unroll
  for (int ns = 0; ns < 2; ++ns) {
    f32x16 a = ns ? acc1 : acc0;
    #pragma unroll
    for (int r = 0; r < 16; ++r) {
      int row = (r & 3) + 8*(r >> 2) + 4*(lane >> 5);
      int m = m0 + wm*32 + row;
      int n = n0 + wn*64 + ns*32 + (lane & 31);
      if (m < CO && n < NTOT)
        part[((size_t)ks*CO + m)*NTOT + n] = a[r];
    }
  }
}

// ---------------- split-K reduce (+ optional bias), [ks][co][n] -> [b][co][sp] ----------------
template<int CO,int NSP,int SPLITK,bool BIAS>
__global__ void splitk_reduce(const float* __restrict__ part, const float* __restrict__ bias,
                              float* __restrict__ out, int B) {
  int i = blockIdx.x*256 + threadIdx.x;
  int NTOT = B*NSP;
  if (i >= CO*NTOT) return;
  int co = i / NTOT, n = i % NTOT;
  float s = 0.f;
  #pragma unroll
  for (int ks = 0; ks < SPLITK; ++ks) s += part[(size_t)(ks*CO + co)*NTOT + n];
  if (BIAS) s += bias[co];
  int b = n / NSP, sp = n % NSP;
  out[((size_t)b*CO + co)*NSP + sp] = s;
}

// ---------------- BN training-mode stats (deterministic two-level) ----------------
template<int C,int HW,int SLICES>
__global__ void bn_partial(const float* __restrict__ x, float* __restrict__ part, int B) {
  int c = blockIdx.x / SLICES, s = blockIdx.x % SLICES;
  int bpp = B / SLICES;
  float sum = 0.f, sq = 0.f;
  for (int b = s*bpp; b < (s+1)*bpp; ++b) {
    const float* p = x + ((size_t)b*C + c)*HW;
    for (int i = threadIdx.x; i < HW; i += blockDim.x) {
      float v = p[i]; sum += v; sq += v*v;
    }
  }
  #pragma unroll
  for (int off = 32; off; off >>= 1) {
    sum += __shfl_down(sum, off, 64);
    sq  += __shfl_down(sq,  off, 64);
  }
  __shared__ float ls[2][4];
  int lane = threadIdx.x & 63, wv = threadIdx.x >> 6;
  if (lane == 0) { ls[0][wv] = sum; ls[1][wv] = sq; }
  __syncthreads();
  if (threadIdx.x == 0) {
    float S = 0.f, Q = 0.f;
    #pragma unroll
    for (int i = 0; i < 4; ++i) { S += ls[0][i]; Q += ls[1][i]; }
    part[(c*SLICES+s)*2+0] = S; part[(c*SLICES+s)*2+1] = Q;
  }
}

template<int C,int SLICES>
__global__ void bn_final(const float* __restrict__ part, const float* __restrict__ g,
                         const float* __restrict__ bta, float* __restrict__ sc, int NHW) {
  int c = blockIdx.x*blockDim.x + threadIdx.x;
  if (c >= C) return;
  float S = 0.f, Q = 0.f;
  for (int s = 0; s < SLICES; ++s) { S += part[(c*SLICES+s)*2]; Q += part[(c*SLICES+s)*2+1]; }
  float m = S / NHW, v = Q / NHW - m*m;
  float inv = rsqrtf(v + 1e-5f);
  float a = g[c] * inv;
  sc[c*2] = a; sc[c*2+1] = bta[c] - m*a;
}

// ---------------- squash primary caps in place ----------------
__global__ void squash_pc(float* __restrict__ pc, int ncaps) {
  int i = blockIdx.x*blockDim.x + threadIdx.x;
  if (i >= ncaps) return;
  float* p = pc + (size_t)i*12;
  float v[12]; float s = 0.f;
  #pragma unroll
  for (int d = 0; d < 12; ++d) { v[d] = p[d]; s += v[d]*v[d]; }
  float sc = s / ((1.f + s)*sqrtf(s + 1e-6f));
  #pragma unroll
  for (int d = 0; d < 12; ++d) p[d] = v[d]*sc;
}

// ---------------- uu gather: index-permutation of squashed pc ----------------
__global__ void uu_gather(const float* __restrict__ sq, float* __restrict__ uu, int B) {
  int idx = blockIdx.x*blockDim.x + threadIdx.x;
  int total = B*49*144*12;
  if (idx >= total) return;
  int ii = idx % 12; int t0 = idx / 12;
  int kk = t0 % 144; t0 /= 144;
  int tt = t0 % 49;  int b = t0 / 49;
  int f = tt*1728 + kk*12 + ii;
  int c = f / 441; int r = f - c*441;
  int k = r / 49;  int sp = r - k*49;
  int y = sp / 7, x = sp - y*7;
  int iy = y + k/3 - 1, ix = x + (k%3) - 1;
  float val = 0.f;
  if (iy >= 0 && iy < 7 && ix >= 0 && ix < 7)
    val = sq[((size_t)(b*192 + c)*7 + iy)*7 + ix];
  uu[idx] = val;
}

// ---------------- ConvCaps einsum: per-k GEMM tile, bf16 u_hat output ----------------
__global__ void cc_einsum(const float* __restrict__ uu, const float* __restrict__ wcc,
                          __hip_bfloat16* __restrict__ uhat, int row0, int nrows) {
  int k  = blockIdx.x;
  int m0 = blockIdx.y * 64;
  __shared__ float A[64][12];
  int o = threadIdx.x;                       // 0..191
  for (int e = threadIdx.x; e < 64*12; e += 192) {
    int m = e / 12, ii = e % 12;
    int row = m0 + m;
    A[m][ii] = (row < nrows) ? uu[((size_t)(row0+row)*144 + k)*12 + ii] : 0.f;
  }
  __syncthreads();
  float w[12];
  #pragma unroll
  for (int ii = 0; ii < 12; ++ii) w[ii] = wcc[((size_t)k*192 + o)*12 + ii];
  int mmax = nrows - m0; if (mmax > 64) mmax = 64;
  for (int m = 0; m < mmax; ++m) {
    float acc = 0.f;
    #pragma unroll
    for (int ii = 0; ii < 12; ++ii) acc = fmaf(w[ii], A[m][ii], acc);
    uhat[((size_t)(m0+m)*144 + k)*192 + o] = __float2bfloat16(acc);
  }
}

// ---------------- ConvCaps routing: u_hat tile resident in LDS, 3 iterations ----------------
__global__ __launch_bounds__(512,1) void cc_route(const __hip_bfloat16* __restrict__ uhat,
                                                  float* __restrict__ u2, int bBase) {
  int row = blockIdx.x;
  __shared__ __align__(16) __hip_bfloat16 uh[144*192];
  __shared__ float blog[144*16];
  __shared__ float cc[144*16];
  __shared__ float sv[2][192];
  __shared__ float scl[16];
  int tid = threadIdx.x;
  const uint4* src = (const uint4*)(uhat + (size_t)row*144*192);
  uint4* dst = (uint4*)uh;
  for (int i = tid; i < 3456; i += 512) dst[i] = src[i];
  for (int i = tid; i < 2304; i += 512) blog[i] = 0.f;
  __syncthreads();
  for (int r = 0; r < 3; ++r) {
    if (tid < 144) {
      float mx = -1e30f;
      #pragma unroll
      for (int o = 0; o < 16; ++o) mx = fmaxf(mx, blog[tid*16+o]);
      float e[16]; float ssum = 0.f;
      #pragma unroll
      for (int o = 0; o < 16; ++o) { e[o] = __expf(blog[tid*16+o]-mx); ssum += e[o]; }
      float inv = 1.f/ssum;
      #pragma unroll
      for (int o = 0; o < 16; ++o) cc[tid*16+o] = e[o]*inv;
    }
    __syncthreads();
    if (tid < 384) {
      int o = tid % 192, half = tid / 192;
      float acc = 0.f;
      for (int k = half*72; k < half*72+72; ++k)
        acc = fmaf(cc[k*16 + o/12], __bfloat162float(uh[k*192+o]), acc);
      sv[half][o] = acc;
    }
    __syncthreads();
    if (tid < 192) sv[0][tid] += sv[1][tid];
    __syncthreads();
    if (tid < 16) {
      float s = 0.f;
      #pragma unroll
      for (int d = 0; d < 12; ++d) { float v = sv[0][tid*12+d]; s += v*v; }
      scl[tid] = s / ((1.f + s)*sqrtf(s + 1e-6f));
    }
    __syncthreads();
    if (tid < 192) sv[0][tid] *= scl[tid/12];
    __syncthreads();
    if (r < 2) {
      for (int p = tid; p < 2304; p += 512) {
        int k = p >> 4, oc = p & 15;
        float dot = 0.f;
        #pragma unroll
        for (int d = 0; d < 12; ++d)
          dot = fmaf(sv[0][oc*12+d], __bfloat162float(uh[k*192+oc*12+d]), dot);
        blog[p] += dot;
      }
      __syncthreads();
    }
  }
  if (tid < 192) u2[((size_t)bBase*49 + row)*192 + tid] = sv[0][tid];
}

// ---------------- Class caps einsum ----------------
__global__ void class_einsum(const float* __restrict__ u2, const float* __restrict__ wcl,
                             float* __restrict__ uhat2, int B) {
  int n = blockIdx.x;
  __shared__ float u2l[64][12];
  int tid = threadIdx.x;
  for (int e = tid; e < 64*12; e += 320) {
    int b = e / 12, i = e % 12;
    u2l[b][i] = u2[(size_t)b*9408 + n*12 + i];
  }
  __syncthreads();
  int od = tid % 160, bh = tid / 160;
  int o = od >> 4, d = od & 15;
  float w[12];
  #pragma unroll
  for (int i = 0; i < 12; ++i) w[i] = wcl[(size_t)n*1920 + o*192 + d*12 + i];
  for (int b = bh*32; b < bh*32+32; ++b) {
    float acc = 0.f;
    #pragma unroll
    for (int i = 0; i < 12; ++i) acc = fmaf(w[i], u2l[b][i], acc);
    uhat2[((size_t)b*784 + n)*160 + od] = acc;
  }
}

__global__ void fill_zero(float* __restrict__ p, int n) {
  int i = blockIdx.x*blockDim.x + threadIdx.x;
  if (i < n) p[i] = 0.f;
}

__global__ void class_softmax(const float* __restrict__ b2l, float* __restrict__ c2, int total) {
  int i = blockIdx.x*blockDim.x + threadIdx.x;
  if (i >= total) return;
  const float* p = b2l + (size_t)i*10;
  float mx = -1e30f;
  #pragma unroll
  for (int o = 0; o < 10; ++o) mx = fmaxf(mx, p[o]);
  float e[10]; float s = 0.f;
  #pragma unroll
  for (int o = 0; o < 10; ++o) { e[o] = __expf(p[o]-mx); s += e[o]; }
  float inv = 1.f/s;
  float* q = c2 + (size_t)i*10;
  #pragma unroll
  for (int o = 0; o < 10; ++o) q[o] = e[o]*inv;
}

__global__ void class_s(const float* __restrict__ c2, const float* __restrict__ uhat2,
                        float* __restrict__ vout, int B) {
  int b = blockIdx.x / 10, o = blockIdx.x % 10;
  int d = threadIdx.x & 15, sl = threadIdx.x >> 4;
  float acc = 0.f;
  for (int n = sl; n < 784; n += 16)
    acc = fmaf(c2[((size_t)b*784+n)*10+o], uhat2[((size_t)b*784+n)*160 + o*16 + d], acc);
  __shared__ float red[16][17];
  __shared__ float sd[16];
  red[sl][d] = acc;
  __syncthreads();
  if (threadIdx.x < 16) {
    float s = 0.f;
    #pragma unroll
    for (int i = 0; i < 16; ++i) s += red[i][threadIdx.x];
    sd[threadIdx.x] = s;
  }
  __syncthreads();
  if (threadIdx.x < 16) {
    float nrm = 0.f;
    #pragma unroll
    for (int i = 0; i < 16; ++i) nrm += sd[i]*sd[i];
    float sc = nrm / ((1.f + nrm)*sqrtf(nrm + 1e-6f));
    vout[((size_t)b*10+o)*16 + threadIdx.x] = sd[threadIdx.x]*sc;
  }
}

__global__ void class_bupd(const float* __restrict__ vv, const float* __restrict__ uhat2,
                           float* __restrict__ b2l, int total) {
  int i = blockIdx.x*blockDim.x + threadIdx.x;
  if (i >= total) return;
  int o = i % 10; int bn = i / 10; int b = bn / 784;
  const float* up = uhat2 + (size_t)bn*160 + o*16;
  const float* vp = vv + ((size_t)b*10+o)*16;
  float dot = 0.f;
  #pragma unroll
  for (int d = 0; d < 16; ++d) dot = fmaf(vp[d], up[d], dot);
  b2l[i] += dot;
}

// ---------------- host launch ----------------
extern "C" void kernel_launch(void* const* d_in, const int* in_sizes, int n_in,
                              void* d_out, int out_size, void* d_ws, size_t ws_size,
                              hipStream_t stream) {
  const float* images = (const float*)d_in[0];
  const float* w1  = (const float*)d_in[1];
  const float* g1  = (const float*)d_in[2];
  const float* b1  = (const float*)d_in[3];
  const float* w2  = (const float*)d_in[4];
  const float* g2  = (const float*)d_in[5];
  const float* b2  = (const float*)d_in[6];
  const float* w3  = (const float*)d_in[7];
  const float* g3  = (const float*)d_in[8];
  const float* b3  = (const float*)d_in[9];
  const float* wp  = (const float*)d_in[10];
  const float* bp  = (const float*)d_in[11];
  const float* wcc = (const float*)d_in[12];
  const float* wcl = (const float*)d_in[13];
  float* out = (float*)d_out;
  float* ws  = (float*)d_ws;

  // persistent regions (float offsets)
  float* t1    = ws + 0;            // 3,145,728
  float* t2    = ws + 3145728;      // 1,572,864
  float* t3    = ws + 4718592;      // 3,145,728
  float* pc    = ws + 7864320;      //   602,112
  float* uu    = ws + 8466432;      // 5,419,008
  float* u2b   = ws + 13885440;     //   602,112
  float* uh2   = ws + 14487552;     // 8,028,160
  float* b2l   = ws + 22515712;     //   501,760
  float* c2    = ws + 23017472;     //   501,760
  float* v2    = ws + 23519232;     //    10,240
  float* spart = ws + 23529472;     //     3,072
  float* ssc1  = ws + 23532544;     //        96
  float* ssc2  = ws + 23532640;     //       192
  float* ssc3  = ws + 23532832;     //       384
  float* U     = ws + 23533312;     // arena, 10,838,016 f32 (uhc region)
  __hip_bfloat16* uhc = (__hip_bfloat16*)U;

  // split/reordered weights live in dead `uu` region (dead until uu_gather)
  unsigned short* wh2 = (unsigned short*)(uu + 0);
  unsigned short* wl2 = (unsigned short*)(uu + 20736);
  unsigned short* wh3 = (unsigned short*)(uu + 41472);
  unsigned short* wl3 = (unsigned short*)(uu + 124416);
  unsigned short* whp = (unsigned short*)(uu + 207360);
  unsigned short* wlp = (unsigned short*)(uu + 373248);

  // phase transients in the U arena (sequential reuse, all dead before cc_einsum)
  unsigned short* x2h = (unsigned short*)(U + 0);         // 3,551,232 ush
  unsigned short* x2l = (unsigned short*)(U + 1775616);
  float*          part2 = U + 3551232;                    // 3x96x16384 f32
  unsigned short* x3h = (unsigned short*)(U + 0);         // 1,990,656 ush
  unsigned short* x3l = (unsigned short*)(U + 995328);
  float*          part3 = U + 1990656;                    // 2x192x16384 f32
  unsigned short* xph = (unsigned short*)(U + 0);         // 3,145,728 ush
  unsigned short* xpl = (unsigned short*)(U + 1572864);
  float*          partp = U + 3145728;                    // 8x192x3136 f32

  const int B = 64;

  // weight splits
  split_w<<<(96*432+255)/256,256,0,stream>>>(w2, wh2, wl2, 96, 48);
  split_w<<<(192*864+255)/256,256,0,stream>>>(w3, wh3, wl3, 192, 96);
  split_w<<<(192*1728+255)/256,256,0,stream>>>(wp, whp, wlp, 192, 192);

  // conv1 (direct fp32) + BN1 stats
  conv_direct<3,48,32,32,32,32,1,1,false><<<12288,256,0,stream>>>(images, w1, nullptr, t1, B);
  bn_partial<48,1024,8><<<48*8,256,0,stream>>>(t1, spart, B);
  bn_final<48,8><<<1,256,0,stream>>>(spart, g1, b1, ssc1, 65536);

  // conv2: BN1+ReLU+split to padded NHWC, MFMA, reduce
  fill_zero<<<(3551232+255)/256,256,0,stream>>>(U, 3551232);   // x2h+x2l halo zeros
  bn_split_nhwc<48,32,32,1><<<64*32,256,0,stream>>>(t1, ssc1, x2h, x2l);
  conv_mfma<48,34,34,16,16,2,3><<<dim3(2,128,3),256,0,stream>>>(x2h, x2l, wh2, wl2, part2, 96, B);
  splitk_reduce<96,256,3,false><<<6144,256,0,stream>>>(part2, nullptr, t2, B);
  bn_partial<96,256,8><<<96*8,256,0,stream>>>(t2, spart, B);
  bn_final<96,8><<<1,256,0,stream>>>(spart, g2, b2, ssc2, 16384);

  // conv3
  fill_zero<<<(1990656+255)/256,256,0,stream>>>(U, 1990656);
  bn_split_nhwc<96,16,16,1><<<64*16,256,0,stream>>>(t2, ssc2, x3h, x3l);
  conv_mfma<96,18,18,16,16,1,2><<<dim3(3,128,2),256,0,stream>>>(x3h, x3l, wh3, wl3, part3, 192, B);
  splitk_reduce<192,256,2,false><<<12288,256,0,stream>>>(part3, nullptr, t3, B);
  bn_partial<192,256,8><<<192*8,256,0,stream>>>(t3, spart, B);
  bn_final<192,8><<<1,256,0,stream>>>(spart, g3, b3, ssc3, 16384);

  // primary caps conv (no pad), bias added in reduce; then squash
  bn_split_nhwc<192,16,16,0><<<64*16,256,0,stream>>>(t3, ssc3, xph, xpl);
  conv_mfma<192,16,16,7,7,2,8><<<dim3(3,25,8),256,0,stream>>>(xph, xpl, whp, wlp, partp, 192, B);
  splitk_reduce<192,49,8,true><<<2352,256,0,stream>>>(partp, bp, pc, B);
  squash_pc<<<196,256,0,stream>>>(pc, 50176);

  // uu gather (B,49,144,12) — uu overlay (weights) dead now
  uu_gather<<<21168,256,0,stream>>>(pc, uu, B);
  // ConvCaps einsum + fused in-LDS routing, chunked over b (4 x 16 images)
  for (int cb = 0; cb < 4; ++cb) {
    cc_einsum<<<dim3(144,13),192,0,stream>>>(uu, wcc, uhc, cb*784, 784);
    cc_route<<<784,512,0,stream>>>(uhc, u2b, cb*16);
  }
  // Class caps einsum + routing
  class_einsum<<<784,320,0,stream>>>(u2b, wcl, uh2, B);
  fill_zero<<<1960,256,0,stream>>>(b2l, 501760);
  for (int r = 0; r < 3; ++r) {
    class_softmax<<<196,256,0,stream>>>(b2l, c2, 50176);
    class_s<<<640,256,0,stream>>>(c2, uh2, (r == 2) ? out : v2, B);
    if (r < 2) class_bupd<<<1960,256,0,stream>>>(v2, uh2, b2l, 501760);
  }
  (void)in_sizes; (void)n_in; (void)out_size; (void)ws_size;
}

// Round 6
// 507.883 us; speedup vs baseline: 4.7574x; 1.0053x over previous
//
#include <hip/hip_runtime.h>
#include <hip/hip_bf16.h>

typedef __attribute__((ext_vector_type(4))) short short4v;
typedef __attribute__((ext_vector_type(8))) short short8v;
typedef __attribute__((ext_vector_type(16))) float f32x16;

union frag8 { short8v v8; struct { short4v lo, hi; } p; };

__device__ __forceinline__ unsigned short f2bf(float v) {
  unsigned u = __float_as_uint(v);
  unsigned r = u + 0x7fffu + ((u >> 16) & 1u);
  return (unsigned short)(r >> 16);
}
__device__ __forceinline__ float bf2f(unsigned short h) {
  return __uint_as_float(((unsigned)h) << 16);
}

// ---------------- conv1: one block per (b,h), LDS input slab, weights in regs ----------------
__global__ __launch_bounds__(192) void conv1_fused(const float* __restrict__ images,
                                                   const float* __restrict__ w1,
                                                   float* __restrict__ out) {
  int b = blockIdx.x >> 5, h = blockIdx.x & 31;
  __shared__ __align__(16) float lin[3][3][36];   // [ci][ki][wi], wi = w+1, zero-padded
  int tid = threadIdx.x;
  for (int e = tid; e < 324; e += 192) {
    int ci = e / 108, rem = e % 108, ki = rem / 36, wi = rem % 36;
    int row = h + ki - 1, col = wi - 1;
    float v = 0.f;
    if (row >= 0 && row < 32 && col >= 0 && col < 32)
      v = images[((size_t)(b*3 + ci)*32 + row)*32 + col];
    lin[ci][ki][wi] = v;
  }
  int co = tid >> 2, ws = tid & 3;
  float wr[27];
  #pragma unroll
  for (int j = 0; j < 27; ++j) wr[j] = w1[co*27 + j];
  __syncthreads();
  float o[8];
  #pragma unroll
  for (int j = 0; j < 8; ++j) o[j] = 0.f;
  #pragma unroll
  for (int ci = 0; ci < 3; ++ci)
    #pragma unroll
    for (int ki = 0; ki < 3; ++ki) {
      float4 q0 = *(const float4*)&lin[ci][ki][ws*8];
      float4 q1 = *(const float4*)&lin[ci][ki][ws*8+4];
      float4 q2 = *(const float4*)&lin[ci][ki][ws*8+8];
      float r[12] = {q0.x,q0.y,q0.z,q0.w,q1.x,q1.y,q1.z,q1.w,q2.x,q2.y,q2.z,q2.w};
      #pragma unroll
      for (int kj = 0; kj < 3; ++kj) {
        float wv = wr[(ci*3+ki)*3+kj];
        #pragma unroll
        for (int j = 0; j < 8; ++j) o[j] = fmaf(r[j+kj], wv, o[j]);
      }
    }
  float* dst = out + (((size_t)(b*48+co)*32 + h)*32 + ws*8);
  *(float4*)dst       = make_float4(o[0],o[1],o[2],o[3]);
  *(float4*)(dst + 4) = make_float4(o[4],o[5],o[6],o[7]);
}

// ---------------- weight split+reorder: w[CO][CI][9] -> wh/wl [CO][tap][CI] bf16 ----------------
__global__ void split_w(const float* __restrict__ w, unsigned short* __restrict__ wh,
                        unsigned short* __restrict__ wl, int CO, int CI) {
  int K = CI*9;
  int i = blockIdx.x*256 + threadIdx.x;
  if (i >= CO*K) return;
  int co = i / K, rem = i % K, tap = rem / CI, ci = rem % CI;
  float v = w[(co*CI + ci)*9 + tap];
  unsigned short h = f2bf(v);
  wh[i] = h;
  wl[i] = f2bf(v - bf2f(h));
}

// ---------------- BN affine + ReLU + split to padded NHWC bf16 hi/lo (writes halos) ----------------
template<int C,int H,int W,int P>
__global__ void bn_split_nhwc(const float* __restrict__ in, const float* __restrict__ sc,
                              unsigned short* __restrict__ xh, unsigned short* __restrict__ xl) {
  constexpr int HP = H + 2*P, WP = W + 2*P;
  int b = blockIdx.x / HP, hp = blockIdx.x % HP;
  int h = hp - P;
  for (int e = threadIdx.x; e < WP*C; e += 256) {
    int wp = e / C, c = e % C;
    int w = wp - P;
    float v = 0.f;
    if (h >= 0 && h < H && w >= 0 && w < W) {
      v = in[((size_t)(b*C + c)*H + h)*W + w];
      v = fmaf(v, sc[c*2], sc[c*2+1]);
      v = v > 0.f ? v : 0.f;
    }
    unsigned short hh = f2bf(v);
    size_t o = ((size_t)(b*HP + hp)*WP + wp)*C + c;
    xh[o] = hh;
    xl[o] = f2bf(v - bf2f(hh));
  }
}

// ---------------- MFMA implicit-GEMM conv (unchanged from round 4) ----------------
template<int CI,int HIP,int WIP,int HO,int WO,int STR,int SPLITK>
__global__ __launch_bounds__(256,4) void conv_mfma(
    const unsigned short* __restrict__ xh, const unsigned short* __restrict__ xl,
    const unsigned short* __restrict__ wh, const unsigned short* __restrict__ wl,
    float* __restrict__ part, int CO, int B) {
  constexpr int K = CI*9, NSP = HO*WO, KCH = K/SPLITK, LDA = 36;
  const int NTOT = B*NSP;
  const int m0 = blockIdx.x*64, n0 = blockIdx.y*128, ks = blockIdx.z;
  __shared__ unsigned short Ah[64*LDA], Al[64*LDA], Bh[128*LDA], Bl[128*LDA];
  const int tid = threadIdx.x, lane = tid & 63, wid = tid >> 6;
  const int wm = wid >> 1, wn = wid & 1;
  const int arow = tid >> 2, ak0 = (tid & 3)*8;
  const bool aok = (m0 + arow) < CO;
  const size_t abase = (size_t)(m0 + arow)*K;
  int brow[2], bk0[2];
  size_t bbase[2];
  #pragma unroll
  for (int i = 0; i < 2; ++i) {
    int e = tid + i*256;
    brow[i] = e >> 2; bk0[i] = (e & 3)*8;
    int nn = n0 + brow[i]; if (nn > NTOT-1) nn = NTOT-1;
    int bb = nn / NSP, sp = nn % NSP;
    int ho = sp / WO, wo = sp % WO;
    bbase[i] = ((size_t)bb*HIP + ho*STR)*WIP + wo*STR;
  }
  f32x16 acc0 = (f32x16)0.f, acc1 = (f32x16)0.f;
  const int kBeg = ks*KCH, kEnd = kBeg + KCH;
  for (int kc = kBeg; kc < kEnd; kc += 32) {
    const int kLim = (kEnd - kc) < 32 ? (kEnd - kc) : 32;
    {
      frag8 vh, vl;
      vh.v8 = (short8v)(short)0; vl.v8 = (short8v)(short)0;
      if (aok && ak0 < kLim) {
        size_t off = abase + kc + ak0;
        vh.v8 = *(const short8v*)(wh + off);
        vl.v8 = *(const short8v*)(wl + off);
      }
      int lo_ = arow*LDA + ak0;
      *(short4v*)(Ah + lo_) = vh.p.lo; *(short4v*)(Ah + lo_ + 4) = vh.p.hi;
      *(short4v*)(Al + lo_) = vl.p.lo; *(short4v*)(Al + lo_ + 4) = vl.p.hi;
    }
    #pragma unroll
    for (int i = 0; i < 2; ++i) {
      frag8 vh, vl;
      vh.v8 = (short8v)(short)0; vl.v8 = (short8v)(short)0;
      if (bk0[i] < kLim) {
        int kg = kc + bk0[i];
        int tap = kg / CI, ci0 = kg - tap*CI;
        int dh = tap / 3, dw = tap - dh*3;
        size_t off = (bbase[i] + (size_t)dh*WIP + dw)*CI + ci0;
        vh.v8 = *(const short8v*)(xh + off);
        vl.v8 = *(const short8v*)(xl + off);
      }
      int lo_ = brow[i]*LDA + bk0[i];
      *(short4v*)(Bh + lo_) = vh.p.lo; *(short4v*)(Bh + lo_ + 4) = vh.p.hi;
      *(short4v*)(Bl + lo_) = vl.p.lo; *(short4v*)(Bl + lo_ + 4) = vl.p.hi;
    }
    __syncthreads();
    #pragma unroll
    for (int kst = 0; kst < 2; ++kst) {
      const int kb = kst*16 + 8*(lane >> 5);
      const int ar = wm*32 + (lane & 31);
      frag8 ah, al;
      { int o = ar*LDA + kb;
        ah.p.lo = *(const short4v*)(Ah + o); ah.p.hi = *(const short4v*)(Ah + o + 4);
        al.p.lo = *(const short4v*)(Al + o); al.p.hi = *(const short4v*)(Al + o + 4); }
      const int br = wn*64 + (lane & 31);
      frag8 bh0, bl0, bh1, bl1;
      { int o = br*LDA + kb;
        bh0.p.lo = *(const short4v*)(Bh + o); bh0.p.hi = *(const short4v*)(Bh + o + 4);
        bl0.p.lo = *(const short4v*)(Bl + o); bl0.p.hi = *(const short4v*)(Bl + o + 4); }
      { int o = (br+32)*LDA + kb;
        bh1.p.lo = *(const short4v*)(Bh + o); bh1.p.hi = *(const short4v*)(Bh + o + 4);
        bl1.p.lo = *(const short4v*)(Bl + o); bl1.p.hi = *(const short4v*)(Bl + o + 4); }
      acc0 = __builtin_amdgcn_mfma_f32_32x32x16_bf16(ah.v8, bh0.v8, acc0, 0, 0, 0);
      acc0 = __builtin_amdgcn_mfma_f32_32x32x16_bf16(ah.v8, bl0.v8, acc0, 0, 0, 0);
      acc0 = __builtin_amdgcn_mfma_f32_32x32x16_bf16(al.v8, bh0.v8, acc0, 0, 0, 0);
      acc1 = __builtin_amdgcn_mfma_f32_32x32x16_bf16(ah.v8, bh1.v8, acc1, 0, 0, 0);
      acc1 = __builtin_amdgcn_mfma_f32_32x32x16_bf16(ah.v8, bl1.v8, acc1, 0, 0, 0);
      acc1 = __builtin_amdgcn_mfma_f32_32x32x16_bf16(al.v8, bh1.v8, acc1, 0, 0, 0);
    }
    __syncthreads();
  }
  #pragma unroll
  for (int ns = 0; ns < 2; ++ns) {
    f32x16 a = ns ? acc1 : acc0;
    #pragma unroll
    for (int r = 0; r < 16; ++r) {
      int row = (r & 3) + 8*(r >> 2) + 4*(lane >> 5);
      int m = m0 + wm*32 + row;
      int n = n0 + wn*64 + ns*32 + (lane & 31);
      if (m < CO && n < NTOT)
        part[((size_t)ks*CO + m)*NTOT + n] = a[r];
    }
  }
}

// ---------------- split-K reduce (+bias, + optional fused BN partial stats) ----------------
template<int CO,int NSP,int SPLITK,bool BIAS,bool STATS>
__global__ void splitk_reduce(const float* __restrict__ part, const float* __restrict__ bias,
                              float* __restrict__ out, float* __restrict__ stats, int B) {
  const int NTOT = B*NSP;
  int i = blockIdx.x*256 + threadIdx.x;
  bool valid = i < CO*NTOT;
  float s = 0.f;
  if (valid) {
    int co = i / NTOT, n = i % NTOT;
    #pragma unroll
    for (int ks = 0; ks < SPLITK; ++ks) s += part[(size_t)(ks*CO + co)*NTOT + n];
    if (BIAS) s += bias[co];
    int b = n / NSP, sp = n % NSP;
    out[((size_t)b*CO + co)*NSP + sp] = s;
  }
  if (STATS) {
    // whole block lies within one co (NTOT % 256 == 0)
    float sum = valid ? s : 0.f, sq = valid ? s*s : 0.f;
    #pragma unroll
    for (int off = 32; off; off >>= 1) {
      sum += __shfl_down(sum, off, 64);
      sq  += __shfl_down(sq,  off, 64);
    }
    __shared__ float ls[2][4];
    int lane = threadIdx.x & 63, wv = threadIdx.x >> 6;
    if (lane == 0) { ls[0][wv] = sum; ls[1][wv] = sq; }
    __syncthreads();
    if (threadIdx.x == 0) {
      float S = 0.f, Q = 0.f;
      #pragma unroll
      for (int j = 0; j < 4; ++j) { S += ls[0][j]; Q += ls[1][j]; }
      int bpc = NTOT/256;
      int co = blockIdx.x / bpc, slice = blockIdx.x % bpc;
      stats[(co*bpc + slice)*2 + 0] = S;
      stats[(co*bpc + slice)*2 + 1] = Q;
    }
  }
}

// ---------------- BN stats (conv1 path) ----------------
template<int C,int HW,int SLICES>
__global__ void bn_partial(const float* __restrict__ x, float* __restrict__ part, int B) {
  int c = blockIdx.x / SLICES, s = blockIdx.x % SLICES;
  int bpp = B / SLICES;
  float sum = 0.f, sq = 0.f;
  for (int b = s*bpp; b < (s+1)*bpp; ++b) {
    const float* p = x + ((size_t)b*C + c)*HW;
    for (int i = threadIdx.x; i < HW; i += blockDim.x) {
      float v = p[i]; sum += v; sq += v*v;
    }
  }
  #pragma unroll
  for (int off = 32; off; off >>= 1) {
    sum += __shfl_down(sum, off, 64);
    sq  += __shfl_down(sq,  off, 64);
  }
  __shared__ float ls[2][4];
  int lane = threadIdx.x & 63, wv = threadIdx.x >> 6;
  if (lane == 0) { ls[0][wv] = sum; ls[1][wv] = sq; }
  __syncthreads();
  if (threadIdx.x == 0) {
    float S = 0.f, Q = 0.f;
    #pragma unroll
    for (int i = 0; i < 4; ++i) { S += ls[0][i]; Q += ls[1][i]; }
    part[(c*SLICES+s)*2+0] = S; part[(c*SLICES+s)*2+1] = Q;
  }
}

template<int C,int SLICES>
__global__ void bn_final(const float* __restrict__ part, const float* __restrict__ g,
                         const float* __restrict__ bta, float* __restrict__ sc, int NHW) {
  int c = blockIdx.x*blockDim.x + threadIdx.x;
  if (c >= C) return;
  float S = 0.f, Q = 0.f;
  for (int s = 0; s < SLICES; ++s) { S += part[(c*SLICES+s)*2]; Q += part[(c*SLICES+s)*2+1]; }
  float m = S / NHW, v = Q / NHW - m*m;
  float inv = rsqrtf(v + 1e-5f);
  float a = g[c] * inv;
  sc[c*2] = a; sc[c*2+1] = bta[c] - m*a;
}

// ---------------- squash primary caps in place ----------------
__global__ void squash_pc(float* __restrict__ pc, int ncaps) {
  int i = blockIdx.x*blockDim.x + threadIdx.x;
  if (i >= ncaps) return;
  float* p = pc + (size_t)i*12;
  float v[12]; float s = 0.f;
  #pragma unroll
  for (int d = 0; d < 12; ++d) { v[d] = p[d]; s += v[d]*v[d]; }
  float sc = s / ((1.f + s)*sqrtf(s + 1e-6f));
  #pragma unroll
  for (int d = 0; d < 12; ++d) p[d] = v[d]*sc;
}

// ---------------- uu gather ----------------
__global__ void uu_gather(const float* __restrict__ sq, float* __restrict__ uu, int B) {
  int idx = blockIdx.x*blockDim.x + threadIdx.x;
  int total = B*49*144*12;
  if (idx >= total) return;
  int ii = idx % 12; int t0 = idx / 12;
  int kk = t0 % 144; t0 /= 144;
  int tt = t0 % 49;  int b = t0 / 49;
  int f = tt*1728 + kk*12 + ii;
  int c = f / 441; int r = f - c*441;
  int k = r / 49;  int sp = r - k*49;
  int y = sp / 7, x = sp - y*7;
  int iy = y + k/3 - 1, ix = x + (k%3) - 1;
  float val = 0.f;
  if (iy >= 0 && iy < 7 && ix >= 0 && ix < 7)
    val = sq[((size_t)(b*192 + c)*7 + iy)*7 + ix];
  uu[idx] = val;
}

// ---------------- ConvCaps einsum: broadcast global reads, no LDS ----------------
__global__ __launch_bounds__(192) void cc_einsum2(const float* __restrict__ uu,
                                                  const float* __restrict__ wcc,
                                                  __hip_bfloat16* __restrict__ uhat,
                                                  int row0, int nrows) {
  int k  = blockIdx.x;
  int m0 = blockIdx.y * 64;
  int o = threadIdx.x;
  const float4* wp4 = (const float4*)(wcc + ((size_t)k*192 + o)*12);
  float4 w0 = wp4[0], w1 = wp4[1], w2 = wp4[2];
  int mmax = nrows - m0; if (mmax > 64) mmax = 64;
  #pragma unroll 2
  for (int m = 0; m < mmax; ++m) {
    const float4* ar = (const float4*)(uu + ((size_t)(row0+m0+m)*144 + k)*12);
    float4 a0 = ar[0], a1 = ar[1], a2 = ar[2];
    float acc = a0.x*w0.x + a0.y*w0.y + a0.z*w0.z + a0.w*w0.w
              + a1.x*w1.x + a1.y*w1.y + a1.z*w1.z + a1.w*w1.w
              + a2.x*w2.x + a2.y*w2.y + a2.z*w2.z + a2.w*w2.w;
    uhat[((size_t)(m0+m)*144 + k)*192 + o] = __float2bfloat16(acc);
  }
}

// ---------------- ConvCaps routing (unchanged) ----------------
__global__ __launch_bounds__(512,1) void cc_route(const __hip_bfloat16* __restrict__ uhat,
                                                  float* __restrict__ u2, int bBase) {
  int row = blockIdx.x;
  __shared__ __align__(16) __hip_bfloat16 uh[144*192];
  __shared__ float blog[144*16];
  __shared__ float cc[144*16];
  __shared__ float sv[2][192];
  __shared__ float scl[16];
  int tid = threadIdx.x;
  const uint4* src = (const uint4*)(uhat + (size_t)row*144*192);
  uint4* dst = (uint4*)uh;
  for (int i = tid; i < 3456; i += 512) dst[i] = src[i];
  for (int i = tid; i < 2304; i += 512) blog[i] = 0.f;
  __syncthreads();
  for (int r = 0; r < 3; ++r) {
    if (tid < 144) {
      float mx = -1e30f;
      #pragma unroll
      for (int o = 0; o < 16; ++o) mx = fmaxf(mx, blog[tid*16+o]);
      float e[16]; float ssum = 0.f;
      #pragma unroll
      for (int o = 0; o < 16; ++o) { e[o] = __expf(blog[tid*16+o]-mx); ssum += e[o]; }
      float inv = 1.f/ssum;
      #pragma unroll
      for (int o = 0; o < 16; ++o) cc[tid*16+o] = e[o]*inv;
    }
    __syncthreads();
    if (tid < 384) {
      int o = tid % 192, half = tid / 192;
      float acc = 0.f;
      for (int k = half*72; k < half*72+72; ++k)
        acc = fmaf(cc[k*16 + o/12], __bfloat162float(uh[k*192+o]), acc);
      sv[half][o] = acc;
    }
    __syncthreads();
    if (tid < 192) sv[0][tid] += sv[1][tid];
    __syncthreads();
    if (tid < 16) {
      float s = 0.f;
      #pragma unroll
      for (int d = 0; d < 12; ++d) { float v = sv[0][tid*12+d]; s += v*v; }
      scl[tid] = s / ((1.f + s)*sqrtf(s + 1e-6f));
    }
    __syncthreads();
    if (tid < 192) sv[0][tid] *= scl[tid/12];
    __syncthreads();
    if (r < 2) {
      for (int p = tid; p < 2304; p += 512) {
        int k = p >> 4, oc = p & 15;
        float dot = 0.f;
        #pragma unroll
        for (int d = 0; d < 12; ++d)
          dot = fmaf(sv[0][oc*12+d], __bfloat162float(uh[k*192+oc*12+d]), dot);
        blog[p] += dot;
      }
      __syncthreads();
    }
  }
  if (tid < 192) u2[((size_t)bBase*49 + row)*192 + tid] = sv[0][tid];
}

// ---------------- Class caps einsum (bf16 output) ----------------
__global__ void class_einsum(const float* __restrict__ u2, const float* __restrict__ wcl,
                             unsigned short* __restrict__ uhat2, int B) {
  int n = blockIdx.x;
  __shared__ float u2l[64][12];
  int tid = threadIdx.x;
  for (int e = tid; e < 64*12; e += 320) {
    int b = e / 12, i = e % 12;
    u2l[b][i] = u2[(size_t)b*9408 + n*12 + i];
  }
  __syncthreads();
  int od = tid % 160, bh = tid / 160;
  int o = od >> 4, d = od & 15;
  float w[12];
  #pragma unroll
  for (int i = 0; i < 12; ++i) w[i] = wcl[(size_t)n*1920 + o*192 + d*12 + i];
  for (int b = bh*32; b < bh*32+32; ++b) {
    float acc = 0.f;
    #pragma unroll
    for (int i = 0; i < 12; ++i) acc = fmaf(w[i], u2l[b][i], acc);
    uhat2[((size_t)b*784 + n)*160 + od] = f2bf(acc);
  }
}

// ---------------- class routing: mean partial (iter 0, c uniform) ----------------
__global__ __launch_bounds__(160) void cls_mean_part(const unsigned short* __restrict__ uh2b,
                                                     float* __restrict__ cpart) {
  int b = blockIdx.x, sl = blockIdx.y, od = threadIdx.x;
  float s = 0.f;
  for (int it = 0; it < 98; ++it) {
    int n = sl*98 + it;
    s += bf2f(uh2b[((size_t)b*784 + n)*160 + od]);
  }
  cpart[((size_t)b*8 + sl)*160 + od] = s;
}

// ---------------- class routing: fused b-update + softmax + weighted accumulate ----------------
template<bool FIRST, bool WRITEB>
__global__ __launch_bounds__(320) void cls_fused(const unsigned short* __restrict__ uh2b,
                                                 const float* __restrict__ vprev,
                                                 float* __restrict__ b2l,
                                                 float* __restrict__ cpart) {
  int b = blockIdx.x, sl = blockIdx.y;
  int sub = threadIdx.x / 160, od = threadIdx.x % 160;
  int o = od >> 4, d = od & 15;
  __shared__ float cls_c[2][10];
  __shared__ float sred[320];
  float v = vprev[b*160 + od];
  float sacc = 0.f;
  for (int it = 0; it < 49; ++it) {
    int n = sl*98 + it*2 + sub;
    float u = bf2f(uh2b[((size_t)b*784 + n)*160 + od]);
    float dot = v * u;
    #pragma unroll
    for (int off = 8; off; off >>= 1) dot += __shfl_xor(dot, off, 16);
    __shared__ float dls[2][10];
    if (d == 0) {
      float bb = dot;
      if (!FIRST) bb += b2l[((size_t)b*784 + n)*10 + o];
      if (WRITEB) b2l[((size_t)b*784 + n)*10 + o] = bb;
      dls[sub][o] = bb;
    }
    __syncthreads();
    if (threadIdx.x < 2) {
      int s = threadIdx.x;
      float mx = dls[s][0];
      #pragma unroll
      for (int j = 1; j < 10; ++j) mx = fmaxf(mx, dls[s][j]);
      float e[10]; float sum = 0.f;
      #pragma unroll
      for (int j = 0; j < 10; ++j) { e[j] = __expf(dls[s][j]-mx); sum += e[j]; }
      float inv = 1.f/sum;
      #pragma unroll
      for (int j = 0; j < 10; ++j) cls_c[s][j] = e[j]*inv;
    }
    __syncthreads();
    sacc = fmaf(cls_c[sub][o], u, sacc);
    __syncthreads();
  }
  sred[threadIdx.x] = sacc;
  __syncthreads();
  if (sub == 0)
    cpart[((size_t)b*8 + sl)*160 + od] = sred[od] + sred[160 + od];
}

// ---------------- class routing: reduce partials + squash ----------------
__global__ __launch_bounds__(160) void cls_finish(const float* __restrict__ cpart,
                                                  float* __restrict__ vout, float fac) {
  int b = blockIdx.x, od = threadIdx.x;
  float s = 0.f;
  #pragma unroll
  for (int sl = 0; sl < 8; ++sl) s += cpart[((size_t)b*8 + sl)*160 + od];
  s *= fac;
  float nrm = s*s;
  #pragma unroll
  for (int off = 8; off; off >>= 1) nrm += __shfl_xor(nrm, off, 16);
  float sc = nrm / ((1.f + nrm)*sqrtf(nrm + 1e-6f));
  vout[(size_t)b*160 + od] = s*sc;
}

// ---------------- host launch ----------------
extern "C" void kernel_launch(void* const* d_in, const int* in_sizes, int n_in,
                              void* d_out, int out_size, void* d_ws, size_t ws_size,
                              hipStream_t stream) {
  const float* images = (const float*)d_in[0];
  const float* w1  = (const float*)d_in[1];
  const float* g1  = (const float*)d_in[2];
  const float* b1  = (const float*)d_in[3];
  const float* w2  = (const float*)d_in[4];
  const float* g2  = (const float*)d_in[5];
  const float* b2  = (const float*)d_in[6];
  const float* w3  = (const float*)d_in[7];
  const float* g3  = (const float*)d_in[8];
  const float* b3  = (const float*)d_in[9];
  const float* wp  = (const float*)d_in[10];
  const float* bp  = (const float*)d_in[11];
  const float* wcc = (const float*)d_in[12];
  const float* wcl = (const float*)d_in[13];
  float* out = (float*)d_out;
  float* ws  = (float*)d_ws;

  // persistent regions (float offsets)
  float* t1    = ws + 0;            // 3,145,728
  float* t2    = ws + 3145728;      // 1,572,864
  float* t3    = ws + 4718592;      // 3,145,728
  float* pc    = ws + 7864320;      //   602,112
  float* uu    = ws + 8466432;      // 5,419,008
  float* u2b   = ws + 13885440;     //   602,112
  unsigned short* uh2b = (unsigned short*)(ws + 14487552);  // 8,028,160 ushorts
  float* b2l   = ws + 22515712;     //   501,760
  float* scrC  = ws + 23017472;     //   501,760 (spartB during convs, cpart during class)
  float* v2    = ws + 23519232;     //    10,240
  float* spart = ws + 23529472;     //     3,072 (conv1 BN)
  float* ssc1  = ws + 23532544;     //        96
  float* ssc2  = ws + 23532640;     //       192
  float* ssc3  = ws + 23532832;     //       384
  float* U     = ws + 23533312;     // arena, 10,838,016 f32
  __hip_bfloat16* uhc = (__hip_bfloat16*)U;

  // split/reordered weights live in dead `uu` region (dead until uu_gather)
  unsigned short* wh2 = (unsigned short*)(uu + 0);
  unsigned short* wl2 = (unsigned short*)(uu + 20736);
  unsigned short* wh3 = (unsigned short*)(uu + 41472);
  unsigned short* wl3 = (unsigned short*)(uu + 124416);
  unsigned short* whp = (unsigned short*)(uu + 207360);
  unsigned short* wlp = (unsigned short*)(uu + 373248);

  // phase transients in the U arena
  unsigned short* x2h = (unsigned short*)(U + 0);
  unsigned short* x2l = (unsigned short*)(U + 1775616);
  float*          part2 = U + 3551232;                    // 3x96x16384
  unsigned short* x3h = (unsigned short*)(U + 0);
  unsigned short* x3l = (unsigned short*)(U + 995328);
  float*          part3 = U + 1990656;                    // 2x192x16384
  unsigned short* xph = (unsigned short*)(U + 0);
  unsigned short* xpl = (unsigned short*)(U + 1572864);
  float*          partp = U + 3145728;                    // 8x192x3136

  const int B = 64;

  // weight splits
  split_w<<<(96*432+255)/256,256,0,stream>>>(w2, wh2, wl2, 96, 48);
  split_w<<<(192*864+255)/256,256,0,stream>>>(w3, wh3, wl3, 192, 96);
  split_w<<<(192*1728+255)/256,256,0,stream>>>(wp, whp, wlp, 192, 192);

  // conv1 + BN1 stats
  conv1_fused<<<2048,192,0,stream>>>(images, w1, t1);
  bn_partial<48,1024,8><<<48*8,256,0,stream>>>(t1, spart, B);
  bn_final<48,8><<<1,64,0,stream>>>(spart, g1, b1, ssc1, 65536);

  // conv2: BN1+ReLU+split (with halos), MFMA, reduce+stats
  bn_split_nhwc<48,32,32,1><<<64*34,256,0,stream>>>(t1, ssc1, x2h, x2l);
  conv_mfma<48,34,34,16,16,2,3><<<dim3(2,128,3),256,0,stream>>>(x2h, x2l, wh2, wl2, part2, 96, B);
  splitk_reduce<96,256,3,false,true><<<6144,256,0,stream>>>(part2, nullptr, t2, scrC, B);
  bn_final<96,64><<<1,128,0,stream>>>(scrC, g2, b2, ssc2, 16384);

  // conv3
  bn_split_nhwc<96,16,16,1><<<64*18,256,0,stream>>>(t2, ssc2, x3h, x3l);
  conv_mfma<96,18,18,16,16,1,2><<<dim3(3,128,2),256,0,stream>>>(x3h, x3l, wh3, wl3, part3, 192, B);
  splitk_reduce<192,256,2,false,true><<<12288,256,0,stream>>>(part3, nullptr, t3, scrC, B);
  bn_final<192,64><<<1,192,0,stream>>>(scrC, g3, b3, ssc3, 16384);

  // primary caps conv + bias, then squash
  bn_split_nhwc<192,16,16,0><<<64*16,256,0,stream>>>(t3, ssc3, xph, xpl);
  conv_mfma<192,16,16,7,7,2,8><<<dim3(3,25,8),256,0,stream>>>(xph, xpl, whp, wlp, partp, 192, B);
  splitk_reduce<192,49,8,true,false><<<2352,256,0,stream>>>(partp, bp, pc, nullptr, B);
  squash_pc<<<196,256,0,stream>>>(pc, 50176);

  // uu gather
  uu_gather<<<21168,256,0,stream>>>(pc, uu, B);
  // ConvCaps einsum + fused in-LDS routing, chunked over b
  for (int cb = 0; cb < 4; ++cb) {
    cc_einsum2<<<dim3(144,13),192,0,stream>>>(uu, wcc, uhc, cb*784, 784);
    cc_route<<<784,512,0,stream>>>(uhc, u2b, cb*16);
  }
  // Class caps einsum (bf16) + restructured routing
  class_einsum<<<784,320,0,stream>>>(u2b, wcl, uh2b, B);
  cls_mean_part<<<dim3(64,8),160,0,stream>>>(uh2b, scrC);
  cls_finish<<<64,160,0,stream>>>(scrC, v2, 0.1f);
  cls_fused<true,true><<<dim3(64,8),320,0,stream>>>(uh2b, v2, b2l, scrC);
  cls_finish<<<64,160,0,stream>>>(scrC, v2, 1.0f);
  cls_fused<false,false><<<dim3(64,8),320,0,stream>>>(uh2b, v2, b2l, scrC);
  cls_finish<<<64,160,0,stream>>>(scrC, out, 1.0f);
  (void)in_sizes; (void)n_in; (void)out_size; (void)ws_size;
}

// Round 7
// 448.858 us; speedup vs baseline: 5.3830x; 1.1315x over previous
//
#include <hip/hip_runtime.h>
#include <hip/hip_bf16.h>

typedef __attribute__((ext_vector_type(4))) short short4v;
typedef __attribute__((ext_vector_type(8))) short short8v;
typedef __attribute__((ext_vector_type(16))) float f32x16;

union frag8 { short8v v8; struct { short4v lo, hi; } p; };

__device__ __forceinline__ unsigned short f2bf(float v) {
  unsigned u = __float_as_uint(v);
  unsigned r = u + 0x7fffu + ((u >> 16) & 1u);
  return (unsigned short)(r >> 16);
}
__device__ __forceinline__ float bf2f(unsigned short h) {
  return __uint_as_float(((unsigned)h) << 16);
}

// ---------------- conv1: one block per (b,h), LDS input slab, weights in regs ----------------
__global__ __launch_bounds__(192) void conv1_fused(const float* __restrict__ images,
                                                   const float* __restrict__ w1,
                                                   float* __restrict__ out) {
  int b = blockIdx.x >> 5, h = blockIdx.x & 31;
  __shared__ __align__(16) float lin[3][3][36];
  int tid = threadIdx.x;
  for (int e = tid; e < 324; e += 192) {
    int ci = e / 108, rem = e % 108, ki = rem / 36, wi = rem % 36;
    int row = h + ki - 1, col = wi - 1;
    float v = 0.f;
    if (row >= 0 && row < 32 && col >= 0 && col < 32)
      v = images[((size_t)(b*3 + ci)*32 + row)*32 + col];
    lin[ci][ki][wi] = v;
  }
  int co = tid >> 2, ws = tid & 3;
  float wr[27];
  #pragma unroll
  for (int j = 0; j < 27; ++j) wr[j] = w1[co*27 + j];
  __syncthreads();
  float o[8];
  #pragma unroll
  for (int j = 0; j < 8; ++j) o[j] = 0.f;
  #pragma unroll
  for (int ci = 0; ci < 3; ++ci)
    #pragma unroll
    for (int ki = 0; ki < 3; ++ki) {
      float4 q0 = *(const float4*)&lin[ci][ki][ws*8];
      float4 q1 = *(const float4*)&lin[ci][ki][ws*8+4];
      float4 q2 = *(const float4*)&lin[ci][ki][ws*8+8];
      float r[12] = {q0.x,q0.y,q0.z,q0.w,q1.x,q1.y,q1.z,q1.w,q2.x,q2.y,q2.z,q2.w};
      #pragma unroll
      for (int kj = 0; kj < 3; ++kj) {
        float wv = wr[(ci*3+ki)*3+kj];
        #pragma unroll
        for (int j = 0; j < 8; ++j) o[j] = fmaf(r[j+kj], wv, o[j]);
      }
    }
  float* dst = out + (((size_t)(b*48+co)*32 + h)*32 + ws*8);
  *(float4*)dst       = make_float4(o[0],o[1],o[2],o[3]);
  *(float4*)(dst + 4) = make_float4(o[4],o[5],o[6],o[7]);
}

// ---------------- weight split+reorder: w[CO][CI][9] -> wh/wl [CO][tap][CI] bf16 ----------------
__global__ void split_w(const float* __restrict__ w, unsigned short* __restrict__ wh,
                        unsigned short* __restrict__ wl, int CO, int CI) {
  int K = CI*9;
  int i = blockIdx.x*256 + threadIdx.x;
  if (i >= CO*K) return;
  int co = i / K, rem = i % K, tap = rem / CI, ci = rem % CI;
  float v = w[(co*CI + ci)*9 + tap];
  unsigned short h = f2bf(v);
  wh[i] = h;
  wl[i] = f2bf(v - bf2f(h));
}

// ---------------- BN affine + ReLU + split to padded NHWC bf16 hi/lo (writes halos) ----------------
template<int C,int H,int W,int P>
__global__ void bn_split_nhwc(const float* __restrict__ in, const float* __restrict__ sc,
                              unsigned short* __restrict__ xh, unsigned short* __restrict__ xl) {
  constexpr int HP = H + 2*P, WP = W + 2*P;
  int b = blockIdx.x / HP, hp = blockIdx.x % HP;
  int h = hp - P;
  for (int e = threadIdx.x; e < WP*C; e += 256) {
    int wp = e / C, c = e % C;
    int w = wp - P;
    float v = 0.f;
    if (h >= 0 && h < H && w >= 0 && w < W) {
      v = in[((size_t)(b*C + c)*H + h)*W + w];
      v = fmaf(v, sc[c*2], sc[c*2+1]);
      v = v > 0.f ? v : 0.f;
    }
    unsigned short hh = f2bf(v);
    size_t o = ((size_t)(b*HP + hp)*WP + wp)*C + c;
    xh[o] = hh;
    xl[o] = f2bf(v - bf2f(hh));
  }
}

// ---------------- MFMA implicit-GEMM conv (unchanged) ----------------
template<int CI,int HIP,int WIP,int HO,int WO,int STR,int SPLITK>
__global__ __launch_bounds__(256,4) void conv_mfma(
    const unsigned short* __restrict__ xh, const unsigned short* __restrict__ xl,
    const unsigned short* __restrict__ wh, const unsigned short* __restrict__ wl,
    float* __restrict__ part, int CO, int B) {
  constexpr int K = CI*9, NSP = HO*WO, KCH = K/SPLITK, LDA = 36;
  const int NTOT = B*NSP;
  const int m0 = blockIdx.x*64, n0 = blockIdx.y*128, ks = blockIdx.z;
  __shared__ unsigned short Ah[64*LDA], Al[64*LDA], Bh[128*LDA], Bl[128*LDA];
  const int tid = threadIdx.x, lane = tid & 63, wid = tid >> 6;
  const int wm = wid >> 1, wn = wid & 1;
  const int arow = tid >> 2, ak0 = (tid & 3)*8;
  const bool aok = (m0 + arow) < CO;
  const size_t abase = (size_t)(m0 + arow)*K;
  int brow[2], bk0[2];
  size_t bbase[2];
  #pragma unroll
  for (int i = 0; i < 2; ++i) {
    int e = tid + i*256;
    brow[i] = e >> 2; bk0[i] = (e & 3)*8;
    int nn = n0 + brow[i]; if (nn > NTOT-1) nn = NTOT-1;
    int bb = nn / NSP, sp = nn % NSP;
    int ho = sp / WO, wo = sp % WO;
    bbase[i] = ((size_t)bb*HIP + ho*STR)*WIP + wo*STR;
  }
  f32x16 acc0 = (f32x16)0.f, acc1 = (f32x16)0.f;
  const int kBeg = ks*KCH, kEnd = kBeg + KCH;
  for (int kc = kBeg; kc < kEnd; kc += 32) {
    const int kLim = (kEnd - kc) < 32 ? (kEnd - kc) : 32;
    {
      frag8 vh, vl;
      vh.v8 = (short8v)(short)0; vl.v8 = (short8v)(short)0;
      if (aok && ak0 < kLim) {
        size_t off = abase + kc + ak0;
        vh.v8 = *(const short8v*)(wh + off);
        vl.v8 = *(const short8v*)(wl + off);
      }
      int lo_ = arow*LDA + ak0;
      *(short4v*)(Ah + lo_) = vh.p.lo; *(short4v*)(Ah + lo_ + 4) = vh.p.hi;
      *(short4v*)(Al + lo_) = vl.p.lo; *(short4v*)(Al + lo_ + 4) = vl.p.hi;
    }
    #pragma unroll
    for (int i = 0; i < 2; ++i) {
      frag8 vh, vl;
      vh.v8 = (short8v)(short)0; vl.v8 = (short8v)(short)0;
      if (bk0[i] < kLim) {
        int kg = kc + bk0[i];
        int tap = kg / CI, ci0 = kg - tap*CI;
        int dh = tap / 3, dw = tap - dh*3;
        size_t off = (bbase[i] + (size_t)dh*WIP + dw)*CI + ci0;
        vh.v8 = *(const short8v*)(xh + off);
        vl.v8 = *(const short8v*)(xl + off);
      }
      int lo_ = brow[i]*LDA + bk0[i];
      *(short4v*)(Bh + lo_) = vh.p.lo; *(short4v*)(Bh + lo_ + 4) = vh.p.hi;
      *(short4v*)(Bl + lo_) = vl.p.lo; *(short4v*)(Bl + lo_ + 4) = vl.p.hi;
    }
    __syncthreads();
    #pragma unroll
    for (int kst = 0; kst < 2; ++kst) {
      const int kb = kst*16 + 8*(lane >> 5);
      const int ar = wm*32 + (lane & 31);
      frag8 ah, al;
      { int o = ar*LDA + kb;
        ah.p.lo = *(const short4v*)(Ah + o); ah.p.hi = *(const short4v*)(Ah + o + 4);
        al.p.lo = *(const short4v*)(Al + o); al.p.hi = *(const short4v*)(Al + o + 4); }
      const int br = wn*64 + (lane & 31);
      frag8 bh0, bl0, bh1, bl1;
      { int o = br*LDA + kb;
        bh0.p.lo = *(const short4v*)(Bh + o); bh0.p.hi = *(const short4v*)(Bh + o + 4);
        bl0.p.lo = *(const short4v*)(Bl + o); bl0.p.hi = *(const short4v*)(Bl + o + 4); }
      { int o = (br+32)*LDA + kb;
        bh1.p.lo = *(const short4v*)(Bh + o); bh1.p.hi = *(const short4v*)(Bh + o + 4);
        bl1.p.lo = *(const short4v*)(Bl + o); bl1.p.hi = *(const short4v*)(Bl + o + 4); }
      acc0 = __builtin_amdgcn_mfma_f32_32x32x16_bf16(ah.v8, bh0.v8, acc0, 0, 0, 0);
      acc0 = __builtin_amdgcn_mfma_f32_32x32x16_bf16(ah.v8, bl0.v8, acc0, 0, 0, 0);
      acc0 = __builtin_amdgcn_mfma_f32_32x32x16_bf16(al.v8, bh0.v8, acc0, 0, 0, 0);
      acc1 = __builtin_amdgcn_mfma_f32_32x32x16_bf16(ah.v8, bh1.v8, acc1, 0, 0, 0);
      acc1 = __builtin_amdgcn_mfma_f32_32x32x16_bf16(ah.v8, bl1.v8, acc1, 0, 0, 0);
      acc1 = __builtin_amdgcn_mfma_f32_32x32x16_bf16(al.v8, bh1.v8, acc1, 0, 0, 0);
    }
    __syncthreads();
  }
  #pragma unroll
  for (int ns = 0; ns < 2; ++ns) {
    f32x16 a = ns ? acc1 : acc0;
    #pragma unroll
    for (int r = 0; r < 16; ++r) {
      int row = (r & 3) + 8*(r >> 2) + 4*(lane >> 5);
      int m = m0 + wm*32 + row;
      int n = n0 + wn*64 + ns*32 + (lane & 31);
      if (m < CO && n < NTOT)
        part[((size_t)ks*CO + m)*NTOT + n] = a[r];
    }
  }
}

// ---------------- split-K reduce (+bias, + optional fused BN partial stats) ----------------
template<int CO,int NSP,int SPLITK,bool BIAS,bool STATS>
__global__ void splitk_reduce(const float* __restrict__ part, const float* __restrict__ bias,
                              float* __restrict__ out, float* __restrict__ stats, int B) {
  const int NTOT = B*NSP;
  int i = blockIdx.x*256 + threadIdx.x;
  bool valid = i < CO*NTOT;
  float s = 0.f;
  if (valid) {
    int co = i / NTOT, n = i % NTOT;
    #pragma unroll
    for (int ks = 0; ks < SPLITK; ++ks) s += part[(size_t)(ks*CO + co)*NTOT + n];
    if (BIAS) s += bias[co];
    int b = n / NSP, sp = n % NSP;
    out[((size_t)b*CO + co)*NSP + sp] = s;
  }
  if (STATS) {
    float sum = valid ? s : 0.f, sq = valid ? s*s : 0.f;
    #pragma unroll
    for (int off = 32; off; off >>= 1) {
      sum += __shfl_down(sum, off, 64);
      sq  += __shfl_down(sq,  off, 64);
    }
    __shared__ float ls[2][4];
    int lane = threadIdx.x & 63, wv = threadIdx.x >> 6;
    if (lane == 0) { ls[0][wv] = sum; ls[1][wv] = sq; }
    __syncthreads();
    if (threadIdx.x == 0) {
      float S = 0.f, Q = 0.f;
      #pragma unroll
      for (int j = 0; j < 4; ++j) { S += ls[0][j]; Q += ls[1][j]; }
      int bpc = NTOT/256;
      int co = blockIdx.x / bpc, slice = blockIdx.x % bpc;
      stats[(co*bpc + slice)*2 + 0] = S;
      stats[(co*bpc + slice)*2 + 1] = Q;
    }
  }
}

// ---------------- BN stats (conv1 path) ----------------
template<int C,int HW,int SLICES>
__global__ void bn_partial(const float* __restrict__ x, float* __restrict__ part, int B) {
  int c = blockIdx.x / SLICES, s = blockIdx.x % SLICES;
  int bpp = B / SLICES;
  float sum = 0.f, sq = 0.f;
  for (int b = s*bpp; b < (s+1)*bpp; ++b) {
    const float* p = x + ((size_t)b*C + c)*HW;
    for (int i = threadIdx.x; i < HW; i += blockDim.x) {
      float v = p[i]; sum += v; sq += v*v;
    }
  }
  #pragma unroll
  for (int off = 32; off; off >>= 1) {
    sum += __shfl_down(sum, off, 64);
    sq  += __shfl_down(sq,  off, 64);
  }
  __shared__ float ls[2][4];
  int lane = threadIdx.x & 63, wv = threadIdx.x >> 6;
  if (lane == 0) { ls[0][wv] = sum; ls[1][wv] = sq; }
  __syncthreads();
  if (threadIdx.x == 0) {
    float S = 0.f, Q = 0.f;
    #pragma unroll
    for (int i = 0; i < 4; ++i) { S += ls[0][i]; Q += ls[1][i]; }
    part[(c*SLICES+s)*2+0] = S; part[(c*SLICES+s)*2+1] = Q;
  }
}

template<int C,int SLICES>
__global__ void bn_final(const float* __restrict__ part, const float* __restrict__ g,
                         const float* __restrict__ bta, float* __restrict__ sc, int NHW) {
  int c = blockIdx.x*blockDim.x + threadIdx.x;
  if (c >= C) return;
  float S = 0.f, Q = 0.f;
  for (int s = 0; s < SLICES; ++s) { S += part[(c*SLICES+s)*2]; Q += part[(c*SLICES+s)*2+1]; }
  float m = S / NHW, v = Q / NHW - m*m;
  float inv = rsqrtf(v + 1e-5f);
  float a = g[c] * inv;
  sc[c*2] = a; sc[c*2+1] = bta[c] - m*a;
}

// ---------------- squash primary caps in place ----------------
__global__ void squash_pc(float* __restrict__ pc, int ncaps) {
  int i = blockIdx.x*blockDim.x + threadIdx.x;
  if (i >= ncaps) return;
  float* p = pc + (size_t)i*12;
  float v[12]; float s = 0.f;
  #pragma unroll
  for (int d = 0; d < 12; ++d) { v[d] = p[d]; s += v[d]*v[d]; }
  float sc = s / ((1.f + s)*sqrtf(s + 1e-6f));
  #pragma unroll
  for (int d = 0; d < 12; ++d) p[d] = v[d]*sc;
}

// ---------------- uu gather ----------------
__global__ void uu_gather(const float* __restrict__ sq, float* __restrict__ uu, int B) {
  int idx = blockIdx.x*blockDim.x + threadIdx.x;
  int total = B*49*144*12;
  if (idx >= total) return;
  int ii = idx % 12; int t0 = idx / 12;
  int kk = t0 % 144; t0 /= 144;
  int tt = t0 % 49;  int b = t0 / 49;
  int f = tt*1728 + kk*12 + ii;
  int c = f / 441; int r = f - c*441;
  int k = r / 49;  int sp = r - k*49;
  int y = sp / 7, x = sp - y*7;
  int iy = y + k/3 - 1, ix = x + (k%3) - 1;
  float val = 0.f;
  if (iy >= 0 && iy < 7 && ix >= 0 && ix < 7)
    val = sq[((size_t)(b*192 + c)*7 + iy)*7 + ix];
  uu[idx] = val;
}

// ---------------- ConvCaps einsum: broadcast global reads, no LDS ----------------
__global__ __launch_bounds__(192) void cc_einsum2(const float* __restrict__ uu,
                                                  const float* __restrict__ wcc,
                                                  __hip_bfloat16* __restrict__ uhat,
                                                  int row0, int nrows) {
  int k  = blockIdx.x;
  int m0 = blockIdx.y * 64;
  int o = threadIdx.x;
  const float4* wp4 = (const float4*)(wcc + ((size_t)k*192 + o)*12);
  float4 w0 = wp4[0], w1 = wp4[1], w2 = wp4[2];
  int mmax = nrows - m0; if (mmax > 64) mmax = 64;
  #pragma unroll 2
  for (int m = 0; m < mmax; ++m) {
    const float4* ar = (const float4*)(uu + ((size_t)(row0+m0+m)*144 + k)*12);
    float4 a0 = ar[0], a1 = ar[1], a2 = ar[2];
    float acc = a0.x*w0.x + a0.y*w0.y + a0.z*w0.z + a0.w*w0.w
              + a1.x*w1.x + a1.y*w1.y + a1.z*w1.z + a1.w*w1.w
              + a2.x*w2.x + a2.y*w2.y + a2.z*w2.z + a2.w*w2.w;
    uhat[((size_t)(m0+m)*144 + k)*192 + o] = __float2bfloat16(acc);
  }
}

// ---------------- ConvCaps routing (unchanged) ----------------
__global__ __launch_bounds__(512,1) void cc_route(const __hip_bfloat16* __restrict__ uhat,
                                                  float* __restrict__ u2, int bBase) {
  int row = blockIdx.x;
  __shared__ __align__(16) __hip_bfloat16 uh[144*192];
  __shared__ float blog[144*16];
  __shared__ float cc[144*16];
  __shared__ float sv[2][192];
  __shared__ float scl[16];
  int tid = threadIdx.x;
  const uint4* src = (const uint4*)(uhat + (size_t)row*144*192);
  uint4* dst = (uint4*)uh;
  for (int i = tid; i < 3456; i += 512) dst[i] = src[i];
  for (int i = tid; i < 2304; i += 512) blog[i] = 0.f;
  __syncthreads();
  for (int r = 0; r < 3; ++r) {
    if (tid < 144) {
      float mx = -1e30f;
      #pragma unroll
      for (int o = 0; o < 16; ++o) mx = fmaxf(mx, blog[tid*16+o]);
      float e[16]; float ssum = 0.f;
      #pragma unroll
      for (int o = 0; o < 16; ++o) { e[o] = __expf(blog[tid*16+o]-mx); ssum += e[o]; }
      float inv = 1.f/ssum;
      #pragma unroll
      for (int o = 0; o < 16; ++o) cc[tid*16+o] = e[o]*inv;
    }
    __syncthreads();
    if (tid < 384) {
      int o = tid % 192, half = tid / 192;
      float acc = 0.f;
      for (int k = half*72; k < half*72+72; ++k)
        acc = fmaf(cc[k*16 + o/12], __bfloat162float(uh[k*192+o]), acc);
      sv[half][o] = acc;
    }
    __syncthreads();
    if (tid < 192) sv[0][tid] += sv[1][tid];
    __syncthreads();
    if (tid < 16) {
      float s = 0.f;
      #pragma unroll
      for (int d = 0; d < 12; ++d) { float v = sv[0][tid*12+d]; s += v*v; }
      scl[tid] = s / ((1.f + s)*sqrtf(s + 1e-6f));
    }
    __syncthreads();
    if (tid < 192) sv[0][tid] *= scl[tid/12];
    __syncthreads();
    if (r < 2) {
      for (int p = tid; p < 2304; p += 512) {
        int k = p >> 4, oc = p & 15;
        float dot = 0.f;
        #pragma unroll
        for (int d = 0; d < 12; ++d)
          dot = fmaf(sv[0][oc*12+d], __bfloat162float(uh[k*192+oc*12+d]), dot);
        blog[p] += dot;
      }
      __syncthreads();
    }
  }
  if (tid < 192) u2[((size_t)bBase*49 + row)*192 + tid] = sv[0][tid];
}

// ---------------- Class caps einsum (bf16 output) ----------------
__global__ void class_einsum(const float* __restrict__ u2, const float* __restrict__ wcl,
                             unsigned short* __restrict__ uhat2, int B) {
  int n = blockIdx.x;
  __shared__ float u2l[64][12];
  int tid = threadIdx.x;
  for (int e = tid; e < 64*12; e += 320) {
    int b = e / 12, i = e % 12;
    u2l[b][i] = u2[(size_t)b*9408 + n*12 + i];
  }
  __syncthreads();
  int od = tid % 160, bh = tid / 160;
  int o = od >> 4, d = od & 15;
  float w[12];
  #pragma unroll
  for (int i = 0; i < 12; ++i) w[i] = wcl[(size_t)n*1920 + o*192 + d*12 + i];
  for (int b = bh*32; b < bh*32+32; ++b) {
    float acc = 0.f;
    #pragma unroll
    for (int i = 0; i < 12; ++i) acc = fmaf(w[i], u2l[b][i], acc);
    uhat2[((size_t)b*784 + n)*160 + od] = f2bf(acc);
  }
}

// ---------------- class routing: wave-local pass, no barriers in main loop ----------------
// lane = (nl 0..3, d 0..15); 4 n per wave, 4 waves => 16 n per step, 7 steps, 112 n per block.
// MODE 0: uniform c (sum u). MODE 1: blog = dot(v,u), write, softmax, acc.
// MODE 2: blog += dot(v,u) (read only), softmax, acc.
template<int MODE>
__global__ __launch_bounds__(256) void cls_pass(const unsigned short* __restrict__ uh2b,
                                                const float* __restrict__ vprev,
                                                float* __restrict__ b2l,
                                                float* __restrict__ cpart) {
  const int b = blockIdx.x, sl = blockIdx.y;   // sl 0..6
  const int tid = threadIdx.x, lane = tid & 63, wv = tid >> 6;
  const int nl = lane >> 4, d = lane & 15;
  float v[10];
  if (MODE != 0) {
    #pragma unroll
    for (int o = 0; o < 10; ++o) v[o] = vprev[b*160 + o*16 + d];
  }
  float sacc[10];
  #pragma unroll
  for (int o = 0; o < 10; ++o) sacc[o] = 0.f;
  for (int step = 0; step < 7; ++step) {
    const int n = sl*112 + step*16 + wv*4 + nl;
    const unsigned short* up = uh2b + ((size_t)b*784 + n)*160 + d;
    float u[10];
    #pragma unroll
    for (int o = 0; o < 10; ++o) u[o] = bf2f(up[o*16]);
    if (MODE == 0) {
      #pragma unroll
      for (int o = 0; o < 10; ++o) sacc[o] += u[o];
    } else {
      float bb[10];
      #pragma unroll
      for (int o = 0; o < 10; ++o) {
        float t = v[o]*u[o];
        #pragma unroll
        for (int off = 8; off; off >>= 1) t += __shfl_xor(t, off, 16);
        bb[o] = t;
      }
      if (MODE == 2) {
        #pragma unroll
        for (int o = 0; o < 10; ++o) bb[o] += b2l[((size_t)b*784 + n)*10 + o];
      }
      if (MODE == 1 && d < 10) b2l[((size_t)b*784 + n)*10 + d] = bb[d];
      float mx = bb[0];
      #pragma unroll
      for (int o = 1; o < 10; ++o) mx = fmaxf(mx, bb[o]);
      float es = 0.f;
      #pragma unroll
      for (int o = 0; o < 10; ++o) { bb[o] = __expf(bb[o]-mx); es += bb[o]; }
      float inv = 1.f/es;
      #pragma unroll
      for (int o = 0; o < 10; ++o) sacc[o] = fmaf(bb[o]*inv, u[o], sacc[o]);
    }
  }
  // reduce over the 4 n-subgroups within the wave (lane bits 4,5)
  #pragma unroll
  for (int o = 0; o < 10; ++o) {
    sacc[o] += __shfl_xor(sacc[o], 16, 64);
    sacc[o] += __shfl_xor(sacc[o], 32, 64);
  }
  __shared__ float red[4][160];
  if (lane < 16) {
    #pragma unroll
    for (int o = 0; o < 10; ++o) red[wv][o*16 + d] = sacc[o];
  }
  __syncthreads();
  if (tid < 160) {
    float s = red[0][tid] + red[1][tid] + red[2][tid] + red[3][tid];
    cpart[((size_t)b*7 + sl)*160 + tid] = s;
  }
}

// ---------------- class routing: reduce partials + squash ----------------
__global__ __launch_bounds__(160) void cls_finish(const float* __restrict__ cpart,
                                                  float* __restrict__ vout, float fac) {
  int b = blockIdx.x, od = threadIdx.x;
  float s = 0.f;
  #pragma unroll
  for (int sl = 0; sl < 7; ++sl) s += cpart[((size_t)b*7 + sl)*160 + od];
  s *= fac;
  float nrm = s*s;
  #pragma unroll
  for (int off = 8; off; off >>= 1) nrm += __shfl_xor(nrm, off, 16);
  float sc = nrm / ((1.f + nrm)*sqrtf(nrm + 1e-6f));
  vout[(size_t)b*160 + od] = s*sc;
}

// ---------------- host launch ----------------
extern "C" void kernel_launch(void* const* d_in, const int* in_sizes, int n_in,
                              void* d_out, int out_size, void* d_ws, size_t ws_size,
                              hipStream_t stream) {
  const float* images = (const float*)d_in[0];
  const float* w1  = (const float*)d_in[1];
  const float* g1  = (const float*)d_in[2];
  const float* b1  = (const float*)d_in[3];
  const float* w2  = (const float*)d_in[4];
  const float* g2  = (const float*)d_in[5];
  const float* b2  = (const float*)d_in[6];
  const float* w3  = (const float*)d_in[7];
  const float* g3  = (const float*)d_in[8];
  const float* b3  = (const float*)d_in[9];
  const float* wp  = (const float*)d_in[10];
  const float* bp  = (const float*)d_in[11];
  const float* wcc = (const float*)d_in[12];
  const float* wcl = (const float*)d_in[13];
  float* out = (float*)d_out;
  float* ws  = (float*)d_ws;

  // persistent regions (float offsets)
  float* t1    = ws + 0;            // 3,145,728
  float* t2    = ws + 3145728;      // 1,572,864
  float* t3    = ws + 4718592;      // 3,145,728
  float* pc    = ws + 7864320;      //   602,112
  float* uu    = ws + 8466432;      // 5,419,008
  float* u2b   = ws + 13885440;     //   602,112
  unsigned short* uh2b = (unsigned short*)(ws + 14487552);  // 8,028,160 ushorts
  float* b2l   = ws + 22515712;     //   501,760
  float* scrC  = ws + 23017472;     //   501,760 (BN stats during convs, cpart during class)
  float* v2    = ws + 23519232;     //    10,240
  float* spart = ws + 23529472;     //     3,072 (conv1 BN)
  float* ssc1  = ws + 23532544;     //        96
  float* ssc2  = ws + 23532640;     //       192
  float* ssc3  = ws + 23532832;     //       384
  float* U     = ws + 23533312;     // arena, 10,838,016 f32
  __hip_bfloat16* uhc = (__hip_bfloat16*)U;

  // split/reordered weights live in dead `uu` region (dead until uu_gather)
  unsigned short* wh2 = (unsigned short*)(uu + 0);
  unsigned short* wl2 = (unsigned short*)(uu + 20736);
  unsigned short* wh3 = (unsigned short*)(uu + 41472);
  unsigned short* wl3 = (unsigned short*)(uu + 124416);
  unsigned short* whp = (unsigned short*)(uu + 207360);
  unsigned short* wlp = (unsigned short*)(uu + 373248);

  // phase transients in the U arena
  unsigned short* x2h = (unsigned short*)(U + 0);
  unsigned short* x2l = (unsigned short*)(U + 1775616);
  float*          part2 = U + 3551232;                    // 3x96x16384
  unsigned short* x3h = (unsigned short*)(U + 0);
  unsigned short* x3l = (unsigned short*)(U + 995328);
  float*          part3 = U + 1990656;                    // 2x192x16384
  unsigned short* xph = (unsigned short*)(U + 0);
  unsigned short* xpl = (unsigned short*)(U + 1572864);
  float*          partp = U + 3145728;                    // 8x192x3136

  const int B = 64;

  // weight splits
  split_w<<<(96*432+255)/256,256,0,stream>>>(w2, wh2, wl2, 96, 48);
  split_w<<<(192*864+255)/256,256,0,stream>>>(w3, wh3, wl3, 192, 96);
  split_w<<<(192*1728+255)/256,256,0,stream>>>(wp, whp, wlp, 192, 192);

  // conv1 + BN1 stats
  conv1_fused<<<2048,192,0,stream>>>(images, w1, t1);
  bn_partial<48,1024,8><<<48*8,256,0,stream>>>(t1, spart, B);
  bn_final<48,8><<<1,64,0,stream>>>(spart, g1, b1, ssc1, 65536);

  // conv2: BN1+ReLU+split (with halos), MFMA, reduce+stats
  bn_split_nhwc<48,32,32,1><<<64*34,256,0,stream>>>(t1, ssc1, x2h, x2l);
  conv_mfma<48,34,34,16,16,2,3><<<dim3(2,128,3),256,0,stream>>>(x2h, x2l, wh2, wl2, part2, 96, B);
  splitk_reduce<96,256,3,false,true><<<6144,256,0,stream>>>(part2, nullptr, t2, scrC, B);
  bn_final<96,64><<<1,128,0,stream>>>(scrC, g2, b2, ssc2, 16384);

  // conv3
  bn_split_nhwc<96,16,16,1><<<64*18,256,0,stream>>>(t2, ssc2, x3h, x3l);
  conv_mfma<96,18,18,16,16,1,2><<<dim3(3,128,2),256,0,stream>>>(x3h, x3l, wh3, wl3, part3, 192, B);
  splitk_reduce<192,256,2,false,true><<<12288,256,0,stream>>>(part3, nullptr, t3, scrC, B);
  bn_final<192,64><<<1,192,0,stream>>>(scrC, g3, b3, ssc3, 16384);

  // primary caps conv + bias, then squash
  bn_split_nhwc<192,16,16,0><<<64*16,256,0,stream>>>(t3, ssc3, xph, xpl);
  conv_mfma<192,16,16,7,7,2,8><<<dim3(3,25,8),256,0,stream>>>(xph, xpl, whp, wlp, partp, 192, B);
  splitk_reduce<192,49,8,true,false><<<2352,256,0,stream>>>(partp, bp, pc, nullptr, B);
  squash_pc<<<196,256,0,stream>>>(pc, 50176);

  // uu gather
  uu_gather<<<21168,256,0,stream>>>(pc, uu, B);
  // ConvCaps einsum + fused in-LDS routing, chunked over b
  for (int cb = 0; cb < 4; ++cb) {
    cc_einsum2<<<dim3(144,13),192,0,stream>>>(uu, wcc, uhc, cb*784, 784);
    cc_route<<<784,512,0,stream>>>(uhc, u2b, cb*16);
  }
  // Class caps einsum (bf16) + wave-local routing
  class_einsum<<<784,320,0,stream>>>(u2b, wcl, uh2b, B);
  cls_pass<0><<<dim3(64,7),256,0,stream>>>(uh2b, v2, b2l, scrC);
  cls_finish<<<64,160,0,stream>>>(scrC, v2, 0.1f);
  cls_pass<1><<<dim3(64,7),256,0,stream>>>(uh2b, v2, b2l, scrC);
  cls_finish<<<64,160,0,stream>>>(scrC, v2, 1.0f);
  cls_pass<2><<<dim3(64,7),256,0,stream>>>(uh2b, v2, b2l, scrC);
  cls_finish<<<64,160,0,stream>>>(scrC, out, 1.0f);
  (void)in_sizes; (void)n_in; (void)out_size; (void)ws_size;
}

// Round 8
// 410.670 us; speedup vs baseline: 5.8835x; 1.0930x over previous
//
#include <hip/hip_runtime.h>
#include <hip/hip_bf16.h>

typedef __attribute__((ext_vector_type(4))) short short4v;
typedef __attribute__((ext_vector_type(8))) short short8v;
typedef __attribute__((ext_vector_type(16))) float f32x16;

union frag8 { short8v v8; struct { short4v lo, hi; } p; };

__device__ __forceinline__ unsigned short f2bf(float v) {
  unsigned u = __float_as_uint(v);
  unsigned r = u + 0x7fffu + ((u >> 16) & 1u);
  return (unsigned short)(r >> 16);
}
__device__ __forceinline__ float bf2f(unsigned short h) {
  return __uint_as_float(((unsigned)h) << 16);
}

// ---------------- conv1: one block per (b,h), LDS input slab, weights in regs ----------------
__global__ __launch_bounds__(192) void conv1_fused(const float* __restrict__ images,
                                                   const float* __restrict__ w1,
                                                   float* __restrict__ out) {
  int b = blockIdx.x >> 5, h = blockIdx.x & 31;
  __shared__ __align__(16) float lin[3][3][36];
  int tid = threadIdx.x;
  for (int e = tid; e < 324; e += 192) {
    int ci = e / 108, rem = e % 108, ki = rem / 36, wi = rem % 36;
    int row = h + ki - 1, col = wi - 1;
    float v = 0.f;
    if (row >= 0 && row < 32 && col >= 0 && col < 32)
      v = images[((size_t)(b*3 + ci)*32 + row)*32 + col];
    lin[ci][ki][wi] = v;
  }
  int co = tid >> 2, ws = tid & 3;
  float wr[27];
  #pragma unroll
  for (int j = 0; j < 27; ++j) wr[j] = w1[co*27 + j];
  __syncthreads();
  float o[8];
  #pragma unroll
  for (int j = 0; j < 8; ++j) o[j] = 0.f;
  #pragma unroll
  for (int ci = 0; ci < 3; ++ci)
    #pragma unroll
    for (int ki = 0; ki < 3; ++ki) {
      float4 q0 = *(const float4*)&lin[ci][ki][ws*8];
      float4 q1 = *(const float4*)&lin[ci][ki][ws*8+4];
      float4 q2 = *(const float4*)&lin[ci][ki][ws*8+8];
      float r[12] = {q0.x,q0.y,q0.z,q0.w,q1.x,q1.y,q1.z,q1.w,q2.x,q2.y,q2.z,q2.w};
      #pragma unroll
      for (int kj = 0; kj < 3; ++kj) {
        float wv = wr[(ci*3+ki)*3+kj];
        #pragma unroll
        for (int j = 0; j < 8; ++j) o[j] = fmaf(r[j+kj], wv, o[j]);
      }
    }
  float* dst = out + (((size_t)(b*48+co)*32 + h)*32 + ws*8);
  *(float4*)dst       = make_float4(o[0],o[1],o[2],o[3]);
  *(float4*)(dst + 4) = make_float4(o[4],o[5],o[6],o[7]);
}

// ---------------- merged weight split+reorder for conv2/conv3/primary ----------------
__device__ __forceinline__ void split_one(const float* w, unsigned short* wh,
                                          unsigned short* wl, int CI, int i) {
  int K = CI*9;
  int co = i / K, rem = i % K, tap = rem / CI, ci = rem % CI;
  float v = w[(co*CI + ci)*9 + tap];
  unsigned short h = f2bf(v);
  wh[i] = h;
  wl[i] = f2bf(v - bf2f(h));
}
__global__ void split_w_all(const float* __restrict__ w2, const float* __restrict__ w3,
                            const float* __restrict__ wp,
                            unsigned short* wh2, unsigned short* wl2,
                            unsigned short* wh3, unsigned short* wl3,
                            unsigned short* whp, unsigned short* wlp) {
  int i = blockIdx.x*256 + threadIdx.x;
  if (i < 41472) split_one(w2, wh2, wl2, 48, i);
  else if (i < 207360) split_one(w3, wh3, wl3, 96, i - 41472);
  else if (i < 539136) split_one(wp, whp, wlp, 192, i - 207360);
}

// ---------------- BN affine + ReLU + split to padded NHWC bf16 hi/lo (writes halos) ----------------
template<int C,int H,int W,int P>
__global__ void bn_split_nhwc(const float* __restrict__ in, const float* __restrict__ sc,
                              unsigned short* __restrict__ xh, unsigned short* __restrict__ xl) {
  constexpr int HP = H + 2*P, WP = W + 2*P;
  int b = blockIdx.x / HP, hp = blockIdx.x % HP;
  int h = hp - P;
  for (int e = threadIdx.x; e < WP*C; e += 256) {
    int wp = e / C, c = e % C;
    int w = wp - P;
    float v = 0.f;
    if (h >= 0 && h < H && w >= 0 && w < W) {
      v = in[((size_t)(b*C + c)*H + h)*W + w];
      v = fmaf(v, sc[c*2], sc[c*2+1]);
      v = v > 0.f ? v : 0.f;
    }
    unsigned short hh = f2bf(v);
    size_t o = ((size_t)(b*HP + hp)*WP + wp)*C + c;
    xh[o] = hh;
    xl[o] = f2bf(v - bf2f(hh));
  }
}

// ---------------- MFMA implicit-GEMM conv; SPLITK==1 writes NCHW directly ----------------
template<int CI,int HIP,int WIP,int HO,int WO,int STR,int SPLITK>
__global__ __launch_bounds__(256,4) void conv_mfma(
    const unsigned short* __restrict__ xh, const unsigned short* __restrict__ xl,
    const unsigned short* __restrict__ wh, const unsigned short* __restrict__ wl,
    float* __restrict__ part, int CO, int B) {
  constexpr int K = CI*9, NSP = HO*WO, KCH = K/SPLITK, LDA = 36;
  const int NTOT = B*NSP;
  const int m0 = blockIdx.x*64, n0 = blockIdx.y*128, ks = blockIdx.z;
  __shared__ unsigned short Ah[64*LDA], Al[64*LDA], Bh[128*LDA], Bl[128*LDA];
  const int tid = threadIdx.x, lane = tid & 63, wid = tid >> 6;
  const int wm = wid >> 1, wn = wid & 1;
  const int arow = tid >> 2, ak0 = (tid & 3)*8;
  const bool aok = (m0 + arow) < CO;
  const size_t abase = (size_t)(m0 + arow)*K;
  int brow[2], bk0[2];
  size_t bbase[2];
  #pragma unroll
  for (int i = 0; i < 2; ++i) {
    int e = tid + i*256;
    brow[i] = e >> 2; bk0[i] = (e & 3)*8;
    int nn = n0 + brow[i]; if (nn > NTOT-1) nn = NTOT-1;
    int bb = nn / NSP, sp = nn % NSP;
    int ho = sp / WO, wo = sp % WO;
    bbase[i] = ((size_t)bb*HIP + ho*STR)*WIP + wo*STR;
  }
  f32x16 acc0 = (f32x16)0.f, acc1 = (f32x16)0.f;
  const int kBeg = ks*KCH, kEnd = kBeg + KCH;
  for (int kc = kBeg; kc < kEnd; kc += 32) {
    const int kLim = (kEnd - kc) < 32 ? (kEnd - kc) : 32;
    {
      frag8 vh, vl;
      vh.v8 = (short8v)(short)0; vl.v8 = (short8v)(short)0;
      if (aok && ak0 < kLim) {
        size_t off = abase + kc + ak0;
        vh.v8 = *(const short8v*)(wh + off);
        vl.v8 = *(const short8v*)(wl + off);
      }
      int lo_ = arow*LDA + ak0;
      *(short4v*)(Ah + lo_) = vh.p.lo; *(short4v*)(Ah + lo_ + 4) = vh.p.hi;
      *(short4v*)(Al + lo_) = vl.p.lo; *(short4v*)(Al + lo_ + 4) = vl.p.hi;
    }
    #pragma unroll
    for (int i = 0; i < 2; ++i) {
      frag8 vh, vl;
      vh.v8 = (short8v)(short)0; vl.v8 = (short8v)(short)0;
      if (bk0[i] < kLim) {
        int kg = kc + bk0[i];
        int tap = kg / CI, ci0 = kg - tap*CI;
        int dh = tap / 3, dw = tap - dh*3;
        size_t off = (bbase[i] + (size_t)dh*WIP + dw)*CI + ci0;
        vh.v8 = *(const short8v*)(xh + off);
        vl.v8 = *(const short8v*)(xl + off);
      }
      int lo_ = brow[i]*LDA + bk0[i];
      *(short4v*)(Bh + lo_) = vh.p.lo; *(short4v*)(Bh + lo_ + 4) = vh.p.hi;
      *(short4v*)(Bl + lo_) = vl.p.lo; *(short4v*)(Bl + lo_ + 4) = vl.p.hi;
    }
    __syncthreads();
    #pragma unroll
    for (int kst = 0; kst < 2; ++kst) {
      const int kb = kst*16 + 8*(lane >> 5);
      const int ar = wm*32 + (lane & 31);
      frag8 ah, al;
      { int o = ar*LDA + kb;
        ah.p.lo = *(const short4v*)(Ah + o); ah.p.hi = *(const short4v*)(Ah + o + 4);
        al.p.lo = *(const short4v*)(Al + o); al.p.hi = *(const short4v*)(Al + o + 4); }
      const int br = wn*64 + (lane & 31);
      frag8 bh0, bl0, bh1, bl1;
      { int o = br*LDA + kb;
        bh0.p.lo = *(const short4v*)(Bh + o); bh0.p.hi = *(const short4v*)(Bh + o + 4);
        bl0.p.lo = *(const short4v*)(Bl + o); bl0.p.hi = *(const short4v*)(Bl + o + 4); }
      { int o = (br+32)*LDA + kb;
        bh1.p.lo = *(const short4v*)(Bh + o); bh1.p.hi = *(const short4v*)(Bh + o + 4);
        bl1.p.lo = *(const short4v*)(Bl + o); bl1.p.hi = *(const short4v*)(Bl + o + 4); }
      acc0 = __builtin_amdgcn_mfma_f32_32x32x16_bf16(ah.v8, bh0.v8, acc0, 0, 0, 0);
      acc0 = __builtin_amdgcn_mfma_f32_32x32x16_bf16(ah.v8, bl0.v8, acc0, 0, 0, 0);
      acc0 = __builtin_amdgcn_mfma_f32_32x32x16_bf16(al.v8, bh0.v8, acc0, 0, 0, 0);
      acc1 = __builtin_amdgcn_mfma_f32_32x32x16_bf16(ah.v8, bh1.v8, acc1, 0, 0, 0);
      acc1 = __builtin_amdgcn_mfma_f32_32x32x16_bf16(ah.v8, bl1.v8, acc1, 0, 0, 0);
      acc1 = __builtin_amdgcn_mfma_f32_32x32x16_bf16(al.v8, bh1.v8, acc1, 0, 0, 0);
    }
    __syncthreads();
  }
  #pragma unroll
  for (int ns = 0; ns < 2; ++ns) {
    f32x16 a = ns ? acc1 : acc0;
    #pragma unroll
    for (int r = 0; r < 16; ++r) {
      int row = (r & 3) + 8*(r >> 2) + 4*(lane >> 5);
      int m = m0 + wm*32 + row;
      int n = n0 + wn*64 + ns*32 + (lane & 31);
      if (m < CO && n < NTOT) {
        if (SPLITK == 1) {
          int b = n / NSP, sp = n % NSP;
          part[((size_t)b*CO + m)*NSP + sp] = a[r];
        } else {
          part[((size_t)ks*CO + m)*NTOT + n] = a[r];
        }
      }
    }
  }
}

// ---------------- split-K reduce (+bias, + optional fused BN partial stats) ----------------
template<int CO,int NSP,int SPLITK,bool BIAS,bool STATS>
__global__ void splitk_reduce(const float* __restrict__ part, const float* __restrict__ bias,
                              float* __restrict__ out, float* __restrict__ stats, int B) {
  const int NTOT = B*NSP;
  int i = blockIdx.x*256 + threadIdx.x;
  bool valid = i < CO*NTOT;
  float s = 0.f;
  if (valid) {
    int co = i / NTOT, n = i % NTOT;
    #pragma unroll
    for (int ks = 0; ks < SPLITK; ++ks) s += part[(size_t)(ks*CO + co)*NTOT + n];
    if (BIAS) s += bias[co];
    int b = n / NSP, sp = n % NSP;
    out[((size_t)b*CO + co)*NSP + sp] = s;
  }
  if (STATS) {
    float sum = valid ? s : 0.f, sq = valid ? s*s : 0.f;
    #pragma unroll
    for (int off = 32; off; off >>= 1) {
      sum += __shfl_down(sum, off, 64);
      sq  += __shfl_down(sq,  off, 64);
    }
    __shared__ float ls[2][4];
    int lane = threadIdx.x & 63, wv = threadIdx.x >> 6;
    if (lane == 0) { ls[0][wv] = sum; ls[1][wv] = sq; }
    __syncthreads();
    if (threadIdx.x == 0) {
      float S = 0.f, Q = 0.f;
      #pragma unroll
      for (int j = 0; j < 4; ++j) { S += ls[0][j]; Q += ls[1][j]; }
      int bpc = NTOT/256;
      int co = blockIdx.x / bpc, slice = blockIdx.x % bpc;
      stats[(co*bpc + slice)*2 + 0] = S;
      stats[(co*bpc + slice)*2 + 1] = Q;
    }
  }
}

// ---------------- BN stats ----------------
template<int C,int HW,int SLICES>
__global__ void bn_partial(const float* __restrict__ x, float* __restrict__ part, int B) {
  int c = blockIdx.x / SLICES, s = blockIdx.x % SLICES;
  int bpp = B / SLICES;
  float sum = 0.f, sq = 0.f;
  for (int b = s*bpp; b < (s+1)*bpp; ++b) {
    const float* p = x + ((size_t)b*C + c)*HW;
    for (int i = threadIdx.x; i < HW; i += blockDim.x) {
      float v = p[i]; sum += v; sq += v*v;
    }
  }
  #pragma unroll
  for (int off = 32; off; off >>= 1) {
    sum += __shfl_down(sum, off, 64);
    sq  += __shfl_down(sq,  off, 64);
  }
  __shared__ float ls[2][4];
  int lane = threadIdx.x & 63, wv = threadIdx.x >> 6;
  if (lane == 0) { ls[0][wv] = sum; ls[1][wv] = sq; }
  __syncthreads();
  if (threadIdx.x == 0) {
    float S = 0.f, Q = 0.f;
    #pragma unroll
    for (int i = 0; i < 4; ++i) { S += ls[0][i]; Q += ls[1][i]; }
    part[(c*SLICES+s)*2+0] = S; part[(c*SLICES+s)*2+1] = Q;
  }
}

template<int C,int SLICES>
__global__ void bn_final(const float* __restrict__ part, const float* __restrict__ g,
                         const float* __restrict__ bta, float* __restrict__ sc, int NHW) {
  int c = blockIdx.x*blockDim.x + threadIdx.x;
  if (c >= C) return;
  float S = 0.f, Q = 0.f;
  for (int s = 0; s < SLICES; ++s) { S += part[(c*SLICES+s)*2]; Q += part[(c*SLICES+s)*2+1]; }
  float m = S / NHW, v = Q / NHW - m*m;
  float inv = rsqrtf(v + 1e-5f);
  float a = g[c] * inv;
  sc[c*2] = a; sc[c*2+1] = bta[c] - m*a;
}

// ---------------- squash primary caps in place ----------------
__global__ void squash_pc(float* __restrict__ pc, int ncaps) {
  int i = blockIdx.x*blockDim.x + threadIdx.x;
  if (i >= ncaps) return;
  float* p = pc + (size_t)i*12;
  float v[12]; float s = 0.f;
  #pragma unroll
  for (int d = 0; d < 12; ++d) { v[d] = p[d]; s += v[d]*v[d]; }
  float sc = s / ((1.f + s)*sqrtf(s + 1e-6f));
  #pragma unroll
  for (int d = 0; d < 12; ++d) p[d] = v[d]*sc;
}

// ---------------- uu gather ----------------
__global__ void uu_gather(const float* __restrict__ sq, float* __restrict__ uu, int B) {
  int idx = blockIdx.x*blockDim.x + threadIdx.x;
  int total = B*49*144*12;
  if (idx >= total) return;
  int ii = idx % 12; int t0 = idx / 12;
  int kk = t0 % 144; t0 /= 144;
  int tt = t0 % 49;  int b = t0 / 49;
  int f = tt*1728 + kk*12 + ii;
  int c = f / 441; int r = f - c*441;
  int k = r / 49;  int sp = r - k*49;
  int y = sp / 7, x = sp - y*7;
  int iy = y + k/3 - 1, ix = x + (k%3) - 1;
  float val = 0.f;
  if (iy >= 0 && iy < 7 && ix >= 0 && ix < 7)
    val = sq[((size_t)(b*192 + c)*7 + iy)*7 + ix];
  uu[idx] = val;
}

// ---------------- ConvCaps einsum: broadcast global reads, no LDS ----------------
__global__ __launch_bounds__(192) void cc_einsum2(const float* __restrict__ uu,
                                                  const float* __restrict__ wcc,
                                                  __hip_bfloat16* __restrict__ uhat,
                                                  int row0, int nrows) {
  int k  = blockIdx.x;
  int m0 = blockIdx.y * 64;
  int o = threadIdx.x;
  const float4* wp4 = (const float4*)(wcc + ((size_t)k*192 + o)*12);
  float4 w0 = wp4[0], w1 = wp4[1], w2 = wp4[2];
  int mmax = nrows - m0; if (mmax > 64) mmax = 64;
  #pragma unroll 2
  for (int m = 0; m < mmax; ++m) {
    const float4* ar = (const float4*)(uu + ((size_t)(row0+m0+m)*144 + k)*12);
    float4 a0 = ar[0], a1 = ar[1], a2 = ar[2];
    float acc = a0.x*w0.x + a0.y*w0.y + a0.z*w0.z + a0.w*w0.w
              + a1.x*w1.x + a1.y*w1.y + a1.z*w1.z + a1.w*w1.w
              + a2.x*w2.x + a2.y*w2.y + a2.z*w2.z + a2.w*w2.w;
    uhat[((size_t)(m0+m)*144 + k)*192 + o] = __float2bfloat16(acc);
  }
}

// ---------------- ConvCaps routing: u_hat read from global (L2/L3-served), small LDS ----------------
__global__ __launch_bounds__(512) void cc_route(const __hip_bfloat16* __restrict__ uhat,
                                                float* __restrict__ u2, int rowOff) {
  const int row = blockIdx.x;
  const unsigned short* __restrict__ uh = (const unsigned short*)uhat + (size_t)row*27648;
  __shared__ float blog[144*16];   // [k][oc]
  __shared__ float cc[144*16];
  __shared__ float sv8[8][192];
  __shared__ float sv0[192];
  __shared__ float svs[192];
  const int tid = threadIdx.x;
  for (int i = tid; i < 2304; i += 512) blog[i] = 0.f;
  __syncthreads();
  for (int r = 0; r < 3; ++r) {
    // softmax over oc per k
    if (tid < 144) {
      float mx = -1e30f;
      #pragma unroll
      for (int o = 0; o < 16; ++o) mx = fmaxf(mx, blog[tid*16+o]);
      float e[16]; float ssum = 0.f;
      #pragma unroll
      for (int o = 0; o < 16; ++o) { e[o] = __expf(blog[tid*16+o]-mx); ssum += e[o]; }
      float inv = 1.f/ssum;
      #pragma unroll
      for (int o = 0; o < 16; ++o) cc[tid*16+o] = e[o]*inv;
    }
    __syncthreads();
    // s-compute: thread = (q 0..7, o4 0..47); 18 k's per q; uint2 = 4 bf16 per load
    if (tid < 384) {
      int q = tid / 48, o4 = tid % 48;
      int oc = o4 / 3;            // all 4 o's share the same oc
      const unsigned short* up = uh + o4*4;
      float a0 = 0.f, a1 = 0.f, a2 = 0.f, a3 = 0.f;
      #pragma unroll 6
      for (int k = q*18; k < q*18+18; ++k) {
        uint2 u = *(const uint2*)(up + k*192);
        float c = cc[k*16 + oc];
        a0 = fmaf(c, bf2f((unsigned short)(u.x & 0xffff)), a0);
        a1 = fmaf(c, bf2f((unsigned short)(u.x >> 16)),   a1);
        a2 = fmaf(c, bf2f((unsigned short)(u.y & 0xffff)), a2);
        a3 = fmaf(c, bf2f((unsigned short)(u.y >> 16)),   a3);
      }
      sv8[q][o4*4+0] = a0; sv8[q][o4*4+1] = a1;
      sv8[q][o4*4+2] = a2; sv8[q][o4*4+3] = a3;
    }
    __syncthreads();
    if (tid < 192) {
      float s = 0.f;
      #pragma unroll
      for (int q = 0; q < 8; ++q) s += sv8[q][tid];
      sv0[tid] = s;
    }
    __syncthreads();
    // squash (each of 192 threads recomputes its oc's norm; writes to svs)
    if (tid < 192) {
      int oc = tid / 12;
      float nrm = 0.f;
      #pragma unroll
      for (int d = 0; d < 12; ++d) { float v = sv0[oc*12+d]; nrm += v*v; }
      float sc = nrm / ((1.f + nrm)*sqrtf(nrm + 1e-6f));
      svs[tid] = sv0[tid]*sc;
    }
    __syncthreads();
    if (r < 2) {
      for (int p = tid; p < 2304; p += 512) {
        int k = p >> 4, oc = p & 15;
        const unsigned short* up = uh + k*192 + oc*12;
        uint2 u0 = *(const uint2*)(up);
        uint2 u1 = *(const uint2*)(up + 4);
        uint2 u2v = *(const uint2*)(up + 8);
        const float* vp = svs + oc*12;
        float dot = 0.f;
        dot = fmaf(vp[0],  bf2f((unsigned short)(u0.x & 0xffff)), dot);
        dot = fmaf(vp[1],  bf2f((unsigned short)(u0.x >> 16)),    dot);
        dot = fmaf(vp[2],  bf2f((unsigned short)(u0.y & 0xffff)), dot);
        dot = fmaf(vp[3],  bf2f((unsigned short)(u0.y >> 16)),    dot);
        dot = fmaf(vp[4],  bf2f((unsigned short)(u1.x & 0xffff)), dot);
        dot = fmaf(vp[5],  bf2f((unsigned short)(u1.x >> 16)),    dot);
        dot = fmaf(vp[6],  bf2f((unsigned short)(u1.y & 0xffff)), dot);
        dot = fmaf(vp[7],  bf2f((unsigned short)(u1.y >> 16)),    dot);
        dot = fmaf(vp[8],  bf2f((unsigned short)(u2v.x & 0xffff)), dot);
        dot = fmaf(vp[9],  bf2f((unsigned short)(u2v.x >> 16)),    dot);
        dot = fmaf(vp[10], bf2f((unsigned short)(u2v.y & 0xffff)), dot);
        dot = fmaf(vp[11], bf2f((unsigned short)(u2v.y >> 16)),    dot);
        blog[p] += dot;
      }
      __syncthreads();
    }
  }
  if (tid < 192) u2[((size_t)(rowOff + row))*192 + tid] = svs[tid];
}

// ---------------- Class caps einsum (bf16 output) ----------------
__global__ void class_einsum(const float* __restrict__ u2, const float* __restrict__ wcl,
                             unsigned short* __restrict__ uhat2, int B) {
  int n = blockIdx.x;
  __shared__ float u2l[64][12];
  int tid = threadIdx.x;
  for (int e = tid; e < 64*12; e += 320) {
    int b = e / 12, i = e % 12;
    u2l[b][i] = u2[(size_t)b*9408 + n*12 + i];
  }
  __syncthreads();
  int od = tid % 160, bh = tid / 160;
  int o = od >> 4, d = od & 15;
  float w[12];
  #pragma unroll
  for (int i = 0; i < 12; ++i) w[i] = wcl[(size_t)n*1920 + o*192 + d*12 + i];
  for (int b = bh*32; b < bh*32+32; ++b) {
    float acc = 0.f;
    #pragma unroll
    for (int i = 0; i < 12; ++i) acc = fmaf(w[i], u2l[b][i], acc);
    uhat2[((size_t)b*784 + n)*160 + od] = f2bf(acc);
  }
}

// ---------------- class routing: wave-local pass, no barriers in main loop ----------------
template<int MODE>
__global__ __launch_bounds__(256) void cls_pass(const unsigned short* __restrict__ uh2b,
                                                const float* __restrict__ vprev,
                                                float* __restrict__ b2l,
                                                float* __restrict__ cpart) {
  const int b = blockIdx.x, sl = blockIdx.y;   // sl 0..6
  const int tid = threadIdx.x, lane = tid & 63, wv = tid >> 6;
  const int nl = lane >> 4, d = lane & 15;
  float v[10];
  if (MODE != 0) {
    #pragma unroll
    for (int o = 0; o < 10; ++o) v[o] = vprev[b*160 + o*16 + d];
  }
  float sacc[10];
  #pragma unroll
  for (int o = 0; o < 10; ++o) sacc[o] = 0.f;
  for (int step = 0; step < 7; ++step) {
    const int n = sl*112 + step*16 + wv*4 + nl;
    const unsigned short* up = uh2b + ((size_t)b*784 + n)*160 + d;
    float u[10];
    #pragma unroll
    for (int o = 0; o < 10; ++o) u[o] = bf2f(up[o*16]);
    if (MODE == 0) {
      #pragma unroll
      for (int o = 0; o < 10; ++o) sacc[o] += u[o];
    } else {
      float bb[10];
      #pragma unroll
      for (int o = 0; o < 10; ++o) {
        float t = v[o]*u[o];
        #pragma unroll
        for (int off = 8; off; off >>= 1) t += __shfl_xor(t, off, 16);
        bb[o] = t;
      }
      if (MODE == 2) {
        #pragma unroll
        for (int o = 0; o < 10; ++o) bb[o] += b2l[((size_t)b*784 + n)*10 + o];
      }
      if (MODE == 1 && d < 10) b2l[((size_t)b*784 + n)*10 + d] = bb[d];
      float mx = bb[0];
      #pragma unroll
      for (int o = 1; o < 10; ++o) mx = fmaxf(mx, bb[o]);
      float es = 0.f;
      #pragma unroll
      for (int o = 0; o < 10; ++o) { bb[o] = __expf(bb[o]-mx); es += bb[o]; }
      float inv = 1.f/es;
      #pragma unroll
      for (int o = 0; o < 10; ++o) sacc[o] = fmaf(bb[o]*inv, u[o], sacc[o]);
    }
  }
  #pragma unroll
  for (int o = 0; o < 10; ++o) {
    sacc[o] += __shfl_xor(sacc[o], 16, 64);
    sacc[o] += __shfl_xor(sacc[o], 32, 64);
  }
  __shared__ float red[4][160];
  if (lane < 16) {
    #pragma unroll
    for (int o = 0; o < 10; ++o) red[wv][o*16 + d] = sacc[o];
  }
  __syncthreads();
  if (tid < 160) {
    float s = red[0][tid] + red[1][tid] + red[2][tid] + red[3][tid];
    cpart[((size_t)b*7 + sl)*160 + tid] = s;
  }
}

__global__ __launch_bounds__(160) void cls_finish(const float* __restrict__ cpart,
                                                  float* __restrict__ vout, float fac) {
  int b = blockIdx.x, od = threadIdx.x;
  float s = 0.f;
  #pragma unroll
  for (int sl = 0; sl < 7; ++sl) s += cpart[((size_t)b*7 + sl)*160 + od];
  s *= fac;
  float nrm = s*s;
  #pragma unroll
  for (int off = 8; off; off >>= 1) nrm += __shfl_xor(nrm, off, 16);
  float sc = nrm / ((1.f + nrm)*sqrtf(nrm + 1e-6f));
  vout[(size_t)b*160 + od] = s*sc;
}

// ---------------- host launch ----------------
extern "C" void kernel_launch(void* const* d_in, const int* in_sizes, int n_in,
                              void* d_out, int out_size, void* d_ws, size_t ws_size,
                              hipStream_t stream) {
  const float* images = (const float*)d_in[0];
  const float* w1  = (const float*)d_in[1];
  const float* g1  = (const float*)d_in[2];
  const float* b1  = (const float*)d_in[3];
  const float* w2  = (const float*)d_in[4];
  const float* g2  = (const float*)d_in[5];
  const float* b2  = (const float*)d_in[6];
  const float* w3  = (const float*)d_in[7];
  const float* g3  = (const float*)d_in[8];
  const float* b3  = (const float*)d_in[9];
  const float* wp  = (const float*)d_in[10];
  const float* bp  = (const float*)d_in[11];
  const float* wcc = (const float*)d_in[12];
  const float* wcl = (const float*)d_in[13];
  float* out = (float*)d_out;
  float* ws  = (float*)d_ws;

  // persistent regions (float offsets)
  float* t1    = ws + 0;            // 3,145,728
  float* t2    = ws + 3145728;      // 1,572,864
  float* t3    = ws + 4718592;      // 3,145,728
  float* pc    = ws + 7864320;      //   602,112
  float* uu    = ws + 8466432;      // 5,419,008
  float* u2b   = ws + 13885440;     //   602,112
  unsigned short* uh2b = (unsigned short*)(ws + 14487552);  // 8,028,160 ushorts
  float* b2l   = ws + 22515712;     //   501,760
  float* scrC  = ws + 23017472;     //   501,760 (BN stats during convs, cpart during class)
  float* v2    = ws + 23519232;     //    10,240
  float* spart = ws + 23529472;     //     3,072
  float* ssc1  = ws + 23532544;     //        96
  float* ssc2  = ws + 23532640;     //       192
  float* ssc3  = ws + 23532832;     //       384
  float* U     = ws + 23533312;     // arena, 10,838,016 f32 (conv transients)
  __hip_bfloat16* uhc = (__hip_bfloat16*)(ws + 34371328);   // 43,352,064 bf16 (one 32-img chunk)

  // split/reordered weights live in dead `uu` region (dead until uu_gather)
  unsigned short* wh2 = (unsigned short*)(uu + 0);
  unsigned short* wl2 = (unsigned short*)(uu + 20736);
  unsigned short* wh3 = (unsigned short*)(uu + 41472);
  unsigned short* wl3 = (unsigned short*)(uu + 124416);
  unsigned short* whp = (unsigned short*)(uu + 207360);
  unsigned short* wlp = (unsigned short*)(uu + 373248);

  // phase transients in the U arena
  unsigned short* x2h = (unsigned short*)(U + 0);
  unsigned short* x2l = (unsigned short*)(U + 1775616);
  float*          part2 = U + 3551232;                    // 3x96x16384
  unsigned short* x3h = (unsigned short*)(U + 0);
  unsigned short* x3l = (unsigned short*)(U + 995328);
  unsigned short* xph = (unsigned short*)(U + 0);
  unsigned short* xpl = (unsigned short*)(U + 1572864);
  float*          partp = U + 3145728;                    // 8x192x3136

  const int B = 64;

  // merged weight splits
  split_w_all<<<2106,256,0,stream>>>(w2, w3, wp, wh2, wl2, wh3, wl3, whp, wlp);

  // conv1 + BN1 stats
  conv1_fused<<<2048,192,0,stream>>>(images, w1, t1);
  bn_partial<48,1024,8><<<48*8,256,0,stream>>>(t1, spart, B);
  bn_final<48,8><<<1,64,0,stream>>>(spart, g1, b1, ssc1, 65536);

  // conv2: BN1+ReLU+split (with halos), MFMA split-K=3, reduce+stats
  bn_split_nhwc<48,32,32,1><<<64*34,256,0,stream>>>(t1, ssc1, x2h, x2l);
  conv_mfma<48,34,34,16,16,2,3><<<dim3(2,128,3),256,0,stream>>>(x2h, x2l, wh2, wl2, part2, 96, B);
  splitk_reduce<96,256,3,false,true><<<6144,256,0,stream>>>(part2, nullptr, t2, scrC, B);
  bn_final<96,64><<<1,128,0,stream>>>(scrC, g2, b2, ssc2, 16384);

  // conv3: direct NCHW write (split-K=1), stats via bn_partial
  bn_split_nhwc<96,16,16,1><<<64*18,256,0,stream>>>(t2, ssc2, x3h, x3l);
  conv_mfma<96,18,18,16,16,1,1><<<dim3(3,128,1),256,0,stream>>>(x3h, x3l, wh3, wl3, t3, 192, B);
  bn_partial<192,256,8><<<192*8,256,0,stream>>>(t3, spart, B);
  bn_final<192,8><<<1,192,0,stream>>>(spart, g3, b3, ssc3, 16384);

  // primary caps conv + bias, then squash
  bn_split_nhwc<192,16,16,0><<<64*16,256,0,stream>>>(t3, ssc3, xph, xpl);
  conv_mfma<192,16,16,7,7,2,8><<<dim3(3,25,8),256,0,stream>>>(xph, xpl, whp, wlp, partp, 192, B);
  splitk_reduce<192,49,8,true,false><<<2352,256,0,stream>>>(partp, bp, pc, nullptr, B);
  squash_pc<<<196,256,0,stream>>>(pc, 50176);

  // uu gather
  uu_gather<<<21168,256,0,stream>>>(pc, uu, B);
  // ConvCaps einsum + routing (u_hat L2/L3-served), 2 chunks of 32 images
  for (int cb = 0; cb < 2; ++cb) {
    cc_einsum2<<<dim3(144,25),192,0,stream>>>(uu, wcc, uhc, cb*1568, 1568);
    cc_route<<<1568,512,0,stream>>>(uhc, u2b, cb*1568);
  }
  // Class caps einsum (bf16) + wave-local routing
  class_einsum<<<784,320,0,stream>>>(u2b, wcl, uh2b, B);
  cls_pass<0><<<dim3(64,7),256,0,stream>>>(uh2b, v2, b2l, scrC);
  cls_finish<<<64,160,0,stream>>>(scrC, v2, 0.1f);
  cls_pass<1><<<dim3(64,7),256,0,stream>>>(uh2b, v2, b2l, scrC);
  cls_finish<<<64,160,0,stream>>>(scrC, v2, 1.0f);
  cls_pass<2><<<dim3(64,7),256,0,stream>>>(uh2b, v2, b2l, scrC);
  cls_finish<<<64,160,0,stream>>>(scrC, out, 1.0f);
  (void)in_sizes; (void)n_in; (void)out_size; (void)ws_size;
}

// Round 9
// 398.985 us; speedup vs baseline: 6.0558x; 1.0293x over previous
//
#include <hip/hip_runtime.h>
#include <hip/hip_bf16.h>

typedef __attribute__((ext_vector_type(4))) short short4v;
typedef __attribute__((ext_vector_type(8))) short short8v;
typedef __attribute__((ext_vector_type(16))) float f32x16;

union frag8 { short8v v8; struct { short4v lo, hi; } p; };

__device__ __forceinline__ unsigned short f2bf(float v) {
  unsigned u = __float_as_uint(v);
  unsigned r = u + 0x7fffu + ((u >> 16) & 1u);
  return (unsigned short)(r >> 16);
}
__device__ __forceinline__ float bf2f(unsigned short h) {
  return __uint_as_float(((unsigned)h) << 16);
}

// ---------------- conv1: one block per (b,h), LDS input slab, weights in regs ----------------
__global__ __launch_bounds__(192) void conv1_fused(const float* __restrict__ images,
                                                   const float* __restrict__ w1,
                                                   float* __restrict__ out) {
  int b = blockIdx.x >> 5, h = blockIdx.x & 31;
  __shared__ __align__(16) float lin[3][3][36];
  int tid = threadIdx.x;
  for (int e = tid; e < 324; e += 192) {
    int ci = e / 108, rem = e % 108, ki = rem / 36, wi = rem % 36;
    int row = h + ki - 1, col = wi - 1;
    float v = 0.f;
    if (row >= 0 && row < 32 && col >= 0 && col < 32)
      v = images[((size_t)(b*3 + ci)*32 + row)*32 + col];
    lin[ci][ki][wi] = v;
  }
  int co = tid >> 2, ws = tid & 3;
  float wr[27];
  #pragma unroll
  for (int j = 0; j < 27; ++j) wr[j] = w1[co*27 + j];
  __syncthreads();
  float o[8];
  #pragma unroll
  for (int j = 0; j < 8; ++j) o[j] = 0.f;
  #pragma unroll
  for (int ci = 0; ci < 3; ++ci)
    #pragma unroll
    for (int ki = 0; ki < 3; ++ki) {
      float4 q0 = *(const float4*)&lin[ci][ki][ws*8];
      float4 q1 = *(const float4*)&lin[ci][ki][ws*8+4];
      float4 q2 = *(const float4*)&lin[ci][ki][ws*8+8];
      float r[12] = {q0.x,q0.y,q0.z,q0.w,q1.x,q1.y,q1.z,q1.w,q2.x,q2.y,q2.z,q2.w};
      #pragma unroll
      for (int kj = 0; kj < 3; ++kj) {
        float wv = wr[(ci*3+ki)*3+kj];
        #pragma unroll
        for (int j = 0; j < 8; ++j) o[j] = fmaf(r[j+kj], wv, o[j]);
      }
    }
  float* dst = out + (((size_t)(b*48+co)*32 + h)*32 + ws*8);
  *(float4*)dst       = make_float4(o[0],o[1],o[2],o[3]);
  *(float4*)(dst + 4) = make_float4(o[4],o[5],o[6],o[7]);
}

// ---------------- merged weight split+reorder for conv2/conv3/primary ----------------
__device__ __forceinline__ void split_one(const float* w, unsigned short* wh,
                                          unsigned short* wl, int CI, int i) {
  int K = CI*9;
  int co = i / K, rem = i % K, tap = rem / CI, ci = rem % CI;
  float v = w[(co*CI + ci)*9 + tap];
  unsigned short h = f2bf(v);
  wh[i] = h;
  wl[i] = f2bf(v - bf2f(h));
}
__global__ void split_w_all(const float* __restrict__ w2, const float* __restrict__ w3,
                            const float* __restrict__ wp,
                            unsigned short* wh2, unsigned short* wl2,
                            unsigned short* wh3, unsigned short* wl3,
                            unsigned short* whp, unsigned short* wlp) {
  int i = blockIdx.x*256 + threadIdx.x;
  if (i < 41472) split_one(w2, wh2, wl2, 48, i);
  else if (i < 207360) split_one(w3, wh3, wl3, 96, i - 41472);
  else if (i < 539136) split_one(wp, whp, wlp, 192, i - 207360);
}

// ---------------- BN affine + ReLU + split to padded NHWC bf16 hi/lo (writes halos) ----------------
template<int C,int H,int W,int P>
__global__ void bn_split_nhwc(const float* __restrict__ in, const float* __restrict__ sc,
                              unsigned short* __restrict__ xh, unsigned short* __restrict__ xl) {
  constexpr int HP = H + 2*P, WP = W + 2*P;
  int b = blockIdx.x / HP, hp = blockIdx.x % HP;
  int h = hp - P;
  for (int e = threadIdx.x; e < WP*C; e += 256) {
    int wp = e / C, c = e % C;
    int w = wp - P;
    float v = 0.f;
    if (h >= 0 && h < H && w >= 0 && w < W) {
      v = in[((size_t)(b*C + c)*H + h)*W + w];
      v = fmaf(v, sc[c*2], sc[c*2+1]);
      v = v > 0.f ? v : 0.f;
    }
    unsigned short hh = f2bf(v);
    size_t o = ((size_t)(b*HP + hp)*WP + wp)*C + c;
    xh[o] = hh;
    xl[o] = f2bf(v - bf2f(hh));
  }
}

// ---------------- MFMA implicit-GEMM conv; SPLITK==1 writes NCHW directly ----------------
template<int CI,int HIP,int WIP,int HO,int WO,int STR,int SPLITK>
__global__ __launch_bounds__(256,4) void conv_mfma(
    const unsigned short* __restrict__ xh, const unsigned short* __restrict__ xl,
    const unsigned short* __restrict__ wh, const unsigned short* __restrict__ wl,
    float* __restrict__ part, int CO, int B) {
  constexpr int K = CI*9, NSP = HO*WO, KCH = K/SPLITK, LDA = 36;
  const int NTOT = B*NSP;
  const int m0 = blockIdx.x*64, n0 = blockIdx.y*128, ks = blockIdx.z;
  __shared__ unsigned short Ah[64*LDA], Al[64*LDA], Bh[128*LDA], Bl[128*LDA];
  const int tid = threadIdx.x, lane = tid & 63, wid = tid >> 6;
  const int wm = wid >> 1, wn = wid & 1;
  const int arow = tid >> 2, ak0 = (tid & 3)*8;
  const bool aok = (m0 + arow) < CO;
  const size_t abase = (size_t)(m0 + arow)*K;
  int brow[2], bk0[2];
  size_t bbase[2];
  #pragma unroll
  for (int i = 0; i < 2; ++i) {
    int e = tid + i*256;
    brow[i] = e >> 2; bk0[i] = (e & 3)*8;
    int nn = n0 + brow[i]; if (nn > NTOT-1) nn = NTOT-1;
    int bb = nn / NSP, sp = nn % NSP;
    int ho = sp / WO, wo = sp % WO;
    bbase[i] = ((size_t)bb*HIP + ho*STR)*WIP + wo*STR;
  }
  f32x16 acc0 = (f32x16)0.f, acc1 = (f32x16)0.f;
  const int kBeg = ks*KCH, kEnd = kBeg + KCH;
  for (int kc = kBeg; kc < kEnd; kc += 32) {
    const int kLim = (kEnd - kc) < 32 ? (kEnd - kc) : 32;
    {
      frag8 vh, vl;
      vh.v8 = (short8v)(short)0; vl.v8 = (short8v)(short)0;
      if (aok && ak0 < kLim) {
        size_t off = abase + kc + ak0;
        vh.v8 = *(const short8v*)(wh + off);
        vl.v8 = *(const short8v*)(wl + off);
      }
      int lo_ = arow*LDA + ak0;
      *(short4v*)(Ah + lo_) = vh.p.lo; *(short4v*)(Ah + lo_ + 4) = vh.p.hi;
      *(short4v*)(Al + lo_) = vl.p.lo; *(short4v*)(Al + lo_ + 4) = vl.p.hi;
    }
    #pragma unroll
    for (int i = 0; i < 2; ++i) {
      frag8 vh, vl;
      vh.v8 = (short8v)(short)0; vl.v8 = (short8v)(short)0;
      if (bk0[i] < kLim) {
        int kg = kc + bk0[i];
        int tap = kg / CI, ci0 = kg - tap*CI;
        int dh = tap / 3, dw = tap - dh*3;
        size_t off = (bbase[i] + (size_t)dh*WIP + dw)*CI + ci0;
        vh.v8 = *(const short8v*)(xh + off);
        vl.v8 = *(const short8v*)(xl + off);
      }
      int lo_ = brow[i]*LDA + bk0[i];
      *(short4v*)(Bh + lo_) = vh.p.lo; *(short4v*)(Bh + lo_ + 4) = vh.p.hi;
      *(short4v*)(Bl + lo_) = vl.p.lo; *(short4v*)(Bl + lo_ + 4) = vl.p.hi;
    }
    __syncthreads();
    #pragma unroll
    for (int kst = 0; kst < 2; ++kst) {
      const int kb = kst*16 + 8*(lane >> 5);
      const int ar = wm*32 + (lane & 31);
      frag8 ah, al;
      { int o = ar*LDA + kb;
        ah.p.lo = *(const short4v*)(Ah + o); ah.p.hi = *(const short4v*)(Ah + o + 4);
        al.p.lo = *(const short4v*)(Al + o); al.p.hi = *(const short4v*)(Al + o + 4); }
      const int br = wn*64 + (lane & 31);
      frag8 bh0, bl0, bh1, bl1;
      { int o = br*LDA + kb;
        bh0.p.lo = *(const short4v*)(Bh + o); bh0.p.hi = *(const short4v*)(Bh + o + 4);
        bl0.p.lo = *(const short4v*)(Bl + o); bl0.p.hi = *(const short4v*)(Bl + o + 4); }
      { int o = (br+32)*LDA + kb;
        bh1.p.lo = *(const short4v*)(Bh + o); bh1.p.hi = *(const short4v*)(Bh + o + 4);
        bl1.p.lo = *(const short4v*)(Bl + o); bl1.p.hi = *(const short4v*)(Bl + o + 4); }
      acc0 = __builtin_amdgcn_mfma_f32_32x32x16_bf16(ah.v8, bh0.v8, acc0, 0, 0, 0);
      acc0 = __builtin_amdgcn_mfma_f32_32x32x16_bf16(ah.v8, bl0.v8, acc0, 0, 0, 0);
      acc0 = __builtin_amdgcn_mfma_f32_32x32x16_bf16(al.v8, bh0.v8, acc0, 0, 0, 0);
      acc1 = __builtin_amdgcn_mfma_f32_32x32x16_bf16(ah.v8, bh1.v8, acc1, 0, 0, 0);
      acc1 = __builtin_amdgcn_mfma_f32_32x32x16_bf16(ah.v8, bl1.v8, acc1, 0, 0, 0);
      acc1 = __builtin_amdgcn_mfma_f32_32x32x16_bf16(al.v8, bh1.v8, acc1, 0, 0, 0);
    }
    __syncthreads();
  }
  #pragma unroll
  for (int ns = 0; ns < 2; ++ns) {
    f32x16 a = ns ? acc1 : acc0;
    #pragma unroll
    for (int r = 0; r < 16; ++r) {
      int row = (r & 3) + 8*(r >> 2) + 4*(lane >> 5);
      int m = m0 + wm*32 + row;
      int n = n0 + wn*64 + ns*32 + (lane & 31);
      if (m < CO && n < NTOT) {
        if (SPLITK == 1) {
          int b = n / NSP, sp = n % NSP;
          part[((size_t)b*CO + m)*NSP + sp] = a[r];
        } else {
          part[((size_t)ks*CO + m)*NTOT + n] = a[r];
        }
      }
    }
  }
}

// ---------------- split-K reduce (+bias, + optional fused BN partial stats) ----------------
template<int CO,int NSP,int SPLITK,bool BIAS,bool STATS>
__global__ void splitk_reduce(const float* __restrict__ part, const float* __restrict__ bias,
                              float* __restrict__ out, float* __restrict__ stats, int B) {
  const int NTOT = B*NSP;
  int i = blockIdx.x*256 + threadIdx.x;
  bool valid = i < CO*NTOT;
  float s = 0.f;
  if (valid) {
    int co = i / NTOT, n = i % NTOT;
    #pragma unroll
    for (int ks = 0; ks < SPLITK; ++ks) s += part[(size_t)(ks*CO + co)*NTOT + n];
    if (BIAS) s += bias[co];
    int b = n / NSP, sp = n % NSP;
    out[((size_t)b*CO + co)*NSP + sp] = s;
  }
  if (STATS) {
    float sum = valid ? s : 0.f, sq = valid ? s*s : 0.f;
    #pragma unroll
    for (int off = 32; off; off >>= 1) {
      sum += __shfl_down(sum, off, 64);
      sq  += __shfl_down(sq,  off, 64);
    }
    __shared__ float ls[2][4];
    int lane = threadIdx.x & 63, wv = threadIdx.x >> 6;
    if (lane == 0) { ls[0][wv] = sum; ls[1][wv] = sq; }
    __syncthreads();
    if (threadIdx.x == 0) {
      float S = 0.f, Q = 0.f;
      #pragma unroll
      for (int j = 0; j < 4; ++j) { S += ls[0][j]; Q += ls[1][j]; }
      int bpc = NTOT/256;
      int co = blockIdx.x / bpc, slice = blockIdx.x % bpc;
      stats[(co*bpc + slice)*2 + 0] = S;
      stats[(co*bpc + slice)*2 + 1] = Q;
    }
  }
}

// ---------------- BN stats ----------------
template<int C,int HW,int SLICES>
__global__ void bn_partial(const float* __restrict__ x, float* __restrict__ part, int B) {
  int c = blockIdx.x / SLICES, s = blockIdx.x % SLICES;
  int bpp = B / SLICES;
  float sum = 0.f, sq = 0.f;
  for (int b = s*bpp; b < (s+1)*bpp; ++b) {
    const float* p = x + ((size_t)b*C + c)*HW;
    for (int i = threadIdx.x; i < HW; i += blockDim.x) {
      float v = p[i]; sum += v; sq += v*v;
    }
  }
  #pragma unroll
  for (int off = 32; off; off >>= 1) {
    sum += __shfl_down(sum, off, 64);
    sq  += __shfl_down(sq,  off, 64);
  }
  __shared__ float ls[2][4];
  int lane = threadIdx.x & 63, wv = threadIdx.x >> 6;
  if (lane == 0) { ls[0][wv] = sum; ls[1][wv] = sq; }
  __syncthreads();
  if (threadIdx.x == 0) {
    float S = 0.f, Q = 0.f;
    #pragma unroll
    for (int i = 0; i < 4; ++i) { S += ls[0][i]; Q += ls[1][i]; }
    part[(c*SLICES+s)*2+0] = S; part[(c*SLICES+s)*2+1] = Q;
  }
}

template<int C,int SLICES>
__global__ void bn_final(const float* __restrict__ part, const float* __restrict__ g,
                         const float* __restrict__ bta, float* __restrict__ sc, int NHW) {
  int c = blockIdx.x*blockDim.x + threadIdx.x;
  if (c >= C) return;
  float S = 0.f, Q = 0.f;
  for (int s = 0; s < SLICES; ++s) { S += part[(c*SLICES+s)*2]; Q += part[(c*SLICES+s)*2+1]; }
  float m = S / NHW, v = Q / NHW - m*m;
  float inv = rsqrtf(v + 1e-5f);
  float a = g[c] * inv;
  sc[c*2] = a; sc[c*2+1] = bta[c] - m*a;
}

// ---------------- squash primary caps in place ----------------
__global__ void squash_pc(float* __restrict__ pc, int ncaps) {
  int i = blockIdx.x*blockDim.x + threadIdx.x;
  if (i >= ncaps) return;
  float* p = pc + (size_t)i*12;
  float v[12]; float s = 0.f;
  #pragma unroll
  for (int d = 0; d < 12; ++d) { v[d] = p[d]; s += v[d]*v[d]; }
  float sc = s / ((1.f + s)*sqrtf(s + 1e-6f));
  #pragma unroll
  for (int d = 0; d < 12; ++d) p[d] = v[d]*sc;
}

// ---------------- uu gather ----------------
__global__ void uu_gather(const float* __restrict__ sq, float* __restrict__ uu, int B) {
  int idx = blockIdx.x*blockDim.x + threadIdx.x;
  int total = B*49*144*12;
  if (idx >= total) return;
  int ii = idx % 12; int t0 = idx / 12;
  int kk = t0 % 144; t0 /= 144;
  int tt = t0 % 49;  int b = t0 / 49;
  int f = tt*1728 + kk*12 + ii;
  int c = f / 441; int r = f - c*441;
  int k = r / 49;  int sp = r - k*49;
  int y = sp / 7, x = sp - y*7;
  int iy = y + k/3 - 1, ix = x + (k%3) - 1;
  float val = 0.f;
  if (iy >= 0 && iy < 7 && ix >= 0 && ix < 7)
    val = sq[((size_t)(b*192 + c)*7 + iy)*7 + ix];
  uu[idx] = val;
}

// ---------------- ConvCaps einsum: broadcast global reads, no LDS ----------------
__global__ __launch_bounds__(192) void cc_einsum2(const float* __restrict__ uu,
                                                  const float* __restrict__ wcc,
                                                  __hip_bfloat16* __restrict__ uhat,
                                                  int row0, int nrows) {
  int k  = blockIdx.x;
  int m0 = blockIdx.y * 64;
  int o = threadIdx.x;
  const float4* wp4 = (const float4*)(wcc + ((size_t)k*192 + o)*12);
  float4 w0 = wp4[0], w1 = wp4[1], w2 = wp4[2];
  int mmax = nrows - m0; if (mmax > 64) mmax = 64;
  #pragma unroll 2
  for (int m = 0; m < mmax; ++m) {
    const float4* ar = (const float4*)(uu + ((size_t)(row0+m0+m)*144 + k)*12);
    float4 a0 = ar[0], a1 = ar[1], a2 = ar[2];
    float acc = a0.x*w0.x + a0.y*w0.y + a0.z*w0.z + a0.w*w0.w
              + a1.x*w1.x + a1.y*w1.y + a1.z*w1.z + a1.w*w1.w
              + a2.x*w2.x + a2.y*w2.y + a2.z*w2.z + a2.w*w2.w;
    uhat[((size_t)(m0+m)*144 + k)*192 + o] = __float2bfloat16(acc);
  }
}

// ---------------- ConvCaps routing: fused 3-pass, blog in registers, shuffle softmax ----------
// 256 threads = 16 groups x 16 lanes. lane=(g,oc); group g owns k = g+16j, j=0..8.
// pass 0: uniform c=1/16. passes 1,2: fused {dot(v,u) -> blog += -> softmax(oc) -> s += c*u}.
__global__ __launch_bounds__(256) void cc_route(const __hip_bfloat16* __restrict__ uhat,
                                                float* __restrict__ u2, int rowOff) {
  const int row = blockIdx.x;
  const unsigned short* __restrict__ uh = (const unsigned short*)uhat + (size_t)row*27648;
  __shared__ float red[16][192];
  __shared__ float sraw[192];
  __shared__ float vsh[192];
  const int tid = threadIdx.x;
  const int g = tid >> 4, oc = tid & 15;
  const unsigned short* __restrict__ ubase = uh + oc*12;
  float blog[9];
  #pragma unroll
  for (int j = 0; j < 9; ++j) blog[j] = 0.f;
  float sacc[12];

  for (int r = 0; r < 3; ++r) {
    #pragma unroll
    for (int d = 0; d < 12; ++d) sacc[d] = 0.f;
    float vq[12];
    if (r > 0) {
      #pragma unroll
      for (int d = 0; d < 12; ++d) vq[d] = vsh[oc*12 + d];
    }
    for (int j = 0; j < 9; ++j) {
      const unsigned short* up = ubase + (g + 16*j)*192;
      uint2 q0 = *(const uint2*)up;
      uint2 q1 = *(const uint2*)(up + 4);
      uint2 q2 = *(const uint2*)(up + 8);
      float uf[12];
      uf[0] = bf2f((unsigned short)(q0.x & 0xffff)); uf[1] = bf2f((unsigned short)(q0.x >> 16));
      uf[2] = bf2f((unsigned short)(q0.y & 0xffff)); uf[3] = bf2f((unsigned short)(q0.y >> 16));
      uf[4] = bf2f((unsigned short)(q1.x & 0xffff)); uf[5] = bf2f((unsigned short)(q1.x >> 16));
      uf[6] = bf2f((unsigned short)(q1.y & 0xffff)); uf[7] = bf2f((unsigned short)(q1.y >> 16));
      uf[8] = bf2f((unsigned short)(q2.x & 0xffff)); uf[9] = bf2f((unsigned short)(q2.x >> 16));
      uf[10] = bf2f((unsigned short)(q2.y & 0xffff)); uf[11] = bf2f((unsigned short)(q2.y >> 16));
      if (r == 0) {
        #pragma unroll
        for (int d = 0; d < 12; ++d) sacc[d] += uf[d];
      } else {
        float dot = 0.f;
        #pragma unroll
        for (int d = 0; d < 12; ++d) dot = fmaf(vq[d], uf[d], dot);
        blog[j] += dot;
        float mx = blog[j];
        #pragma unroll
        for (int off = 1; off < 16; off <<= 1) mx = fmaxf(mx, __shfl_xor(mx, off, 16));
        float e = __expf(blog[j] - mx);
        float es = e;
        #pragma unroll
        for (int off = 1; off < 16; off <<= 1) es += __shfl_xor(es, off, 16);
        float c = e / es;
        #pragma unroll
        for (int d = 0; d < 12; ++d) sacc[d] = fmaf(c, uf[d], sacc[d]);
      }
    }
    // cross-group reduce + squash
    #pragma unroll
    for (int d = 0; d < 12; ++d) red[g][oc*12 + d] = sacc[d];
    __syncthreads();
    if (tid < 192) {
      float s = 0.f;
      #pragma unroll
      for (int q = 0; q < 16; ++q) s += red[q][tid];
      if (r == 0) s *= 0.0625f;
      sraw[tid] = s;
    }
    __syncthreads();
    if (tid < 192) {
      int qc = tid / 12;
      float nrm = 0.f;
      #pragma unroll
      for (int d = 0; d < 12; ++d) { float v = sraw[qc*12 + d]; nrm += v*v; }
      float sc = nrm / ((1.f + nrm)*sqrtf(nrm + 1e-6f));
      vsh[tid] = sraw[tid]*sc;
    }
    __syncthreads();
  }
  if (tid < 192) u2[((size_t)(rowOff + row))*192 + tid] = vsh[tid];
}

// ---------------- Class caps einsum (bf16 output) ----------------
__global__ void class_einsum(const float* __restrict__ u2, const float* __restrict__ wcl,
                             unsigned short* __restrict__ uhat2, int B) {
  int n = blockIdx.x;
  __shared__ float u2l[64][12];
  int tid = threadIdx.x;
  for (int e = tid; e < 64*12; e += 320) {
    int b = e / 12, i = e % 12;
    u2l[b][i] = u2[(size_t)b*9408 + n*12 + i];
  }
  __syncthreads();
  int od = tid % 160, bh = tid / 160;
  int o = od >> 4, d = od & 15;
  float w[12];
  #pragma unroll
  for (int i = 0; i < 12; ++i) w[i] = wcl[(size_t)n*1920 + o*192 + d*12 + i];
  for (int b = bh*32; b < bh*32+32; ++b) {
    float acc = 0.f;
    #pragma unroll
    for (int i = 0; i < 12; ++i) acc = fmaf(w[i], u2l[b][i], acc);
    uhat2[((size_t)b*784 + n)*160 + od] = f2bf(acc);
  }
}

// ---------------- class routing: wave-local pass, no barriers in main loop ----------------
template<int MODE>
__global__ __launch_bounds__(256) void cls_pass(const unsigned short* __restrict__ uh2b,
                                                const float* __restrict__ vprev,
                                                float* __restrict__ b2l,
                                                float* __restrict__ cpart) {
  const int b = blockIdx.x, sl = blockIdx.y;   // sl 0..6
  const int tid = threadIdx.x, lane = tid & 63, wv = tid >> 6;
  const int nl = lane >> 4, d = lane & 15;
  float v[10];
  if (MODE != 0) {
    #pragma unroll
    for (int o = 0; o < 10; ++o) v[o] = vprev[b*160 + o*16 + d];
  }
  float sacc[10];
  #pragma unroll
  for (int o = 0; o < 10; ++o) sacc[o] = 0.f;
  for (int step = 0; step < 7; ++step) {
    const int n = sl*112 + step*16 + wv*4 + nl;
    const unsigned short* up = uh2b + ((size_t)b*784 + n)*160 + d;
    float u[10];
    #pragma unroll
    for (int o = 0; o < 10; ++o) u[o] = bf2f(up[o*16]);
    if (MODE == 0) {
      #pragma unroll
      for (int o = 0; o < 10; ++o) sacc[o] += u[o];
    } else {
      float bb[10];
      #pragma unroll
      for (int o = 0; o < 10; ++o) {
        float t = v[o]*u[o];
        #pragma unroll
        for (int off = 8; off; off >>= 1) t += __shfl_xor(t, off, 16);
        bb[o] = t;
      }
      if (MODE == 2) {
        #pragma unroll
        for (int o = 0; o < 10; ++o) bb[o] += b2l[((size_t)b*784 + n)*10 + o];
      }
      if (MODE == 1 && d < 10) b2l[((size_t)b*784 + n)*10 + d] = bb[d];
      float mx = bb[0];
      #pragma unroll
      for (int o = 1; o < 10; ++o) mx = fmaxf(mx, bb[o]);
      float es = 0.f;
      #pragma unroll
      for (int o = 0; o < 10; ++o) { bb[o] = __expf(bb[o]-mx); es += bb[o]; }
      float inv = 1.f/es;
      #pragma unroll
      for (int o = 0; o < 10; ++o) sacc[o] = fmaf(bb[o]*inv, u[o], sacc[o]);
    }
  }
  #pragma unroll
  for (int o = 0; o < 10; ++o) {
    sacc[o] += __shfl_xor(sacc[o], 16, 64);
    sacc[o] += __shfl_xor(sacc[o], 32, 64);
  }
  __shared__ float red[4][160];
  if (lane < 16) {
    #pragma unroll
    for (int o = 0; o < 10; ++o) red[wv][o*16 + d] = sacc[o];
  }
  __syncthreads();
  if (tid < 160) {
    float s = red[0][tid] + red[1][tid] + red[2][tid] + red[3][tid];
    cpart[((size_t)b*7 + sl)*160 + tid] = s;
  }
}

__global__ __launch_bounds__(160) void cls_finish(const float* __restrict__ cpart,
                                                  float* __restrict__ vout, float fac) {
  int b = blockIdx.x, od = threadIdx.x;
  float s = 0.f;
  #pragma unroll
  for (int sl = 0; sl < 7; ++sl) s += cpart[((size_t)b*7 + sl)*160 + od];
  s *= fac;
  float nrm = s*s;
  #pragma unroll
  for (int off = 8; off; off >>= 1) nrm += __shfl_xor(nrm, off, 16);
  float sc = nrm / ((1.f + nrm)*sqrtf(nrm + 1e-6f));
  vout[(size_t)b*160 + od] = s*sc;
}

// ---------------- host launch ----------------
extern "C" void kernel_launch(void* const* d_in, const int* in_sizes, int n_in,
                              void* d_out, int out_size, void* d_ws, size_t ws_size,
                              hipStream_t stream) {
  const float* images = (const float*)d_in[0];
  const float* w1  = (const float*)d_in[1];
  const float* g1  = (const float*)d_in[2];
  const float* b1  = (const float*)d_in[3];
  const float* w2  = (const float*)d_in[4];
  const float* g2  = (const float*)d_in[5];
  const float* b2  = (const float*)d_in[6];
  const float* w3  = (const float*)d_in[7];
  const float* g3  = (const float*)d_in[8];
  const float* b3  = (const float*)d_in[9];
  const float* wp  = (const float*)d_in[10];
  const float* bp  = (const float*)d_in[11];
  const float* wcc = (const float*)d_in[12];
  const float* wcl = (const float*)d_in[13];
  float* out = (float*)d_out;
  float* ws  = (float*)d_ws;

  // persistent regions (float offsets)
  float* t1    = ws + 0;            // 3,145,728
  float* t2    = ws + 3145728;      // 1,572,864
  float* t3    = ws + 4718592;      // 3,145,728
  float* pc    = ws + 7864320;      //   602,112
  float* uu    = ws + 8466432;      // 5,419,008
  float* u2b   = ws + 13885440;     //   602,112
  unsigned short* uh2b = (unsigned short*)(ws + 14487552);  // 8,028,160 ushorts
  float* b2l   = ws + 22515712;     //   501,760
  float* scrC  = ws + 23017472;     //   501,760 (BN stats during convs, cpart during class)
  float* v2    = ws + 23519232;     //    10,240
  float* spart = ws + 23529472;     //     3,072
  float* ssc1  = ws + 23532544;     //        96
  float* ssc2  = ws + 23532640;     //       192
  float* ssc3  = ws + 23532832;     //       384
  float* U     = ws + 23533312;     // arena, 10,838,016 f32 (conv transients)
  __hip_bfloat16* uhc = (__hip_bfloat16*)(ws + 34371328);   // 43,352,064 bf16 (one 32-img chunk)

  // split/reordered weights live in dead `uu` region (dead until uu_gather)
  unsigned short* wh2 = (unsigned short*)(uu + 0);
  unsigned short* wl2 = (unsigned short*)(uu + 20736);
  unsigned short* wh3 = (unsigned short*)(uu + 41472);
  unsigned short* wl3 = (unsigned short*)(uu + 124416);
  unsigned short* whp = (unsigned short*)(uu + 207360);
  unsigned short* wlp = (unsigned short*)(uu + 373248);

  // phase transients in the U arena
  unsigned short* x2h = (unsigned short*)(U + 0);
  unsigned short* x2l = (unsigned short*)(U + 1775616);
  float*          part2 = U + 3551232;                    // 3x96x16384
  unsigned short* x3h = (unsigned short*)(U + 0);
  unsigned short* x3l = (unsigned short*)(U + 995328);
  unsigned short* xph = (unsigned short*)(U + 0);
  unsigned short* xpl = (unsigned short*)(U + 1572864);
  float*          partp = U + 3145728;                    // 8x192x3136

  const int B = 64;

  // merged weight splits
  split_w_all<<<2106,256,0,stream>>>(w2, w3, wp, wh2, wl2, wh3, wl3, whp, wlp);

  // conv1 + BN1 stats
  conv1_fused<<<2048,192,0,stream>>>(images, w1, t1);
  bn_partial<48,1024,8><<<48*8,256,0,stream>>>(t1, spart, B);
  bn_final<48,8><<<1,64,0,stream>>>(spart, g1, b1, ssc1, 65536);

  // conv2: BN1+ReLU+split (with halos), MFMA split-K=3, reduce+stats
  bn_split_nhwc<48,32,32,1><<<64*34,256,0,stream>>>(t1, ssc1, x2h, x2l);
  conv_mfma<48,34,34,16,16,2,3><<<dim3(2,128,3),256,0,stream>>>(x2h, x2l, wh2, wl2, part2, 96, B);
  splitk_reduce<96,256,3,false,true><<<6144,256,0,stream>>>(part2, nullptr, t2, scrC, B);
  bn_final<96,64><<<1,128,0,stream>>>(scrC, g2, b2, ssc2, 16384);

  // conv3: direct NCHW write (split-K=1), stats via bn_partial
  bn_split_nhwc<96,16,16,1><<<64*18,256,0,stream>>>(t2, ssc2, x3h, x3l);
  conv_mfma<96,18,18,16,16,1,1><<<dim3(3,128,1),256,0,stream>>>(x3h, x3l, wh3, wl3, t3, 192, B);
  bn_partial<192,256,8><<<192*8,256,0,stream>>>(t3, spart, B);
  bn_final<192,8><<<1,192,0,stream>>>(spart, g3, b3, ssc3, 16384);

  // primary caps conv + bias, then squash
  bn_split_nhwc<192,16,16,0><<<64*16,256,0,stream>>>(t3, ssc3, xph, xpl);
  conv_mfma<192,16,16,7,7,2,8><<<dim3(3,25,8),256,0,stream>>>(xph, xpl, whp, wlp, partp, 192, B);
  splitk_reduce<192,49,8,true,false><<<2352,256,0,stream>>>(partp, bp, pc, nullptr, B);
  squash_pc<<<196,256,0,stream>>>(pc, 50176);

  // uu gather
  uu_gather<<<21168,256,0,stream>>>(pc, uu, B);
  // ConvCaps einsum + fused 3-pass routing, 2 chunks of 32 images
  for (int cb = 0; cb < 2; ++cb) {
    cc_einsum2<<<dim3(144,25),192,0,stream>>>(uu, wcc, uhc, cb*1568, 1568);
    cc_route<<<1568,256,0,stream>>>(uhc, u2b, cb*1568);
  }
  // Class caps einsum (bf16) + wave-local routing
  class_einsum<<<784,320,0,stream>>>(u2b, wcl, uh2b, B);
  cls_pass<0><<<dim3(64,7),256,0,stream>>>(uh2b, v2, b2l, scrC);
  cls_finish<<<64,160,0,stream>>>(scrC, v2, 0.1f);
  cls_pass<1><<<dim3(64,7),256,0,stream>>>(uh2b, v2, b2l, scrC);
  cls_finish<<<64,160,0,stream>>>(scrC, v2, 1.0f);
  cls_pass<2><<<dim3(64,7),256,0,stream>>>(uh2b, v2, b2l, scrC);
  cls_finish<<<64,160,0,stream>>>(scrC, out, 1.0f);
  (void)in_sizes; (void)n_in; (void)out_size; (void)ws_size;
}

// Round 10
// 384.580 us; speedup vs baseline: 6.2827x; 1.0375x over previous
//
#include <hip/hip_runtime.h>
#include <hip/hip_bf16.h>

typedef __attribute__((ext_vector_type(4))) short short4v;
typedef __attribute__((ext_vector_type(8))) short short8v;
typedef __attribute__((ext_vector_type(16))) float f32x16;

union frag8 { short8v v8; struct { short4v lo, hi; } p; };

__device__ __forceinline__ unsigned short f2bf(float v) {
  unsigned u = __float_as_uint(v);
  unsigned r = u + 0x7fffu + ((u >> 16) & 1u);
  return (unsigned short)(r >> 16);
}
__device__ __forceinline__ float bf2f(unsigned short h) {
  return __uint_as_float(((unsigned)h) << 16);
}

// ---------------- conv1: one block per (b,h), LDS input slab, weights in regs ----------------
__global__ __launch_bounds__(192) void conv1_fused(const float* __restrict__ images,
                                                   const float* __restrict__ w1,
                                                   float* __restrict__ out) {
  int b = blockIdx.x >> 5, h = blockIdx.x & 31;
  __shared__ __align__(16) float lin[3][3][36];
  int tid = threadIdx.x;
  for (int e = tid; e < 324; e += 192) {
    int ci = e / 108, rem = e % 108, ki = rem / 36, wi = rem % 36;
    int row = h + ki - 1, col = wi - 1;
    float v = 0.f;
    if (row >= 0 && row < 32 && col >= 0 && col < 32)
      v = images[((size_t)(b*3 + ci)*32 + row)*32 + col];
    lin[ci][ki][wi] = v;
  }
  int co = tid >> 2, ws = tid & 3;
  float wr[27];
  #pragma unroll
  for (int j = 0; j < 27; ++j) wr[j] = w1[co*27 + j];
  __syncthreads();
  float o[8];
  #pragma unroll
  for (int j = 0; j < 8; ++j) o[j] = 0.f;
  #pragma unroll
  for (int ci = 0; ci < 3; ++ci)
    #pragma unroll
    for (int ki = 0; ki < 3; ++ki) {
      float4 q0 = *(const float4*)&lin[ci][ki][ws*8];
      float4 q1 = *(const float4*)&lin[ci][ki][ws*8+4];
      float4 q2 = *(const float4*)&lin[ci][ki][ws*8+8];
      float r[12] = {q0.x,q0.y,q0.z,q0.w,q1.x,q1.y,q1.z,q1.w,q2.x,q2.y,q2.z,q2.w};
      #pragma unroll
      for (int kj = 0; kj < 3; ++kj) {
        float wv = wr[(ci*3+ki)*3+kj];
        #pragma unroll
        for (int j = 0; j < 8; ++j) o[j] = fmaf(r[j+kj], wv, o[j]);
      }
    }
  float* dst = out + (((size_t)(b*48+co)*32 + h)*32 + ws*8);
  *(float4*)dst       = make_float4(o[0],o[1],o[2],o[3]);
  *(float4*)(dst + 4) = make_float4(o[4],o[5],o[6],o[7]);
}

// ---------------- merged weight split+reorder for conv2/conv3/primary ----------------
__device__ __forceinline__ void split_one(const float* w, unsigned short* wh,
                                          unsigned short* wl, int CI, int i) {
  int K = CI*9;
  int co = i / K, rem = i % K, tap = rem / CI, ci = rem % CI;
  float v = w[(co*CI + ci)*9 + tap];
  unsigned short h = f2bf(v);
  wh[i] = h;
  wl[i] = f2bf(v - bf2f(h));
}
__global__ void split_w_all(const float* __restrict__ w2, const float* __restrict__ w3,
                            const float* __restrict__ wp,
                            unsigned short* wh2, unsigned short* wl2,
                            unsigned short* wh3, unsigned short* wl3,
                            unsigned short* whp, unsigned short* wlp) {
  int i = blockIdx.x*256 + threadIdx.x;
  if (i < 41472) split_one(w2, wh2, wl2, 48, i);
  else if (i < 207360) split_one(w3, wh3, wl3, 96, i - 41472);
  else if (i < 539136) split_one(wp, whp, wlp, 192, i - 207360);
}

// ---------------- BN affine + ReLU + split to padded NHWC bf16 hi/lo (writes halos) ----------------
template<int C,int H,int W,int P>
__global__ void bn_split_nhwc(const float* __restrict__ in, const float* __restrict__ sc,
                              unsigned short* __restrict__ xh, unsigned short* __restrict__ xl) {
  constexpr int HP = H + 2*P, WP = W + 2*P;
  int b = blockIdx.x / HP, hp = blockIdx.x % HP;
  int h = hp - P;
  for (int e = threadIdx.x; e < WP*C; e += 256) {
    int wp = e / C, c = e % C;
    int w = wp - P;
    float v = 0.f;
    if (h >= 0 && h < H && w >= 0 && w < W) {
      v = in[((size_t)(b*C + c)*H + h)*W + w];
      v = fmaf(v, sc[c*2], sc[c*2+1]);
      v = v > 0.f ? v : 0.f;
    }
    unsigned short hh = f2bf(v);
    size_t o = ((size_t)(b*HP + hp)*WP + wp)*C + c;
    xh[o] = hh;
    xl[o] = f2bf(v - bf2f(hh));
  }
}

// ---------------- MFMA implicit-GEMM conv; SPLITK==1 writes NCHW directly ----------------
template<int CI,int HIP,int WIP,int HO,int WO,int STR,int SPLITK>
__global__ __launch_bounds__(256,4) void conv_mfma(
    const unsigned short* __restrict__ xh, const unsigned short* __restrict__ xl,
    const unsigned short* __restrict__ wh, const unsigned short* __restrict__ wl,
    float* __restrict__ part, int CO, int B) {
  constexpr int K = CI*9, NSP = HO*WO, KCH = K/SPLITK, LDA = 36;
  const int NTOT = B*NSP;
  const int m0 = blockIdx.x*64, n0 = blockIdx.y*128, ks = blockIdx.z;
  __shared__ unsigned short Ah[64*LDA], Al[64*LDA], Bh[128*LDA], Bl[128*LDA];
  const int tid = threadIdx.x, lane = tid & 63, wid = tid >> 6;
  const int wm = wid >> 1, wn = wid & 1;
  const int arow = tid >> 2, ak0 = (tid & 3)*8;
  const bool aok = (m0 + arow) < CO;
  const size_t abase = (size_t)(m0 + arow)*K;
  int brow[2], bk0[2];
  size_t bbase[2];
  #pragma unroll
  for (int i = 0; i < 2; ++i) {
    int e = tid + i*256;
    brow[i] = e >> 2; bk0[i] = (e & 3)*8;
    int nn = n0 + brow[i]; if (nn > NTOT-1) nn = NTOT-1;
    int bb = nn / NSP, sp = nn % NSP;
    int ho = sp / WO, wo = sp % WO;
    bbase[i] = ((size_t)bb*HIP + ho*STR)*WIP + wo*STR;
  }
  f32x16 acc0 = (f32x16)0.f, acc1 = (f32x16)0.f;
  const int kBeg = ks*KCH, kEnd = kBeg + KCH;
  for (int kc = kBeg; kc < kEnd; kc += 32) {
    const int kLim = (kEnd - kc) < 32 ? (kEnd - kc) : 32;
    {
      frag8 vh, vl;
      vh.v8 = (short8v)(short)0; vl.v8 = (short8v)(short)0;
      if (aok && ak0 < kLim) {
        size_t off = abase + kc + ak0;
        vh.v8 = *(const short8v*)(wh + off);
        vl.v8 = *(const short8v*)(wl + off);
      }
      int lo_ = arow*LDA + ak0;
      *(short4v*)(Ah + lo_) = vh.p.lo; *(short4v*)(Ah + lo_ + 4) = vh.p.hi;
      *(short4v*)(Al + lo_) = vl.p.lo; *(short4v*)(Al + lo_ + 4) = vl.p.hi;
    }
    #pragma unroll
    for (int i = 0; i < 2; ++i) {
      frag8 vh, vl;
      vh.v8 = (short8v)(short)0; vl.v8 = (short8v)(short)0;
      if (bk0[i] < kLim) {
        int kg = kc + bk0[i];
        int tap = kg / CI, ci0 = kg - tap*CI;
        int dh = tap / 3, dw = tap - dh*3;
        size_t off = (bbase[i] + (size_t)dh*WIP + dw)*CI + ci0;
        vh.v8 = *(const short8v*)(xh + off);
        vl.v8 = *(const short8v*)(xl + off);
      }
      int lo_ = brow[i]*LDA + bk0[i];
      *(short4v*)(Bh + lo_) = vh.p.lo; *(short4v*)(Bh + lo_ + 4) = vh.p.hi;
      *(short4v*)(Bl + lo_) = vl.p.lo; *(short4v*)(Bl + lo_ + 4) = vl.p.hi;
    }
    __syncthreads();
    #pragma unroll
    for (int kst = 0; kst < 2; ++kst) {
      const int kb = kst*16 + 8*(lane >> 5);
      const int ar = wm*32 + (lane & 31);
      frag8 ah, al;
      { int o = ar*LDA + kb;
        ah.p.lo = *(const short4v*)(Ah + o); ah.p.hi = *(const short4v*)(Ah + o + 4);
        al.p.lo = *(const short4v*)(Al + o); al.p.hi = *(const short4v*)(Al + o + 4); }
      const int br = wn*64 + (lane & 31);
      frag8 bh0, bl0, bh1, bl1;
      { int o = br*LDA + kb;
        bh0.p.lo = *(const short4v*)(Bh + o); bh0.p.hi = *(const short4v*)(Bh + o + 4);
        bl0.p.lo = *(const short4v*)(Bl + o); bl0.p.hi = *(const short4v*)(Bl + o + 4); }
      { int o = (br+32)*LDA + kb;
        bh1.p.lo = *(const short4v*)(Bh + o); bh1.p.hi = *(const short4v*)(Bh + o + 4);
        bl1.p.lo = *(const short4v*)(Bl + o); bl1.p.hi = *(const short4v*)(Bl + o + 4); }
      acc0 = __builtin_amdgcn_mfma_f32_32x32x16_bf16(ah.v8, bh0.v8, acc0, 0, 0, 0);
      acc0 = __builtin_amdgcn_mfma_f32_32x32x16_bf16(ah.v8, bl0.v8, acc0, 0, 0, 0);
      acc0 = __builtin_amdgcn_mfma_f32_32x32x16_bf16(al.v8, bh0.v8, acc0, 0, 0, 0);
      acc1 = __builtin_amdgcn_mfma_f32_32x32x16_bf16(ah.v8, bh1.v8, acc1, 0, 0, 0);
      acc1 = __builtin_amdgcn_mfma_f32_32x32x16_bf16(ah.v8, bl1.v8, acc1, 0, 0, 0);
      acc1 = __builtin_amdgcn_mfma_f32_32x32x16_bf16(al.v8, bh1.v8, acc1, 0, 0, 0);
    }
    __syncthreads();
  }
  #pragma unroll
  for (int ns = 0; ns < 2; ++ns) {
    f32x16 a = ns ? acc1 : acc0;
    #pragma unroll
    for (int r = 0; r < 16; ++r) {
      int row = (r & 3) + 8*(r >> 2) + 4*(lane >> 5);
      int m = m0 + wm*32 + row;
      int n = n0 + wn*64 + ns*32 + (lane & 31);
      if (m < CO && n < NTOT) {
        if (SPLITK == 1) {
          int b = n / NSP, sp = n % NSP;
          part[((size_t)b*CO + m)*NSP + sp] = a[r];
        } else {
          part[((size_t)ks*CO + m)*NTOT + n] = a[r];
        }
      }
    }
  }
}

// ---------------- split-K reduce (+bias, + optional fused BN partial stats) ----------------
template<int CO,int NSP,int SPLITK,bool BIAS,bool STATS>
__global__ void splitk_reduce(const float* __restrict__ part, const float* __restrict__ bias,
                              float* __restrict__ out, float* __restrict__ stats, int B) {
  const int NTOT = B*NSP;
  int i = blockIdx.x*256 + threadIdx.x;
  bool valid = i < CO*NTOT;
  float s = 0.f;
  if (valid) {
    int co = i / NTOT, n = i % NTOT;
    #pragma unroll
    for (int ks = 0; ks < SPLITK; ++ks) s += part[(size_t)(ks*CO + co)*NTOT + n];
    if (BIAS) s += bias[co];
    int b = n / NSP, sp = n % NSP;
    out[((size_t)b*CO + co)*NSP + sp] = s;
  }
  if (STATS) {
    float sum = valid ? s : 0.f, sq = valid ? s*s : 0.f;
    #pragma unroll
    for (int off = 32; off; off >>= 1) {
      sum += __shfl_down(sum, off, 64);
      sq  += __shfl_down(sq,  off, 64);
    }
    __shared__ float ls[2][4];
    int lane = threadIdx.x & 63, wv = threadIdx.x >> 6;
    if (lane == 0) { ls[0][wv] = sum; ls[1][wv] = sq; }
    __syncthreads();
    if (threadIdx.x == 0) {
      float S = 0.f, Q = 0.f;
      #pragma unroll
      for (int j = 0; j < 4; ++j) { S += ls[0][j]; Q += ls[1][j]; }
      int bpc = NTOT/256;
      int co = blockIdx.x / bpc, slice = blockIdx.x % bpc;
      stats[(co*bpc + slice)*2 + 0] = S;
      stats[(co*bpc + slice)*2 + 1] = Q;
    }
  }
}

// ---------------- BN stats ----------------
template<int C,int HW,int SLICES>
__global__ void bn_partial(const float* __restrict__ x, float* __restrict__ part, int B) {
  int c = blockIdx.x / SLICES, s = blockIdx.x % SLICES;
  int bpp = B / SLICES;
  float sum = 0.f, sq = 0.f;
  for (int b = s*bpp; b < (s+1)*bpp; ++b) {
    const float* p = x + ((size_t)b*C + c)*HW;
    for (int i = threadIdx.x; i < HW; i += blockDim.x) {
      float v = p[i]; sum += v; sq += v*v;
    }
  }
  #pragma unroll
  for (int off = 32; off; off >>= 1) {
    sum += __shfl_down(sum, off, 64);
    sq  += __shfl_down(sq,  off, 64);
  }
  __shared__ float ls[2][4];
  int lane = threadIdx.x & 63, wv = threadIdx.x >> 6;
  if (lane == 0) { ls[0][wv] = sum; ls[1][wv] = sq; }
  __syncthreads();
  if (threadIdx.x == 0) {
    float S = 0.f, Q = 0.f;
    #pragma unroll
    for (int i = 0; i < 4; ++i) { S += ls[0][i]; Q += ls[1][i]; }
    part[(c*SLICES+s)*2+0] = S; part[(c*SLICES+s)*2+1] = Q;
  }
}

template<int C,int SLICES>
__global__ void bn_final(const float* __restrict__ part, const float* __restrict__ g,
                         const float* __restrict__ bta, float* __restrict__ sc, int NHW) {
  int c = blockIdx.x*blockDim.x + threadIdx.x;
  if (c >= C) return;
  float S = 0.f, Q = 0.f;
  for (int s = 0; s < SLICES; ++s) { S += part[(c*SLICES+s)*2]; Q += part[(c*SLICES+s)*2+1]; }
  float m = S / NHW, v = Q / NHW - m*m;
  float inv = rsqrtf(v + 1e-5f);
  float a = g[c] * inv;
  sc[c*2] = a; sc[c*2+1] = bta[c] - m*a;
}

// ---------------- squash primary caps in place ----------------
__global__ void squash_pc(float* __restrict__ pc, int ncaps) {
  int i = blockIdx.x*blockDim.x + threadIdx.x;
  if (i >= ncaps) return;
  float* p = pc + (size_t)i*12;
  float v[12]; float s = 0.f;
  #pragma unroll
  for (int d = 0; d < 12; ++d) { v[d] = p[d]; s += v[d]*v[d]; }
  float sc = s / ((1.f + s)*sqrtf(s + 1e-6f));
  #pragma unroll
  for (int d = 0; d < 12; ++d) p[d] = v[d]*sc;
}

// ---------------- uu gather ----------------
__global__ void uu_gather(const float* __restrict__ sq, float* __restrict__ uu, int B) {
  int idx = blockIdx.x*blockDim.x + threadIdx.x;
  int total = B*49*144*12;
  if (idx >= total) return;
  int ii = idx % 12; int t0 = idx / 12;
  int kk = t0 % 144; t0 /= 144;
  int tt = t0 % 49;  int b = t0 / 49;
  int f = tt*1728 + kk*12 + ii;
  int c = f / 441; int r = f - c*441;
  int k = r / 49;  int sp = r - k*49;
  int y = sp / 7, x = sp - y*7;
  int iy = y + k/3 - 1, ix = x + (k%3) - 1;
  float val = 0.f;
  if (iy >= 0 && iy < 7 && ix >= 0 && ix < 7)
    val = sq[((size_t)(b*192 + c)*7 + iy)*7 + ix];
  uu[idx] = val;
}

// ---------------- ConvCaps einsum: broadcast global reads, no LDS ----------------
__global__ __launch_bounds__(192) void cc_einsum2(const float* __restrict__ uu,
                                                  const float* __restrict__ wcc,
                                                  __hip_bfloat16* __restrict__ uhat,
                                                  int row0, int nrows) {
  int k  = blockIdx.x;
  int m0 = blockIdx.y * 64;
  int o = threadIdx.x;
  const float4* wp4 = (const float4*)(wcc + ((size_t)k*192 + o)*12);
  float4 w0 = wp4[0], w1 = wp4[1], w2 = wp4[2];
  int mmax = nrows - m0; if (mmax > 64) mmax = 64;
  #pragma unroll 2
  for (int m = 0; m < mmax; ++m) {
    const float4* ar = (const float4*)(uu + ((size_t)(row0+m0+m)*144 + k)*12);
    float4 a0 = ar[0], a1 = ar[1], a2 = ar[2];
    float acc = a0.x*w0.x + a0.y*w0.y + a0.z*w0.z + a0.w*w0.w
              + a1.x*w1.x + a1.y*w1.y + a1.z*w1.z + a1.w*w1.w
              + a2.x*w2.x + a2.y*w2.y + a2.z*w2.z + a2.w*w2.w;
    uhat[((size_t)(m0+m)*144 + k)*192 + o] = __float2bfloat16(acc);
  }
}

// ---------------- ConvCaps routing: LDS-stash row, fused 3-pass, blog in registers -----------
// 256 threads = 16 groups x 16 lanes. lane=(g,oc); group g owns k = g+16j, j=0..8.
// r0: read global -> stash LDS + uniform-c sum. r1/r2: read LDS, fused blog/softmax/s.
__global__ __launch_bounds__(256,2) void cc_route(const __hip_bfloat16* __restrict__ uhat,
                                                  float* __restrict__ u2, int rowOff) {
  const int row = blockIdx.x;
  const unsigned short* __restrict__ uh = (const unsigned short*)uhat + (size_t)row*27648;
  __shared__ __align__(16) unsigned short uhl[144*196];   // padded rows: 8B-aligned cells
  __shared__ float red[4][192];
  __shared__ float sraw[192];
  __shared__ float vsh[192];
  const int tid = threadIdx.x, lane = tid & 63, wv = tid >> 6;
  const int g = tid >> 4, oc = tid & 15;
  float blog[9];
  #pragma unroll
  for (int j = 0; j < 9; ++j) blog[j] = 0.f;

  for (int r = 0; r < 3; ++r) {
    float vq[12];
    if (r > 0) {
      #pragma unroll
      for (int d = 0; d < 12; ++d) vq[d] = vsh[oc*12 + d];
    }
    float sacc[12];
    #pragma unroll
    for (int d = 0; d < 12; ++d) sacc[d] = 0.f;
    #pragma unroll
    for (int j = 0; j < 9; ++j) {
      const int k = g + 16*j;
      uint2 q0, q1, q2;
      if (r == 0) {
        const unsigned short* up = uh + k*192 + oc*12;
        q0 = *(const uint2*)up; q1 = *(const uint2*)(up + 4); q2 = *(const uint2*)(up + 8);
        unsigned short* lp = uhl + k*196 + oc*12;
        *(uint2*)lp = q0; *(uint2*)(lp + 4) = q1; *(uint2*)(lp + 8) = q2;
      } else {
        const unsigned short* lp = uhl + k*196 + oc*12;
        q0 = *(const uint2*)lp; q1 = *(const uint2*)(lp + 4); q2 = *(const uint2*)(lp + 8);
      }
      float uf[12];
      uf[0] = bf2f((unsigned short)(q0.x & 0xffff)); uf[1] = bf2f((unsigned short)(q0.x >> 16));
      uf[2] = bf2f((unsigned short)(q0.y & 0xffff)); uf[3] = bf2f((unsigned short)(q0.y >> 16));
      uf[4] = bf2f((unsigned short)(q1.x & 0xffff)); uf[5] = bf2f((unsigned short)(q1.x >> 16));
      uf[6] = bf2f((unsigned short)(q1.y & 0xffff)); uf[7] = bf2f((unsigned short)(q1.y >> 16));
      uf[8] = bf2f((unsigned short)(q2.x & 0xffff)); uf[9] = bf2f((unsigned short)(q2.x >> 16));
      uf[10] = bf2f((unsigned short)(q2.y & 0xffff)); uf[11] = bf2f((unsigned short)(q2.y >> 16));
      if (r == 0) {
        #pragma unroll
        for (int d = 0; d < 12; ++d) sacc[d] += uf[d];
      } else {
        float dot = 0.f;
        #pragma unroll
        for (int d = 0; d < 12; ++d) dot = fmaf(vq[d], uf[d], dot);
        blog[j] += dot;
        float mx = blog[j];
        #pragma unroll
        for (int off = 1; off < 16; off <<= 1) mx = fmaxf(mx, __shfl_xor(mx, off, 16));
        float e = __expf(blog[j] - mx);
        float es = e;
        #pragma unroll
        for (int off = 1; off < 16; off <<= 1) es += __shfl_xor(es, off, 16);
        float c = e / es;
        #pragma unroll
        for (int d = 0; d < 12; ++d) sacc[d] = fmaf(c, uf[d], sacc[d]);
      }
    }
    // reduce over g: first within wave (lane bits 4,5), then across 4 waves via LDS
    #pragma unroll
    for (int d = 0; d < 12; ++d) {
      sacc[d] += __shfl_xor(sacc[d], 16, 64);
      sacc[d] += __shfl_xor(sacc[d], 32, 64);
    }
    if (lane < 16) {
      #pragma unroll
      for (int d = 0; d < 12; ++d) red[wv][oc*12 + d] = sacc[d];
    }
    __syncthreads();
    if (tid < 192) {
      float s = red[0][tid] + red[1][tid] + red[2][tid] + red[3][tid];
      if (r == 0) s *= 0.0625f;
      sraw[tid] = s;
    }
    __syncthreads();
    if (tid < 192) {
      int qc = tid / 12;
      float nrm = 0.f;
      #pragma unroll
      for (int d = 0; d < 12; ++d) { float v = sraw[qc*12 + d]; nrm += v*v; }
      float sc = nrm / ((1.f + nrm)*sqrtf(nrm + 1e-6f));
      vsh[tid] = sraw[tid]*sc;
    }
    __syncthreads();
  }
  if (tid < 192) u2[((size_t)(rowOff + row))*192 + tid] = vsh[tid];
}

// ---------------- Class caps einsum (bf16 output) ----------------
__global__ void class_einsum(const float* __restrict__ u2, const float* __restrict__ wcl,
                             unsigned short* __restrict__ uhat2, int B) {
  int n = blockIdx.x;
  __shared__ float u2l[64][12];
  int tid = threadIdx.x;
  for (int e = tid; e < 64*12; e += 320) {
    int b = e / 12, i = e % 12;
    u2l[b][i] = u2[(size_t)b*9408 + n*12 + i];
  }
  __syncthreads();
  int od = tid % 160, bh = tid / 160;
  int o = od >> 4, d = od & 15;
  float w[12];
  #pragma unroll
  for (int i = 0; i < 12; ++i) w[i] = wcl[(size_t)n*1920 + o*192 + d*12 + i];
  for (int b = bh*32; b < bh*32+32; ++b) {
    float acc = 0.f;
    #pragma unroll
    for (int i = 0; i < 12; ++i) acc = fmaf(w[i], u2l[b][i], acc);
    uhat2[((size_t)b*784 + n)*160 + od] = f2bf(acc);
  }
}

// ---------------- class routing: wave-local pass, no barriers in main loop ----------------
template<int MODE>
__global__ __launch_bounds__(256) void cls_pass(const unsigned short* __restrict__ uh2b,
                                                const float* __restrict__ vprev,
                                                float* __restrict__ b2l,
                                                float* __restrict__ cpart) {
  const int b = blockIdx.x, sl = blockIdx.y;   // sl 0..6
  const int tid = threadIdx.x, lane = tid & 63, wv = tid >> 6;
  const int nl = lane >> 4, d = lane & 15;
  float v[10];
  if (MODE != 0) {
    #pragma unroll
    for (int o = 0; o < 10; ++o) v[o] = vprev[b*160 + o*16 + d];
  }
  float sacc[10];
  #pragma unroll
  for (int o = 0; o < 10; ++o) sacc[o] = 0.f;
  for (int step = 0; step < 7; ++step) {
    const int n = sl*112 + step*16 + wv*4 + nl;
    const unsigned short* up = uh2b + ((size_t)b*784 + n)*160 + d;
    float u[10];
    #pragma unroll
    for (int o = 0; o < 10; ++o) u[o] = bf2f(up[o*16]);
    if (MODE == 0) {
      #pragma unroll
      for (int o = 0; o < 10; ++o) sacc[o] += u[o];
    } else {
      float bb[10];
      #pragma unroll
      for (int o = 0; o < 10; ++o) {
        float t = v[o]*u[o];
        #pragma unroll
        for (int off = 8; off; off >>= 1) t += __shfl_xor(t, off, 16);
        bb[o] = t;
      }
      if (MODE == 2) {
        #pragma unroll
        for (int o = 0; o < 10; ++o) bb[o] += b2l[((size_t)b*784 + n)*10 + o];
      }
      if (MODE == 1 && d < 10) b2l[((size_t)b*784 + n)*10 + d] = bb[d];
      float mx = bb[0];
      #pragma unroll
      for (int o = 1; o < 10; ++o) mx = fmaxf(mx, bb[o]);
      float es = 0.f;
      #pragma unroll
      for (int o = 0; o < 10; ++o) { bb[o] = __expf(bb[o]-mx); es += bb[o]; }
      float inv = 1.f/es;
      #pragma unroll
      for (int o = 0; o < 10; ++o) sacc[o] = fmaf(bb[o]*inv, u[o], sacc[o]);
    }
  }
  #pragma unroll
  for (int o = 0; o < 10; ++o) {
    sacc[o] += __shfl_xor(sacc[o], 16, 64);
    sacc[o] += __shfl_xor(sacc[o], 32, 64);
  }
  __shared__ float red[4][160];
  if (lane < 16) {
    #pragma unroll
    for (int o = 0; o < 10; ++o) red[wv][o*16 + d] = sacc[o];
  }
  __syncthreads();
  if (tid < 160) {
    float s = red[0][tid] + red[1][tid] + red[2][tid] + red[3][tid];
    cpart[((size_t)b*7 + sl)*160 + tid] = s;
  }
}

__global__ __launch_bounds__(160) void cls_finish(const float* __restrict__ cpart,
                                                  float* __restrict__ vout, float fac) {
  int b = blockIdx.x, od = threadIdx.x;
  float s = 0.f;
  #pragma unroll
  for (int sl = 0; sl < 7; ++sl) s += cpart[((size_t)b*7 + sl)*160 + od];
  s *= fac;
  float nrm = s*s;
  #pragma unroll
  for (int off = 8; off; off >>= 1) nrm += __shfl_xor(nrm, off, 16);
  float sc = nrm / ((1.f + nrm)*sqrtf(nrm + 1e-6f));
  vout[(size_t)b*160 + od] = s*sc;
}

// ---------------- host launch ----------------
extern "C" void kernel_launch(void* const* d_in, const int* in_sizes, int n_in,
                              void* d_out, int out_size, void* d_ws, size_t ws_size,
                              hipStream_t stream) {
  const float* images = (const float*)d_in[0];
  const float* w1  = (const float*)d_in[1];
  const float* g1  = (const float*)d_in[2];
  const float* b1  = (const float*)d_in[3];
  const float* w2  = (const float*)d_in[4];
  const float* g2  = (const float*)d_in[5];
  const float* b2  = (const float*)d_in[6];
  const float* w3  = (const float*)d_in[7];
  const float* g3  = (const float*)d_in[8];
  const float* b3  = (const float*)d_in[9];
  const float* wp  = (const float*)d_in[10];
  const float* bp  = (const float*)d_in[11];
  const float* wcc = (const float*)d_in[12];
  const float* wcl = (const float*)d_in[13];
  float* out = (float*)d_out;
  float* ws  = (float*)d_ws;

  // persistent regions (float offsets)
  float* t1    = ws + 0;            // 3,145,728
  float* t2    = ws + 3145728;      // 1,572,864
  float* t3    = ws + 4718592;      // 3,145,728
  float* pc    = ws + 7864320;      //   602,112
  float* uu    = ws + 8466432;      // 5,419,008
  float* u2b   = ws + 13885440;     //   602,112
  unsigned short* uh2b = (unsigned short*)(ws + 14487552);  // 8,028,160 ushorts
  float* b2l   = ws + 22515712;     //   501,760
  float* scrC  = ws + 23017472;     //   501,760 (BN stats during convs, cpart during class)
  float* v2    = ws + 23519232;     //    10,240
  float* spart = ws + 23529472;     //     3,072
  float* ssc1  = ws + 23532544;     //        96
  float* ssc2  = ws + 23532640;     //       192
  float* ssc3  = ws + 23532832;     //       384
  float* U     = ws + 23533312;     // arena, 10,838,016 f32 (conv transients)
  __hip_bfloat16* uhc = (__hip_bfloat16*)(ws + 34371328);   // 43,352,064 bf16 (one 32-img chunk)

  // split/reordered weights live in dead `uu` region (dead until uu_gather)
  unsigned short* wh2 = (unsigned short*)(uu + 0);
  unsigned short* wl2 = (unsigned short*)(uu + 20736);
  unsigned short* wh3 = (unsigned short*)(uu + 41472);
  unsigned short* wl3 = (unsigned short*)(uu + 124416);
  unsigned short* whp = (unsigned short*)(uu + 207360);
  unsigned short* wlp = (unsigned short*)(uu + 373248);

  // phase transients in the U arena
  unsigned short* x2h = (unsigned short*)(U + 0);
  unsigned short* x2l = (unsigned short*)(U + 1775616);
  float*          part2 = U + 3551232;                    // 3x96x16384
  unsigned short* x3h = (unsigned short*)(U + 0);
  unsigned short* x3l = (unsigned short*)(U + 995328);
  unsigned short* xph = (unsigned short*)(U + 0);
  unsigned short* xpl = (unsigned short*)(U + 1572864);
  float*          partp = U + 3145728;                    // 8x192x3136

  const int B = 64;

  // merged weight splits
  split_w_all<<<2106,256,0,stream>>>(w2, w3, wp, wh2, wl2, wh3, wl3, whp, wlp);

  // conv1 + BN1 stats
  conv1_fused<<<2048,192,0,stream>>>(images, w1, t1);
  bn_partial<48,1024,8><<<48*8,256,0,stream>>>(t1, spart, B);
  bn_final<48,8><<<1,64,0,stream>>>(spart, g1, b1, ssc1, 65536);

  // conv2: BN1+ReLU+split (with halos), MFMA split-K=3, reduce+stats
  bn_split_nhwc<48,32,32,1><<<64*34,256,0,stream>>>(t1, ssc1, x2h, x2l);
  conv_mfma<48,34,34,16,16,2,3><<<dim3(2,128,3),256,0,stream>>>(x2h, x2l, wh2, wl2, part2, 96, B);
  splitk_reduce<96,256,3,false,true><<<6144,256,0,stream>>>(part2, nullptr, t2, scrC, B);
  bn_final<96,64><<<1,128,0,stream>>>(scrC, g2, b2, ssc2, 16384);

  // conv3: direct NCHW write (split-K=1), stats via bn_partial
  bn_split_nhwc<96,16,16,1><<<64*18,256,0,stream>>>(t2, ssc2, x3h, x3l);
  conv_mfma<96,18,18,16,16,1,1><<<dim3(3,128,1),256,0,stream>>>(x3h, x3l, wh3, wl3, t3, 192, B);
  bn_partial<192,256,8><<<192*8,256,0,stream>>>(t3, spart, B);
  bn_final<192,8><<<1,192,0,stream>>>(spart, g3, b3, ssc3, 16384);

  // primary caps conv + bias, then squash
  bn_split_nhwc<192,16,16,0><<<64*16,256,0,stream>>>(t3, ssc3, xph, xpl);
  conv_mfma<192,16,16,7,7,2,8><<<dim3(3,25,8),256,0,stream>>>(xph, xpl, whp, wlp, partp, 192, B);
  splitk_reduce<192,49,8,true,false><<<2352,256,0,stream>>>(partp, bp, pc, nullptr, B);
  squash_pc<<<196,256,0,stream>>>(pc, 50176);

  // uu gather
  uu_gather<<<21168,256,0,stream>>>(pc, uu, B);
  // ConvCaps einsum + LDS-stash fused routing, 2 chunks of 32 images
  for (int cb = 0; cb < 2; ++cb) {
    cc_einsum2<<<dim3(144,25),192,0,stream>>>(uu, wcc, uhc, cb*1568, 1568);
    cc_route<<<1568,256,0,stream>>>(uhc, u2b, cb*1568);
  }
  // Class caps einsum (bf16) + wave-local routing
  class_einsum<<<784,320,0,stream>>>(u2b, wcl, uh2b, B);
  cls_pass<0><<<dim3(64,7),256,0,stream>>>(uh2b, v2, b2l, scrC);
  cls_finish<<<64,160,0,stream>>>(scrC, v2, 0.1f);
  cls_pass<1><<<dim3(64,7),256,0,stream>>>(uh2b, v2, b2l, scrC);
  cls_finish<<<64,160,0,stream>>>(scrC, v2, 1.0f);
  cls_pass<2><<<dim3(64,7),256,0,stream>>>(uh2b, v2, b2l, scrC);
  cls_finish<<<64,160,0,stream>>>(scrC, out, 1.0f);
  (void)in_sizes; (void)n_in; (void)out_size; (void)ws_size;
}